// Round 3
// baseline (975.201 us; speedup 1.0000x reference)
//
#include <hip/hip_runtime.h>
#include <hip/hip_bf16.h>
#include <math.h>

#define N_NODES 50000
#define N_EDGES 800000
#define E_TOT   (N_EDGES + N_NODES)   // 850000
#define HEADS   4
#define NEG     0.2f

__device__ __forceinline__ float bf_lo(unsigned u) { return __uint_as_float(u << 16); }
__device__ __forceinline__ float bf_hi(unsigned u) { return __uint_as_float(u & 0xffff0000u); }
__device__ __forceinline__ float sel4(float4 w, int h) {
    float r = w.x;
    r = (h == 1) ? w.y : r;
    r = (h == 2) ? w.z : r;
    r = (h == 3) ? w.w : r;
    return r;
}

// ---------------- CSR build (dst-sorted) ----------------

__global__ void count_deg(const int* __restrict__ edst, int* __restrict__ cnt) {
    int i = blockIdx.x * blockDim.x + threadIdx.x;
    if (i >= E_TOT) return;
    int d = (i < N_EDGES) ? edst[i] : (i - N_EDGES);
    atomicAdd(&cnt[d], 1);
}

__global__ void scan_block(const int* __restrict__ cnt, int* __restrict__ off) {
    __shared__ int sums[1024];
    int tid = threadIdx.x;
    const int chunk = (N_NODES + 1023) / 1024;
    int start = tid * chunk;
    int end = min(start + chunk, N_NODES);
    int s = 0;
    for (int i = start; i < end; ++i) s += cnt[i];
    sums[tid] = s;
    __syncthreads();
    int local = s;
    for (int d = 1; d < 1024; d <<= 1) {
        int add = (tid >= d) ? sums[tid - d] : 0;
        __syncthreads();
        sums[tid] += add;
        __syncthreads();
    }
    int run = sums[tid] - local;
    for (int i = start; i < end; ++i) { off[i] = run; run += cnt[i]; }
    if (tid == 0) off[N_NODES] = E_TOT;
}

__global__ void scatter_edges(const int* __restrict__ esrc, const int* __restrict__ edst,
                              int* __restrict__ cursor, int* __restrict__ csr_src) {
    int i = blockIdx.x * blockDim.x + threadIdx.x;
    if (i >= E_TOT) return;
    int s, d;
    if (i < N_EDGES) { s = esrc[i]; d = edst[i]; }
    else             { s = i - N_EDGES; d = s; }
    int pos = atomicAdd(&cursor[d], 1);
    csr_src[pos] = s;
}

// ---------------- fp32 GEMM: C = X @ W^T (+bias), optional bf16 mirror ----------------

__global__ __launch_bounds__(256) void gemm_xwt(
        const float* __restrict__ X, const float* __restrict__ W,
        const float* __restrict__ bias, float* __restrict__ C,
        __hip_bfloat16* __restrict__ Cb,
        int n, int k, int m) {
    __shared__ float As[16][65];
    __shared__ float Bs[16][65];
    int tid = threadIdx.x;
    int tx = tid & 15, ty = tid >> 4;
    int r0 = blockIdx.y * 64, c0 = blockIdx.x * 64;
    float acc[4][4] = {};
    for (int kt = 0; kt < k; kt += 16) {
        #pragma unroll
        for (int l = 0; l < 4; ++l) {
            int idx = l * 256 + tid;
            int row = idx >> 4, kk = idx & 15;
            int gk = kt + kk;
            float v = 0.f;
            int gr = r0 + row;
            if (gr < n && gk < k) v = X[(size_t)gr * k + gk];
            As[kk][row] = v;
            float wv = 0.f;
            int gc = c0 + row;
            if (gc < m && gk < k) wv = W[(size_t)gc * k + gk];
            Bs[kk][row] = wv;
        }
        __syncthreads();
        #pragma unroll
        for (int kk = 0; kk < 16; ++kk) {
            float a[4], b[4];
            #pragma unroll
            for (int i = 0; i < 4; ++i) a[i] = As[kk][ty * 4 + i];
            #pragma unroll
            for (int j = 0; j < 4; ++j) b[j] = Bs[kk][tx * 4 + j];
            #pragma unroll
            for (int i = 0; i < 4; ++i)
                #pragma unroll
                for (int j = 0; j < 4; ++j)
                    acc[i][j] += a[i] * b[j];
        }
        __syncthreads();
    }
    #pragma unroll
    for (int i = 0; i < 4; ++i) {
        int gr = r0 + ty * 4 + i;
        if (gr >= n) continue;
        #pragma unroll
        for (int j = 0; j < 4; ++j) {
            int gc = c0 + tx * 4 + j;
            if (gc >= m) continue;
            float v = acc[i][j];
            if (bias) v += bias[gc];
            C[(size_t)gr * m + gc] = v;
            if (Cb) Cb[(size_t)gr * m + gc] = __float2bfloat16(v);
        }
    }
}

// ---------------- per-(node,head) attention logits (fp32 HF) ----------------

__global__ void calc_alpha(const float* __restrict__ HF,
                           const float* __restrict__ a_src, const float* __restrict__ a_dst,
                           float* __restrict__ asrc, float* __restrict__ adst,
                           int C, int stride) {
    int t = blockIdx.x * blockDim.x + threadIdx.x;
    if (t >= N_NODES * HEADS) return;
    int n = t >> 2, h = t & 3;
    const float* row = HF + (size_t)n * stride + h * C;
    const float* as = a_src + h * C;
    const float* ad = a_dst + h * C;
    float ss = 0.f, sd = 0.f;
    for (int c = 0; c < C; ++c) { float v = row[c]; ss += v * as[c]; sd += v * ad[c]; }
    asrc[t] = ss; adst[t] = sd;
}

// ---------------- per-node softmax: edge weights (unnormalized) + 1/den ----------------

__global__ __launch_bounds__(256) void node_softmax(
        const int* __restrict__ off, const int* __restrict__ csr_src,
        const float* __restrict__ asrc, const float* __restrict__ adst,
        float4* __restrict__ W4, float* __restrict__ INV) {
    int wv = threadIdx.x >> 6, lane = threadIdx.x & 63;
    int n = blockIdx.x * 4 + wv;
    int e0 = off[n], e1 = off[n + 1];
    float4 advv = ((const float4*)adst)[n];
    float adv[4] = {advv.x, advv.y, advv.z, advv.w};
    // pass 1: per-head max (edge-parallel)
    float mx[4] = {-INFINITY, -INFINITY, -INFINITY, -INFINITY};
    for (int e = e0 + lane; e < e1; e += 64) {
        int s = csr_src[e];
        float4 av = ((const float4*)asrc)[s];
        float a4[4] = {av.x, av.y, av.z, av.w};
        #pragma unroll
        for (int hh = 0; hh < 4; ++hh) {
            float v = a4[hh] + adv[hh];
            v = v > 0.f ? v : NEG * v;
            mx[hh] = fmaxf(mx[hh], v);
        }
    }
    #pragma unroll
    for (int d = 32; d; d >>= 1)
        #pragma unroll
        for (int hh = 0; hh < 4; ++hh) mx[hh] = fmaxf(mx[hh], __shfl_xor(mx[hh], d));
    // pass 2: exp weights (edge-parallel), accumulate denominators
    float den[4] = {0.f, 0.f, 0.f, 0.f};
    for (int e = e0 + lane; e < e1; e += 64) {
        int s = csr_src[e];
        float4 av = ((const float4*)asrc)[s];
        float a4[4] = {av.x, av.y, av.z, av.w};
        float w[4];
        #pragma unroll
        for (int hh = 0; hh < 4; ++hh) {
            float v = a4[hh] + adv[hh];
            v = v > 0.f ? v : NEG * v;
            w[hh] = __expf(v - mx[hh]);
            den[hh] += w[hh];
        }
        W4[e] = make_float4(w[0], w[1], w[2], w[3]);
    }
    #pragma unroll
    for (int d = 32; d; d >>= 1)
        #pragma unroll
        for (int hh = 0; hh < 4; ++hh) den[hh] += __shfl_xor(den[hh], d);
    if (lane == 0) {
        ((float4*)INV)[n] = make_float4(1.f / (den[0] + 1e-16f), 1.f / (den[1] + 1e-16f),
                                        1.f / (den[2] + 1e-16f), 1.f / (den[3] + 1e-16f));
    }
}

// ---------------- aggregation layers 1-2 (bf16 gather, precomputed weights) ----------------

__global__ __launch_bounds__(256) void agg12(
        const int* __restrict__ off, const int* __restrict__ csr_src,
        const unsigned* __restrict__ HU,   // bf16 HF: [N][64] uints
        const float4* __restrict__ W4, const float* __restrict__ INV,
        const float* __restrict__ bias, const float* __restrict__ LIN,
        float* __restrict__ OUT) {
    int wv = threadIdx.x >> 6, lane = threadIdx.x & 63;
    int n = blockIdx.x * 4 + wv;
    int e0 = off[n], e1 = off[n + 1];
    int h = lane >> 4;                 // head of features 2l, 2l+1
    float acc0 = 0.f, acc1 = 0.f;
    for (int e = e0; e < e1; ++e) {
        int s = csr_src[e];
        float4 w4 = W4[e];             // uniform address -> broadcast
        float w = sel4(w4, h);
        unsigned u = HU[(size_t)s * 64 + lane];
        acc0 += w * bf_lo(u);
        acc1 += w * bf_hi(u);
    }
    float inv = INV[n * 4 + h];
    int f0 = 2 * lane, f1 = 2 * lane + 1;
    size_t base = (size_t)n * 128;
    float o0 = acc0 * inv + bias[f0] + LIN[base + f0];
    float o1 = acc1 * inv + bias[f1] + LIN[base + f1];
    OUT[base + f0] = fmaxf(o0, 0.f);
    OUT[base + f1] = fmaxf(o1, 0.f);
}

// ---------------- layer 3: aggregate (188 bf16), mean heads, +lin, log_softmax ----------------

__global__ __launch_bounds__(256) void agg3(
        const int* __restrict__ off, const int* __restrict__ csr_src,
        const unsigned* __restrict__ HU,   // bf16 HF: [N][94] uints
        const float4* __restrict__ W4, const float* __restrict__ INV,
        const float* __restrict__ b3, const float* __restrict__ LIN,
        float* __restrict__ OUT) {
    __shared__ float tbuf[4][188];
    int wv = threadIdx.x >> 6, lane = threadIdx.x & 63;
    int n = blockIdx.x * 4 + wv;
    int e0 = off[n], e1 = off[n + 1];
    int f0 = 2 * lane, f1 = 2 * lane + 1;
    int f2 = 128 + 2 * lane, f3 = 129 + 2 * lane;
    bool has2 = (lane < 30);
    int hA = f0 / 47, hB = f1 / 47;
    int hC = has2 ? (f2 / 47) : 3, hD = has2 ? (f3 / 47) : 3;
    float acc0 = 0.f, acc1 = 0.f, acc2 = 0.f, acc3 = 0.f;
    for (int e = e0; e < e1; ++e) {
        int s = csr_src[e];
        float4 w4 = W4[e];             // broadcast
        float wA = sel4(w4, hA), wB = sel4(w4, hB);
        const unsigned* row = HU + (size_t)s * 94;
        unsigned u0 = row[lane];
        acc0 += wA * bf_lo(u0);
        acc1 += wB * bf_hi(u0);
        if (has2) {
            float wC = sel4(w4, hC), wD = sel4(w4, hD);
            unsigned u1 = row[64 + lane];
            acc2 += wC * bf_lo(u1);
            acc3 += wD * bf_hi(u1);
        }
    }
    float invA = INV[n * 4 + hA], invB = INV[n * 4 + hB];
    tbuf[wv][f0] = acc0 * invA;
    tbuf[wv][f1] = acc1 * invB;
    if (has2) {
        tbuf[wv][f2] = acc2 * INV[n * 4 + hC];
        tbuf[wv][f3] = acc3 * INV[n * 4 + hD];
    }
    __syncthreads();
    float z = -INFINITY;
    if (lane < 47) {
        z = 0.25f * (tbuf[wv][lane] + tbuf[wv][47 + lane] + tbuf[wv][94 + lane] + tbuf[wv][141 + lane])
            + b3[lane] + LIN[(size_t)n * 47 + lane];
    }
    float m = z;
    #pragma unroll
    for (int d = 32; d; d >>= 1) m = fmaxf(m, __shfl_xor(m, d));
    float ex = (lane < 47) ? __expf(z - m) : 0.f;
    float ssum = ex;
    #pragma unroll
    for (int d = 32; d; d >>= 1) ssum += __shfl_xor(ssum, d);
    if (lane < 47) OUT[(size_t)n * 47 + lane] = z - m - logf(ssum);
}

// ---------------- launch ----------------

extern "C" void kernel_launch(void* const* d_in, const int* in_sizes, int n_in,
                              void* d_out, int out_size, void* d_ws, size_t ws_size,
                              hipStream_t stream) {
    const float* x   = (const float*)d_in[0];
    const int*   ei  = (const int*)d_in[1];
    const float* W1  = (const float*)d_in[2];
    const float* a1s = (const float*)d_in[3];
    const float* a1d = (const float*)d_in[4];
    const float* b1  = (const float*)d_in[5];
    const float* Wl1 = (const float*)d_in[6];
    const float* bl1 = (const float*)d_in[7];
    const float* W2  = (const float*)d_in[8];
    const float* a2s = (const float*)d_in[9];
    const float* a2d = (const float*)d_in[10];
    const float* b2  = (const float*)d_in[11];
    const float* Wl2 = (const float*)d_in[12];
    const float* bl2 = (const float*)d_in[13];
    const float* W3  = (const float*)d_in[14];
    const float* a3s = (const float*)d_in[15];
    const float* a3d = (const float*)d_in[16];
    const float* b3  = (const float*)d_in[17];
    const float* Wl3 = (const float*)d_in[18];
    const float* bl3 = (const float*)d_in[19];
    float* out = (float*)d_out;

    size_t cur = 0;
    char* wsb = (char*)d_ws;
    auto carve = [&](size_t bytes) -> void* {
        void* p = wsb + cur;
        cur += (bytes + 255) & ~(size_t)255;
        return p;
    };
    int*   cnt    = (int*)  carve((size_t)N_NODES * 4);
    int*   offs   = (int*)  carve((size_t)(N_NODES + 1) * 4);
    int*   cursor = (int*)  carve((size_t)N_NODES * 4);
    int*   csr    = (int*)  carve((size_t)E_TOT * 4);
    float* HF     = (float*)carve((size_t)N_NODES * 188 * 4);
    __hip_bfloat16* HFb = (__hip_bfloat16*)carve((size_t)N_NODES * 188 * 2);
    float* LIN    = (float*)carve((size_t)N_NODES * 128 * 4);
    float* ASRC   = (float*)carve((size_t)N_NODES * 4 * 4);
    float* ADST   = (float*)carve((size_t)N_NODES * 4 * 4);
    float* B      = (float*)carve((size_t)N_NODES * 128 * 4);
    float4* W4    = (float4*)carve((size_t)E_TOT * 16);
    float* INV    = (float*)carve((size_t)N_NODES * 4 * 4);

    const int* esrc = ei;
    const int* edst = ei + N_EDGES;

    hipMemsetAsync(cnt, 0, (size_t)N_NODES * 4, stream);
    int egrid = (E_TOT + 255) / 256;
    count_deg<<<egrid, 256, 0, stream>>>(edst, cnt);
    scan_block<<<1, 1024, 0, stream>>>(cnt, offs);
    hipMemcpyAsync(cursor, offs, (size_t)N_NODES * 4, hipMemcpyDeviceToDevice, stream);
    scatter_edges<<<egrid, 256, 0, stream>>>(esrc, edst, cursor, csr);

    int agrid = (N_NODES * HEADS + 255) / 256;
    int ngrid = N_NODES / 4;

    // ---- layer 1 ----
    {
        dim3 g((128 + 63) / 64, (N_NODES + 63) / 64);
        gemm_xwt<<<g, 256, 0, stream>>>(x, W1, nullptr, HF, HFb, N_NODES, 100, 128);
        gemm_xwt<<<g, 256, 0, stream>>>(x, Wl1, bl1, LIN, nullptr, N_NODES, 100, 128);
        calc_alpha<<<agrid, 256, 0, stream>>>(HF, a1s, a1d, ASRC, ADST, 32, 128);
        node_softmax<<<ngrid, 256, 0, stream>>>(offs, csr, ASRC, ADST, W4, INV);
        agg12<<<ngrid, 256, 0, stream>>>(offs, csr, (const unsigned*)HFb, W4, INV, b1, LIN, B);
    }
    // ---- layer 2 ----
    {
        dim3 g((128 + 63) / 64, (N_NODES + 63) / 64);
        gemm_xwt<<<g, 256, 0, stream>>>(B, W2, nullptr, HF, HFb, N_NODES, 128, 128);
        gemm_xwt<<<g, 256, 0, stream>>>(B, Wl2, bl2, LIN, nullptr, N_NODES, 128, 128);
        calc_alpha<<<agrid, 256, 0, stream>>>(HF, a2s, a2d, ASRC, ADST, 32, 128);
        node_softmax<<<ngrid, 256, 0, stream>>>(offs, csr, ASRC, ADST, W4, INV);
        agg12<<<ngrid, 256, 0, stream>>>(offs, csr, (const unsigned*)HFb, W4, INV, b2, LIN, B);
    }
    // ---- layer 3 ----
    {
        dim3 g3a((188 + 63) / 64, (N_NODES + 63) / 64);
        gemm_xwt<<<g3a, 256, 0, stream>>>(B, W3, nullptr, HF, HFb, N_NODES, 128, 188);
        dim3 g3b((47 + 63) / 64, (N_NODES + 63) / 64);
        gemm_xwt<<<g3b, 256, 0, stream>>>(B, Wl3, bl3, LIN, nullptr, N_NODES, 128, 47);
        calc_alpha<<<agrid, 256, 0, stream>>>(HF, a3s, a3d, ASRC, ADST, 47, 188);
        node_softmax<<<ngrid, 256, 0, stream>>>(offs, csr, ASRC, ADST, W4, INV);
        agg3<<<ngrid, 256, 0, stream>>>(offs, csr, (const unsigned*)HFb, W4, INV, b3, LIN, out);
    }
}

// Round 4
// 751.434 us; speedup vs baseline: 1.2978x; 1.2978x over previous
//
#include <hip/hip_runtime.h>
#include <hip/hip_bf16.h>
#include <math.h>

#define N_NODES 50000
#define N_EDGES 800000
#define E_TOT   (N_EDGES + N_NODES)   // 850000
#define HEADS   4
#define NEG     0.2f
#define NROWT   3125                  // 50000/16 row-tiles

typedef __attribute__((ext_vector_type(8))) short short8;   // 8 bf16 (4 VGPRs)
typedef __attribute__((ext_vector_type(4))) float f32x4;

__device__ __forceinline__ float bf_lo(unsigned u) { return __uint_as_float(u << 16); }
__device__ __forceinline__ float bf_hi(unsigned u) { return __uint_as_float(u & 0xffff0000u); }
__device__ __forceinline__ unsigned short f2bbits(float f) {
    __hip_bfloat16 b = __float2bfloat16(f);
    return *reinterpret_cast<unsigned short*>(&b);
}
__device__ __forceinline__ float sel4(float4 w, int h) {
    float r = w.x;
    r = (h == 1) ? w.y : r;
    r = (h == 2) ? w.z : r;
    r = (h == 3) ? w.w : r;
    return r;
}

// ---------------- CSR build (dst-sorted) ----------------

__global__ void count_deg(const int* __restrict__ edst, int* __restrict__ cnt) {
    int i = blockIdx.x * blockDim.x + threadIdx.x;
    if (i >= E_TOT) return;
    int d = (i < N_EDGES) ? edst[i] : (i - N_EDGES);
    atomicAdd(&cnt[d], 1);
}

__global__ void scan_block(const int* __restrict__ cnt, int* __restrict__ off) {
    __shared__ int sums[1024];
    int tid = threadIdx.x;
    const int chunk = (N_NODES + 1023) / 1024;
    int start = tid * chunk;
    int end = min(start + chunk, N_NODES);
    int s = 0;
    for (int i = start; i < end; ++i) s += cnt[i];
    sums[tid] = s;
    __syncthreads();
    int local = s;
    for (int d = 1; d < 1024; d <<= 1) {
        int add = (tid >= d) ? sums[tid - d] : 0;
        __syncthreads();
        sums[tid] += add;
        __syncthreads();
    }
    int run = sums[tid] - local;
    for (int i = start; i < end; ++i) { off[i] = run; run += cnt[i]; }
    if (tid == 0) off[N_NODES] = E_TOT;
}

__global__ void scatter_edges(const int* __restrict__ esrc, const int* __restrict__ edst,
                              int* __restrict__ cursor, int* __restrict__ csr_src) {
    int i = blockIdx.x * blockDim.x + threadIdx.x;
    if (i >= E_TOT) return;
    int s, d;
    if (i < N_EDGES) { s = esrc[i]; d = edst[i]; }
    else             { s = i - N_EDGES; d = s; }
    int pos = atomicAdd(&cursor[d], 1);
    csr_src[pos] = s;
}

// ---------------- weight/input conversion to padded bf16 ----------------
// WALL ushort layout (each section [Mpad][128], zero-padded):
//  0      : 128x128 <- W1  (M=128,K=100)
//  16384  : 128x128 <- Wl1 (M=128,K=100)
//  32768  : 128x128 <- W2  (K=128)
//  49152  : 128x128 <- Wl2 (K=128)
//  65536  : 192x128 <- W3  (M=188,K=128)
//  90112  : 48x128  <- Wl3 (M=47,K=128)
#define WALL_TOT 96256

__global__ void conv_weights(const float* __restrict__ W1, const float* __restrict__ Wl1,
                             const float* __restrict__ W2, const float* __restrict__ Wl2,
                             const float* __restrict__ W3, const float* __restrict__ Wl3,
                             unsigned short* __restrict__ WALL) {
    int i = blockIdx.x * blockDim.x + threadIdx.x;
    if (i >= WALL_TOT) return;
    const float* src; int base, M, K;
    if      (i < 16384) { src = W1;  base = 0;     M = 128; K = 100; }
    else if (i < 32768) { src = Wl1; base = 16384; M = 128; K = 100; }
    else if (i < 49152) { src = W2;  base = 32768; M = 128; K = 128; }
    else if (i < 65536) { src = Wl2; base = 49152; M = 128; K = 128; }
    else if (i < 90112) { src = W3;  base = 65536; M = 188; K = 128; }
    else                { src = Wl3; base = 90112; M = 47;  K = 128; }
    int local = i - base;
    int m = local >> 7, k = local & 127;
    float v = (m < M && k < K) ? src[m * K + k] : 0.f;
    WALL[i] = f2bbits(v);
}

__global__ void conv_x(const float* __restrict__ x, unsigned short* __restrict__ Xb) {
    int i = blockIdx.x * blockDim.x + threadIdx.x;
    if (i >= N_NODES * 128) return;
    int n = i >> 7, k = i & 127;
    float v = (k < 100) ? x[n * 100 + k] : 0.f;
    Xb[i] = f2bbits(v);
}

// ---------------- fused bf16 MFMA GEMM: HF(bf16) + LIN(fp32) ----------------
// A: Xb [N][128] bf16. Wh: [nht*16][128], Wl: [nlt*16][128] bf16 padded.
// HFb: bf16 [N][mh_stride], cols < mh. LIN: fp32 [N][ml], cols < ml (bias bl added).

__global__ __launch_bounds__(256) void gemm_dual(
        const unsigned short* __restrict__ Xb,
        const unsigned short* __restrict__ Wh, const unsigned short* __restrict__ Wl,
        const float* __restrict__ bl,
        unsigned short* __restrict__ HFb, int mh, int mh_stride,
        float* __restrict__ LIN, int ml,
        int nht, int nlt) {
    int wv = threadIdx.x >> 6, lane = threadIdx.x & 63;
    int rt = blockIdx.x * 4 + wv;
    if (rt >= NROWT) return;
    int l16 = lane & 15, kgrp = lane >> 4;
    int arow = rt * 16 + l16;
    const unsigned short* xrow = Xb + (size_t)arow * 128 + kgrp * 8;
    short8 a[4];
    #pragma unroll
    for (int ks = 0; ks < 4; ++ks)
        a[ks] = *reinterpret_cast<const short8*>(xrow + ks * 32);
    int row0 = rt * 16 + kgrp * 4;
    int ntot = nht + nlt;
    for (int ct = 0; ct < ntot; ++ct) {
        bool isH = (ct < nht);
        const unsigned short* W = isH ? Wh : Wl;
        int c = (isH ? ct : ct - nht) * 16 + l16;
        const unsigned short* wrow = W + (size_t)c * 128 + kgrp * 8;
        f32x4 acc = {0.f, 0.f, 0.f, 0.f};
        #pragma unroll
        for (int ks = 0; ks < 4; ++ks) {
            short8 b = *reinterpret_cast<const short8*>(wrow + ks * 32);
            acc = __builtin_amdgcn_mfma_f32_16x16x32_bf16(a[ks], b, acc, 0, 0, 0);
        }
        if (isH) {
            if (c < mh) {
                #pragma unroll
                for (int r = 0; r < 4; ++r)
                    HFb[(size_t)(row0 + r) * mh_stride + c] = f2bbits(acc[r]);
            }
        } else {
            if (c < ml) {
                float bias = bl[c];
                #pragma unroll
                for (int r = 0; r < 4; ++r)
                    LIN[(size_t)(row0 + r) * ml + c] = acc[r] + bias;
            }
        }
    }
}

// ---------------- per-(node,head) attention logits (bf16 HF) ----------------

__global__ void calc_alpha(const unsigned short* __restrict__ HFb,
                           const float* __restrict__ a_src, const float* __restrict__ a_dst,
                           float* __restrict__ asrc, float* __restrict__ adst,
                           int C, int stride) {
    int t = blockIdx.x * blockDim.x + threadIdx.x;
    if (t >= N_NODES * HEADS) return;
    int n = t >> 2, h = t & 3;
    const unsigned short* row = HFb + (size_t)n * stride + h * C;
    const float* as = a_src + h * C;
    const float* ad = a_dst + h * C;
    float ss = 0.f, sd = 0.f;
    for (int c = 0; c < C; ++c) {
        float v = __uint_as_float(((unsigned)row[c]) << 16);
        ss += v * as[c]; sd += v * ad[c];
    }
    asrc[t] = ss; adst[t] = sd;
}

// ---------------- per-node softmax: edge weights (unnormalized) + 1/den ----------------

__global__ __launch_bounds__(256) void node_softmax(
        const int* __restrict__ off, const int* __restrict__ csr_src,
        const float* __restrict__ asrc, const float* __restrict__ adst,
        float4* __restrict__ W4, float* __restrict__ INV) {
    int wv = threadIdx.x >> 6, lane = threadIdx.x & 63;
    int n = blockIdx.x * 4 + wv;
    int e0 = off[n], e1 = off[n + 1];
    float4 advv = ((const float4*)adst)[n];
    float adv[4] = {advv.x, advv.y, advv.z, advv.w};
    float mx[4] = {-INFINITY, -INFINITY, -INFINITY, -INFINITY};
    for (int e = e0 + lane; e < e1; e += 64) {
        int s = csr_src[e];
        float4 av = ((const float4*)asrc)[s];
        float a4[4] = {av.x, av.y, av.z, av.w};
        #pragma unroll
        for (int hh = 0; hh < 4; ++hh) {
            float v = a4[hh] + adv[hh];
            v = v > 0.f ? v : NEG * v;
            mx[hh] = fmaxf(mx[hh], v);
        }
    }
    #pragma unroll
    for (int d = 32; d; d >>= 1)
        #pragma unroll
        for (int hh = 0; hh < 4; ++hh) mx[hh] = fmaxf(mx[hh], __shfl_xor(mx[hh], d));
    float den[4] = {0.f, 0.f, 0.f, 0.f};
    for (int e = e0 + lane; e < e1; e += 64) {
        int s = csr_src[e];
        float4 av = ((const float4*)asrc)[s];
        float a4[4] = {av.x, av.y, av.z, av.w};
        float w[4];
        #pragma unroll
        for (int hh = 0; hh < 4; ++hh) {
            float v = a4[hh] + adv[hh];
            v = v > 0.f ? v : NEG * v;
            w[hh] = __expf(v - mx[hh]);
            den[hh] += w[hh];
        }
        W4[e] = make_float4(w[0], w[1], w[2], w[3]);
    }
    #pragma unroll
    for (int d = 32; d; d >>= 1)
        #pragma unroll
        for (int hh = 0; hh < 4; ++hh) den[hh] += __shfl_xor(den[hh], d);
    if (lane == 0) {
        ((float4*)INV)[n] = make_float4(1.f / (den[0] + 1e-16f), 1.f / (den[1] + 1e-16f),
                                        1.f / (den[2] + 1e-16f), 1.f / (den[3] + 1e-16f));
    }
}

// ---------------- aggregation layers 1-2: bf16 gather -> packed bf16 out ----------------

__global__ __launch_bounds__(256) void agg12(
        const int* __restrict__ off, const int* __restrict__ csr_src,
        const unsigned* __restrict__ HU,   // bf16 HF: [N][64] uints
        const float4* __restrict__ W4, const float* __restrict__ INV,
        const float* __restrict__ bias, const float* __restrict__ LIN,
        unsigned* __restrict__ OUTB) {     // bf16 out: [N][64] uints
    int wv = threadIdx.x >> 6, lane = threadIdx.x & 63;
    int n = blockIdx.x * 4 + wv;
    int e0 = off[n], e1 = off[n + 1];
    int h = lane >> 4;
    float acc0 = 0.f, acc1 = 0.f;
    for (int e = e0; e < e1; ++e) {
        int s = csr_src[e];
        float4 w4 = W4[e];
        float w = sel4(w4, h);
        unsigned u = HU[(size_t)s * 64 + lane];
        acc0 += w * bf_lo(u);
        acc1 += w * bf_hi(u);
    }
    float inv = INV[n * 4 + h];
    int f0 = 2 * lane, f1 = 2 * lane + 1;
    size_t base = (size_t)n * 128;
    float o0 = fmaxf(acc0 * inv + bias[f0] + LIN[base + f0], 0.f);
    float o1 = fmaxf(acc1 * inv + bias[f1] + LIN[base + f1], 0.f);
    OUTB[(size_t)n * 64 + lane] = ((unsigned)f2bbits(o1) << 16) | f2bbits(o0);
}

// ---------------- layer 3: aggregate (188 bf16), mean heads, +lin, log_softmax ----------------

__global__ __launch_bounds__(256) void agg3(
        const int* __restrict__ off, const int* __restrict__ csr_src,
        const unsigned* __restrict__ HU,   // bf16 HF: [N][94] uints
        const float4* __restrict__ W4, const float* __restrict__ INV,
        const float* __restrict__ b3, const float* __restrict__ LIN,
        float* __restrict__ OUT) {
    __shared__ float tbuf[4][188];
    int wv = threadIdx.x >> 6, lane = threadIdx.x & 63;
    int n = blockIdx.x * 4 + wv;
    int e0 = off[n], e1 = off[n + 1];
    int f0 = 2 * lane, f1 = 2 * lane + 1;
    int f2 = 128 + 2 * lane, f3 = 129 + 2 * lane;
    bool has2 = (lane < 30);
    int hA = f0 / 47, hB = f1 / 47;
    int hC = has2 ? (f2 / 47) : 3, hD = has2 ? (f3 / 47) : 3;
    float acc0 = 0.f, acc1 = 0.f, acc2 = 0.f, acc3 = 0.f;
    for (int e = e0; e < e1; ++e) {
        int s = csr_src[e];
        float4 w4 = W4[e];
        float wA = sel4(w4, hA), wB = sel4(w4, hB);
        const unsigned* row = HU + (size_t)s * 94;
        unsigned u0 = row[lane];
        acc0 += wA * bf_lo(u0);
        acc1 += wB * bf_hi(u0);
        if (has2) {
            float wC = sel4(w4, hC), wD = sel4(w4, hD);
            unsigned u1 = row[64 + lane];
            acc2 += wC * bf_lo(u1);
            acc3 += wD * bf_hi(u1);
        }
    }
    tbuf[wv][f0] = acc0 * INV[n * 4 + hA];
    tbuf[wv][f1] = acc1 * INV[n * 4 + hB];
    if (has2) {
        tbuf[wv][f2] = acc2 * INV[n * 4 + hC];
        tbuf[wv][f3] = acc3 * INV[n * 4 + hD];
    }
    __syncthreads();
    float z = -INFINITY;
    if (lane < 47) {
        z = 0.25f * (tbuf[wv][lane] + tbuf[wv][47 + lane] + tbuf[wv][94 + lane] + tbuf[wv][141 + lane])
            + b3[lane] + LIN[(size_t)n * 47 + lane];
    }
    float m = z;
    #pragma unroll
    for (int d = 32; d; d >>= 1) m = fmaxf(m, __shfl_xor(m, d));
    float ex = (lane < 47) ? __expf(z - m) : 0.f;
    float ssum = ex;
    #pragma unroll
    for (int d = 32; d; d >>= 1) ssum += __shfl_xor(ssum, d);
    if (lane < 47) OUT[(size_t)n * 47 + lane] = z - m - logf(ssum);
}

// ---------------- launch ----------------

extern "C" void kernel_launch(void* const* d_in, const int* in_sizes, int n_in,
                              void* d_out, int out_size, void* d_ws, size_t ws_size,
                              hipStream_t stream) {
    const float* x   = (const float*)d_in[0];
    const int*   ei  = (const int*)d_in[1];
    const float* W1  = (const float*)d_in[2];
    const float* a1s = (const float*)d_in[3];
    const float* a1d = (const float*)d_in[4];
    const float* b1  = (const float*)d_in[5];
    const float* Wl1 = (const float*)d_in[6];
    const float* bl1 = (const float*)d_in[7];
    const float* W2  = (const float*)d_in[8];
    const float* a2s = (const float*)d_in[9];
    const float* a2d = (const float*)d_in[10];
    const float* b2  = (const float*)d_in[11];
    const float* Wl2 = (const float*)d_in[12];
    const float* bl2 = (const float*)d_in[13];
    const float* W3  = (const float*)d_in[14];
    const float* a3s = (const float*)d_in[15];
    const float* a3d = (const float*)d_in[16];
    const float* b3  = (const float*)d_in[17];
    const float* Wl3 = (const float*)d_in[18];
    const float* bl3 = (const float*)d_in[19];
    float* out = (float*)d_out;

    size_t cur = 0;
    char* wsb = (char*)d_ws;
    auto carve = [&](size_t bytes) -> void* {
        void* p = wsb + cur;
        cur += (bytes + 255) & ~(size_t)255;
        return p;
    };
    int*   cnt    = (int*)  carve((size_t)N_NODES * 4);
    int*   offs   = (int*)  carve((size_t)(N_NODES + 1) * 4);
    int*   cursor = (int*)  carve((size_t)N_NODES * 4);
    int*   csr    = (int*)  carve((size_t)E_TOT * 4);
    unsigned short* WALL = (unsigned short*)carve((size_t)WALL_TOT * 2);
    unsigned short* Xb   = (unsigned short*)carve((size_t)N_NODES * 128 * 2);
    unsigned short* HFb  = (unsigned short*)carve((size_t)N_NODES * 188 * 2);
    unsigned short* Bb   = (unsigned short*)carve((size_t)N_NODES * 128 * 2);
    float* LIN    = (float*)carve((size_t)N_NODES * 128 * 4);
    float* ASRC   = (float*)carve((size_t)N_NODES * 4 * 4);
    float* ADST   = (float*)carve((size_t)N_NODES * 4 * 4);
    float4* W4    = (float4*)carve((size_t)E_TOT * 16);
    float* INV    = (float*)carve((size_t)N_NODES * 4 * 4);

    unsigned short* Wb1h = WALL + 0;
    unsigned short* Wb1l = WALL + 16384;
    unsigned short* Wb2h = WALL + 32768;
    unsigned short* Wb2l = WALL + 49152;
    unsigned short* Wb3h = WALL + 65536;
    unsigned short* Wb3l = WALL + 90112;

    const int* esrc = ei;
    const int* edst = ei + N_EDGES;

    // conversions
    conv_weights<<<(WALL_TOT + 255) / 256, 256, 0, stream>>>(W1, Wl1, W2, Wl2, W3, Wl3, WALL);
    conv_x<<<(N_NODES * 128 + 255) / 256, 256, 0, stream>>>(x, Xb);

    // CSR build
    hipMemsetAsync(cnt, 0, (size_t)N_NODES * 4, stream);
    int egrid = (E_TOT + 255) / 256;
    count_deg<<<egrid, 256, 0, stream>>>(edst, cnt);
    scan_block<<<1, 1024, 0, stream>>>(cnt, offs);
    hipMemcpyAsync(cursor, offs, (size_t)N_NODES * 4, hipMemcpyDeviceToDevice, stream);
    scatter_edges<<<egrid, 256, 0, stream>>>(esrc, edst, cursor, csr);

    int agrid = (N_NODES * HEADS + 255) / 256;
    int ngrid = N_NODES / 4;
    int ggrid = (NROWT + 3) / 4;   // 782

    // ---- layer 1 ----
    gemm_dual<<<ggrid, 256, 0, stream>>>(Xb, Wb1h, Wb1l, bl1, HFb, 128, 128, LIN, 128, 8, 8);
    calc_alpha<<<agrid, 256, 0, stream>>>(HFb, a1s, a1d, ASRC, ADST, 32, 128);
    node_softmax<<<ngrid, 256, 0, stream>>>(offs, csr, ASRC, ADST, W4, INV);
    agg12<<<ngrid, 256, 0, stream>>>(offs, csr, (const unsigned*)HFb, W4, INV, b1, LIN, (unsigned*)Bb);
    // ---- layer 2 ----
    gemm_dual<<<ggrid, 256, 0, stream>>>(Bb, Wb2h, Wb2l, bl2, HFb, 128, 128, LIN, 128, 8, 8);
    calc_alpha<<<agrid, 256, 0, stream>>>(HFb, a2s, a2d, ASRC, ADST, 32, 128);
    node_softmax<<<ngrid, 256, 0, stream>>>(offs, csr, ASRC, ADST, W4, INV);
    agg12<<<ngrid, 256, 0, stream>>>(offs, csr, (const unsigned*)HFb, W4, INV, b2, LIN, (unsigned*)Bb);
    // ---- layer 3 ----
    gemm_dual<<<ggrid, 256, 0, stream>>>(Bb, Wb3h, Wb3l, bl3, HFb, 188, 188, LIN, 47, 12, 3);
    calc_alpha<<<agrid, 256, 0, stream>>>(HFb, a3s, a3d, ASRC, ADST, 47, 188);
    node_softmax<<<ngrid, 256, 0, stream>>>(offs, csr, ASRC, ADST, W4, INV);
    agg3<<<ngrid, 256, 0, stream>>>(offs, csr, (const unsigned*)HFb, W4, INV, b3, LIN, out);
}

// Round 5
// 552.193 us; speedup vs baseline: 1.7661x; 1.3608x over previous
//
#include <hip/hip_runtime.h>
#include <hip/hip_bf16.h>
#include <math.h>

#define N_NODES 50000
#define N_EDGES 800000
#define E_TOT   (N_EDGES + N_NODES)   // 850000
#define HEADS   4
#define NEG     0.2f
#define NROWT   3125                  // 50000/16 row-tiles

typedef __attribute__((ext_vector_type(8))) short short8;   // 8 bf16 (4 VGPRs)
typedef __attribute__((ext_vector_type(4))) float f32x4;

__device__ __forceinline__ float bf_lo(unsigned u) { return __uint_as_float(u << 16); }
__device__ __forceinline__ float bf_hi(unsigned u) { return __uint_as_float(u & 0xffff0000u); }
__device__ __forceinline__ unsigned short f2bbits(float f) {
    __hip_bfloat16 b = __float2bfloat16(f);
    return *reinterpret_cast<unsigned short*>(&b);
}
__device__ __forceinline__ float sel4(float4 w, int h) {
    float r = w.x;
    r = (h == 1) ? w.y : r;
    r = (h == 2) ? w.z : r;
    r = (h == 3) ? w.w : r;
    return r;
}
__device__ __forceinline__ float lrelu(float v) { return v > 0.f ? v : NEG * v; }

// ---------------- CSR build (dst-sorted) ----------------

__global__ void count_deg(const int* __restrict__ edst, int* __restrict__ cnt) {
    int i = blockIdx.x * blockDim.x + threadIdx.x;
    if (i >= E_TOT) return;
    int d = (i < N_EDGES) ? edst[i] : (i - N_EDGES);
    atomicAdd(&cnt[d], 1);
}

__global__ void scan_block(const int* __restrict__ cnt, int* __restrict__ off) {
    __shared__ int sums[1024];
    int tid = threadIdx.x;
    const int chunk = (N_NODES + 1023) / 1024;
    int start = tid * chunk;
    int end = min(start + chunk, N_NODES);
    int s = 0;
    for (int i = start; i < end; ++i) s += cnt[i];
    sums[tid] = s;
    __syncthreads();
    int local = s;
    for (int d = 1; d < 1024; d <<= 1) {
        int add = (tid >= d) ? sums[tid - d] : 0;
        __syncthreads();
        sums[tid] += add;
        __syncthreads();
    }
    int run = sums[tid] - local;
    for (int i = start; i < end; ++i) { off[i] = run; run += cnt[i]; }
    if (tid == 0) off[N_NODES] = E_TOT;
}

__global__ void scatter_edges(const int* __restrict__ esrc, const int* __restrict__ edst,
                              int* __restrict__ cursor, int* __restrict__ csr_src,
                              int* __restrict__ csr_dst) {
    int i = blockIdx.x * blockDim.x + threadIdx.x;
    if (i >= E_TOT) return;
    int s, d;
    if (i < N_EDGES) { s = esrc[i]; d = edst[i]; }
    else             { s = i - N_EDGES; d = s; }
    int pos = atomicAdd(&cursor[d], 1);
    csr_src[pos] = s;
    csr_dst[pos] = d;
}

// ---------------- weight/input conversion to padded bf16 ----------------
#define WALL_TOT 96256

__global__ void conv_weights(const float* __restrict__ W1, const float* __restrict__ Wl1,
                             const float* __restrict__ W2, const float* __restrict__ Wl2,
                             const float* __restrict__ W3, const float* __restrict__ Wl3,
                             unsigned short* __restrict__ WALL) {
    int i = blockIdx.x * blockDim.x + threadIdx.x;
    if (i >= WALL_TOT) return;
    const float* src; int base, M, K;
    if      (i < 16384) { src = W1;  base = 0;     M = 128; K = 100; }
    else if (i < 32768) { src = Wl1; base = 16384; M = 128; K = 100; }
    else if (i < 49152) { src = W2;  base = 32768; M = 128; K = 128; }
    else if (i < 65536) { src = Wl2; base = 49152; M = 128; K = 128; }
    else if (i < 90112) { src = W3;  base = 65536; M = 188; K = 128; }
    else                { src = Wl3; base = 90112; M = 47;  K = 128; }
    int local = i - base;
    int m = local >> 7, k = local & 127;
    float v = (m < M && k < K) ? src[m * K + k] : 0.f;
    WALL[i] = f2bbits(v);
}

__global__ void conv_x(const float* __restrict__ x, unsigned short* __restrict__ Xb) {
    int i = blockIdx.x * blockDim.x + threadIdx.x;
    if (i >= N_NODES * 128) return;
    int n = i >> 7, k = i & 127;
    float v = (k < 100) ? x[n * 100 + k] : 0.f;
    Xb[i] = f2bbits(v);
}

// ---------------- fused bf16 MFMA GEMM: HF(bf16) + LIN(fp32) ----------------

__global__ __launch_bounds__(256) void gemm_dual(
        const unsigned short* __restrict__ Xb,
        const unsigned short* __restrict__ Wh, const unsigned short* __restrict__ Wl,
        const float* __restrict__ bl,
        unsigned short* __restrict__ HFb, int mh, int mh_stride,
        float* __restrict__ LIN, int ml,
        int nht, int nlt) {
    int wv = threadIdx.x >> 6, lane = threadIdx.x & 63;
    int rt = blockIdx.x * 4 + wv;
    if (rt >= NROWT) return;
    int l16 = lane & 15, kgrp = lane >> 4;
    int arow = rt * 16 + l16;
    const unsigned short* xrow = Xb + (size_t)arow * 128 + kgrp * 8;
    short8 a[4];
    #pragma unroll
    for (int ks = 0; ks < 4; ++ks)
        a[ks] = *reinterpret_cast<const short8*>(xrow + ks * 32);
    int row0 = rt * 16 + kgrp * 4;
    int ntot = nht + nlt;
    for (int ct = 0; ct < ntot; ++ct) {
        bool isH = (ct < nht);
        const unsigned short* W = isH ? Wh : Wl;
        int c = (isH ? ct : ct - nht) * 16 + l16;
        const unsigned short* wrow = W + (size_t)c * 128 + kgrp * 8;
        f32x4 acc = {0.f, 0.f, 0.f, 0.f};
        #pragma unroll
        for (int ks = 0; ks < 4; ++ks) {
            short8 b = *reinterpret_cast<const short8*>(wrow + ks * 32);
            acc = __builtin_amdgcn_mfma_f32_16x16x32_bf16(a[ks], b, acc, 0, 0, 0);
        }
        if (isH) {
            if (c < mh) {
                #pragma unroll
                for (int r = 0; r < 4; ++r)
                    HFb[(size_t)(row0 + r) * mh_stride + c] = f2bbits(acc[r]);
            }
        } else {
            if (c < ml) {
                float bias = bl[c];
                #pragma unroll
                for (int r = 0; r < 4; ++r)
                    LIN[(size_t)(row0 + r) * ml + c] = acc[r] + bias;
            }
        }
    }
}

// ---------------- per-(node,head) attention logits (bf16 HF) ----------------

__global__ void calc_alpha(const unsigned short* __restrict__ HFb,
                           const float* __restrict__ a_src, const float* __restrict__ a_dst,
                           float* __restrict__ asrc, float* __restrict__ adst,
                           int C, int stride) {
    int t = blockIdx.x * blockDim.x + threadIdx.x;
    if (t >= N_NODES * HEADS) return;
    int n = t >> 2, h = t & 3;
    const unsigned short* row = HFb + (size_t)n * stride + h * C;
    const float* as = a_src + h * C;
    const float* ad = a_dst + h * C;
    float ss = 0.f, sd = 0.f;
    for (int c = 0; c < C; ++c) {
        float v = __uint_as_float(((unsigned)row[c]) << 16);
        ss += v * as[c]; sd += v * ad[c];
    }
    asrc[t] = ss; adst[t] = sd;
}

// ---------------- edge-centric exp weights (no max: logits are O(1), safe in fp32) ----

__global__ void edge_weights(const int* __restrict__ csr_src, const int* __restrict__ csr_dst,
                             const float* __restrict__ asrc, const float* __restrict__ adst,
                             float4* __restrict__ W4) {
    int e = blockIdx.x * blockDim.x + threadIdx.x;
    if (e >= E_TOT) return;
    int s = csr_src[e], d = csr_dst[e];
    float4 av = ((const float4*)asrc)[s];
    float4 dv = ((const float4*)adst)[d];
    float4 w;
    w.x = __expf(lrelu(av.x + dv.x));
    w.y = __expf(lrelu(av.y + dv.y));
    w.z = __expf(lrelu(av.z + dv.z));
    w.w = __expf(lrelu(av.w + dv.w));
    W4[e] = w;
}

// ---------------- aggregation layers 1-2: 2-edge split + unroll, inline denom --------

__global__ __launch_bounds__(256) void agg12(
        const int* __restrict__ off, const int* __restrict__ csr_src,
        const uint2* __restrict__ HU2,   // bf16 HF: [N][32] uint2 (128 features)
        const float4* __restrict__ W4,
        const float* __restrict__ bias, const float* __restrict__ LIN,
        unsigned* __restrict__ OUTB) {   // bf16 out: [N][64] uints
    int wv = threadIdx.x >> 6, lane = threadIdx.x & 63;
    int n = blockIdx.x * 4 + wv;
    int e0 = off[n], e1 = off[n + 1];
    int el = lane >> 5;        // which edge of the pair
    int fl = lane & 31;        // uint2 index: features 4fl..4fl+3
    int h = fl >> 3;           // head
    float acc0 = 0.f, acc1 = 0.f, acc2 = 0.f, acc3 = 0.f, den = 0.f;
    int e = e0;
    for (; e + 4 <= e1; e += 4) {
        int sA = csr_src[e + el];
        int sB = csr_src[e + 2 + el];
        float4 wA4 = W4[e + el];
        float4 wB4 = W4[e + 2 + el];
        uint2 uA = HU2[(size_t)sA * 32 + fl];
        uint2 uB = HU2[(size_t)sB * 32 + fl];
        float wA = sel4(wA4, h), wB = sel4(wB4, h);
        den += wA + wB;
        acc0 += wA * bf_lo(uA.x) + wB * bf_lo(uB.x);
        acc1 += wA * bf_hi(uA.x) + wB * bf_hi(uB.x);
        acc2 += wA * bf_lo(uA.y) + wB * bf_lo(uB.y);
        acc3 += wA * bf_hi(uA.y) + wB * bf_hi(uB.y);
    }
    for (; e + 2 <= e1; e += 2) {
        int s = csr_src[e + el];
        float4 w4 = W4[e + el];
        uint2 u = HU2[(size_t)s * 32 + fl];
        float w = sel4(w4, h);
        den += w;
        acc0 += w * bf_lo(u.x);
        acc1 += w * bf_hi(u.x);
        acc2 += w * bf_lo(u.y);
        acc3 += w * bf_hi(u.y);
    }
    if (e + el < e1) {
        int s = csr_src[e + el];
        float4 w4 = W4[e + el];
        uint2 u = HU2[(size_t)s * 32 + fl];
        float w = sel4(w4, h);
        den += w;
        acc0 += w * bf_lo(u.x);
        acc1 += w * bf_hi(u.x);
        acc2 += w * bf_lo(u.y);
        acc3 += w * bf_hi(u.y);
    }
    acc0 += __shfl_xor(acc0, 32);
    acc1 += __shfl_xor(acc1, 32);
    acc2 += __shfl_xor(acc2, 32);
    acc3 += __shfl_xor(acc3, 32);
    den  += __shfl_xor(den, 32);
    float inv = 1.0f / (den + 1e-16f);
    int f0 = 4 * fl;
    size_t base = (size_t)n * 128;
    float4 lin = *reinterpret_cast<const float4*>(&LIN[base + f0]);
    float4 bs  = *reinterpret_cast<const float4*>(&bias[f0]);
    float o0 = fmaxf(acc0 * inv + bs.x + lin.x, 0.f);
    float o1 = fmaxf(acc1 * inv + bs.y + lin.y, 0.f);
    float o2 = fmaxf(acc2 * inv + bs.z + lin.z, 0.f);
    float o3 = fmaxf(acc3 * inv + bs.w + lin.w, 0.f);
    if (el == 0) {
        uint2 p;
        p.x = ((unsigned)f2bbits(o1) << 16) | f2bbits(o0);
        p.y = ((unsigned)f2bbits(o3) << 16) | f2bbits(o2);
        ((uint2*)OUTB)[(size_t)n * 32 + fl] = p;
    }
}

// ---------------- layer 3: aggregate (188 bf16), inline denom, mean heads, log_softmax

__global__ __launch_bounds__(256) void agg3(
        const int* __restrict__ off, const int* __restrict__ csr_src,
        const unsigned* __restrict__ HU,   // bf16 HF: [N][94] uints
        const float4* __restrict__ W4,
        const float* __restrict__ b3, const float* __restrict__ LIN,
        float* __restrict__ OUT) {
    __shared__ float tbuf[4][188];
    int wv = threadIdx.x >> 6, lane = threadIdx.x & 63;
    int n = blockIdx.x * 4 + wv;
    int e0 = off[n], e1 = off[n + 1];
    int f0 = 2 * lane, f1 = 2 * lane + 1;
    int f2 = 128 + 2 * lane, f3 = 129 + 2 * lane;
    bool has2 = (lane < 30);
    int hA = f0 / 47, hB = f1 / 47;
    int hC = has2 ? (f2 / 47) : 3, hD = has2 ? (f3 / 47) : 3;
    float acc0 = 0.f, acc1 = 0.f, acc2 = 0.f, acc3 = 0.f;
    float den0 = 0.f, den1 = 0.f, den2 = 0.f, den3 = 0.f;
    int e = e0;
    for (; e + 2 <= e1; e += 2) {
        int sA = csr_src[e], sB = csr_src[e + 1];
        float4 wA = W4[e], wB = W4[e + 1];
        const unsigned* rA = HU + (size_t)sA * 94;
        const unsigned* rB = HU + (size_t)sB * 94;
        unsigned uA0 = rA[lane], uB0 = rB[lane];
        unsigned uA1 = 0, uB1 = 0;
        if (has2) { uA1 = rA[64 + lane]; uB1 = rB[64 + lane]; }
        den0 += wA.x + wB.x; den1 += wA.y + wB.y;
        den2 += wA.z + wB.z; den3 += wA.w + wB.w;
        acc0 += sel4(wA, hA) * bf_lo(uA0) + sel4(wB, hA) * bf_lo(uB0);
        acc1 += sel4(wA, hB) * bf_hi(uA0) + sel4(wB, hB) * bf_hi(uB0);
        if (has2) {
            acc2 += sel4(wA, hC) * bf_lo(uA1) + sel4(wB, hC) * bf_lo(uB1);
            acc3 += sel4(wA, hD) * bf_hi(uA1) + sel4(wB, hD) * bf_hi(uB1);
        }
    }
    if (e < e1) {
        int s = csr_src[e];
        float4 w4 = W4[e];
        const unsigned* row = HU + (size_t)s * 94;
        unsigned u0 = row[lane];
        den0 += w4.x; den1 += w4.y; den2 += w4.z; den3 += w4.w;
        acc0 += sel4(w4, hA) * bf_lo(u0);
        acc1 += sel4(w4, hB) * bf_hi(u0);
        if (has2) {
            unsigned u1 = row[64 + lane];
            acc2 += sel4(w4, hC) * bf_lo(u1);
            acc3 += sel4(w4, hD) * bf_hi(u1);
        }
    }
    float4 denv = make_float4(den0 + 1e-16f, den1 + 1e-16f, den2 + 1e-16f, den3 + 1e-16f);
    tbuf[wv][f0] = acc0 / sel4(denv, hA);
    tbuf[wv][f1] = acc1 / sel4(denv, hB);
    if (has2) {
        tbuf[wv][f2] = acc2 / sel4(denv, hC);
        tbuf[wv][f3] = acc3 / sel4(denv, hD);
    }
    __syncthreads();
    float z = -INFINITY;
    if (lane < 47) {
        z = 0.25f * (tbuf[wv][lane] + tbuf[wv][47 + lane] + tbuf[wv][94 + lane] + tbuf[wv][141 + lane])
            + b3[lane] + LIN[(size_t)n * 47 + lane];
    }
    float m = z;
    #pragma unroll
    for (int d = 32; d; d >>= 1) m = fmaxf(m, __shfl_xor(m, d));
    float ex = (lane < 47) ? __expf(z - m) : 0.f;
    float ssum = ex;
    #pragma unroll
    for (int d = 32; d; d >>= 1) ssum += __shfl_xor(ssum, d);
    if (lane < 47) OUT[(size_t)n * 47 + lane] = z - m - logf(ssum);
}

// ---------------- launch ----------------

extern "C" void kernel_launch(void* const* d_in, const int* in_sizes, int n_in,
                              void* d_out, int out_size, void* d_ws, size_t ws_size,
                              hipStream_t stream) {
    const float* x   = (const float*)d_in[0];
    const int*   ei  = (const int*)d_in[1];
    const float* W1  = (const float*)d_in[2];
    const float* a1s = (const float*)d_in[3];
    const float* a1d = (const float*)d_in[4];
    const float* b1  = (const float*)d_in[5];
    const float* Wl1 = (const float*)d_in[6];
    const float* bl1 = (const float*)d_in[7];
    const float* W2  = (const float*)d_in[8];
    const float* a2s = (const float*)d_in[9];
    const float* a2d = (const float*)d_in[10];
    const float* b2  = (const float*)d_in[11];
    const float* Wl2 = (const float*)d_in[12];
    const float* bl2 = (const float*)d_in[13];
    const float* W3  = (const float*)d_in[14];
    const float* a3s = (const float*)d_in[15];
    const float* a3d = (const float*)d_in[16];
    const float* b3  = (const float*)d_in[17];
    const float* Wl3 = (const float*)d_in[18];
    const float* bl3 = (const float*)d_in[19];
    float* out = (float*)d_out;

    size_t cur = 0;
    char* wsb = (char*)d_ws;
    auto carve = [&](size_t bytes) -> void* {
        void* p = wsb + cur;
        cur += (bytes + 255) & ~(size_t)255;
        return p;
    };
    int*   cnt    = (int*)  carve((size_t)N_NODES * 4);
    int*   offs   = (int*)  carve((size_t)(N_NODES + 1) * 4);
    int*   cursor = (int*)  carve((size_t)N_NODES * 4);
    int*   csr    = (int*)  carve((size_t)E_TOT * 4);
    int*   csrd   = (int*)  carve((size_t)E_TOT * 4);
    unsigned short* WALL = (unsigned short*)carve((size_t)WALL_TOT * 2);
    unsigned short* Xb   = (unsigned short*)carve((size_t)N_NODES * 128 * 2);
    unsigned short* HFb  = (unsigned short*)carve((size_t)N_NODES * 188 * 2);
    unsigned short* Bb   = (unsigned short*)carve((size_t)N_NODES * 128 * 2);
    float* LIN    = (float*)carve((size_t)N_NODES * 128 * 4);
    float* ASRC   = (float*)carve((size_t)N_NODES * 4 * 4);
    float* ADST   = (float*)carve((size_t)N_NODES * 4 * 4);
    float4* W4    = (float4*)carve((size_t)E_TOT * 16);

    unsigned short* Wb1h = WALL + 0;
    unsigned short* Wb1l = WALL + 16384;
    unsigned short* Wb2h = WALL + 32768;
    unsigned short* Wb2l = WALL + 49152;
    unsigned short* Wb3h = WALL + 65536;
    unsigned short* Wb3l = WALL + 90112;

    const int* esrc = ei;
    const int* edst = ei + N_EDGES;

    conv_weights<<<(WALL_TOT + 255) / 256, 256, 0, stream>>>(W1, Wl1, W2, Wl2, W3, Wl3, WALL);
    conv_x<<<(N_NODES * 128 + 255) / 256, 256, 0, stream>>>(x, Xb);

    hipMemsetAsync(cnt, 0, (size_t)N_NODES * 4, stream);
    int egrid = (E_TOT + 255) / 256;
    count_deg<<<egrid, 256, 0, stream>>>(edst, cnt);
    scan_block<<<1, 1024, 0, stream>>>(cnt, offs);
    hipMemcpyAsync(cursor, offs, (size_t)N_NODES * 4, hipMemcpyDeviceToDevice, stream);
    scatter_edges<<<egrid, 256, 0, stream>>>(esrc, edst, cursor, csr, csrd);

    int agrid = (N_NODES * HEADS + 255) / 256;
    int ngrid = N_NODES / 4;
    int ggrid = (NROWT + 3) / 4;   // 782

    // ---- layer 1 ----
    gemm_dual<<<ggrid, 256, 0, stream>>>(Xb, Wb1h, Wb1l, bl1, HFb, 128, 128, LIN, 128, 8, 8);
    calc_alpha<<<agrid, 256, 0, stream>>>(HFb, a1s, a1d, ASRC, ADST, 32, 128);
    edge_weights<<<egrid, 256, 0, stream>>>(csr, csrd, ASRC, ADST, W4);
    agg12<<<ngrid, 256, 0, stream>>>(offs, csr, (const uint2*)HFb, W4, b1, LIN, (unsigned*)Bb);
    // ---- layer 2 ----
    gemm_dual<<<ggrid, 256, 0, stream>>>(Bb, Wb2h, Wb2l, bl2, HFb, 128, 128, LIN, 128, 8, 8);
    calc_alpha<<<agrid, 256, 0, stream>>>(HFb, a2s, a2d, ASRC, ADST, 32, 128);
    edge_weights<<<egrid, 256, 0, stream>>>(csr, csrd, ASRC, ADST, W4);
    agg12<<<ngrid, 256, 0, stream>>>(offs, csr, (const uint2*)HFb, W4, b2, LIN, (unsigned*)Bb);
    // ---- layer 3 ----
    gemm_dual<<<ggrid, 256, 0, stream>>>(Bb, Wb3h, Wb3l, bl3, HFb, 188, 188, LIN, 47, 12, 3);
    calc_alpha<<<agrid, 256, 0, stream>>>(HFb, a3s, a3d, ASRC, ADST, 47, 188);
    edge_weights<<<egrid, 256, 0, stream>>>(csr, csrd, ASRC, ADST, W4);
    agg3<<<ngrid, 256, 0, stream>>>(offs, csr, (const unsigned*)HFb, W4, b3, LIN, out);
}

// Round 6
// 509.800 us; speedup vs baseline: 1.9129x; 1.0832x over previous
//
#include <hip/hip_runtime.h>
#include <hip/hip_bf16.h>
#include <math.h>

#define N_NODES 50000
#define N_EDGES 800000
#define E_TOT   (N_EDGES + N_NODES)   // 850000
#define HEADS   4
#define NEG     0.2f
#define NROWT   3125                  // 50000/16 row-tiles

typedef __attribute__((ext_vector_type(8))) short short8;   // 8 bf16 (4 VGPRs)
typedef __attribute__((ext_vector_type(4))) float f32x4;

__device__ __forceinline__ float bf_lo(unsigned u) { return __uint_as_float(u << 16); }
__device__ __forceinline__ float bf_hi(unsigned u) { return __uint_as_float(u & 0xffff0000u); }
__device__ __forceinline__ unsigned short f2bbits(float f) {
    __hip_bfloat16 b = __float2bfloat16(f);
    return *reinterpret_cast<unsigned short*>(&b);
}
__device__ __forceinline__ float lrelu(float v) { return v > 0.f ? v : NEG * v; }

// ---------------- CSR build (dst-sorted) ----------------

__global__ void count_deg(const int* __restrict__ edst, int* __restrict__ cnt) {
    int i = blockIdx.x * blockDim.x + threadIdx.x;
    if (i >= E_TOT) return;
    int d = (i < N_EDGES) ? edst[i] : (i - N_EDGES);
    atomicAdd(&cnt[d], 1);
}

__global__ void scan_block(const int* __restrict__ cnt, int* __restrict__ off) {
    __shared__ int sums[1024];
    int tid = threadIdx.x;
    const int chunk = (N_NODES + 1023) / 1024;
    int start = tid * chunk;
    int end = min(start + chunk, N_NODES);
    int s = 0;
    for (int i = start; i < end; ++i) s += cnt[i];
    sums[tid] = s;
    __syncthreads();
    int local = s;
    for (int d = 1; d < 1024; d <<= 1) {
        int add = (tid >= d) ? sums[tid - d] : 0;
        __syncthreads();
        sums[tid] += add;
        __syncthreads();
    }
    int run = sums[tid] - local;
    for (int i = start; i < end; ++i) { off[i] = run; run += cnt[i]; }
    if (tid == 0) off[N_NODES] = E_TOT;
}

__global__ void scatter_edges(const int* __restrict__ esrc, const int* __restrict__ edst,
                              int* __restrict__ cursor, int* __restrict__ csr_src,
                              int* __restrict__ csr_dst) {
    int i = blockIdx.x * blockDim.x + threadIdx.x;
    if (i >= E_TOT) return;
    int s, d;
    if (i < N_EDGES) { s = esrc[i]; d = edst[i]; }
    else             { s = i - N_EDGES; d = s; }
    int pos = atomicAdd(&cursor[d], 1);
    csr_src[pos] = s;
    csr_dst[pos] = d;
}

// ---------------- unified preprocessing ----------------
// WALL layout (ushort, zero-padded [Mpad][K]):
//  0      : 128x128 <- W1  (M=128,K=100)
//  16384  : 128x128 <- Wl1 (M=128,K=100)
//  32768  : 128x128 <- W2  (K=128)
//  49152  : 128x128 <- Wl2 (K=128)
//  65536  : 48x128  <- Wl3 (M=47,K=128)
//  71680  : 48x512  <- W3m (0.25*W3 head-concat: [c][h*128+k])
#define WALL_TOT 96256
#define PREP_TOT (WALL_TOT + N_NODES * 128 + 1024)

__global__ void prep(const float* __restrict__ W1, const float* __restrict__ Wl1,
                     const float* __restrict__ W2, const float* __restrict__ Wl2,
                     const float* __restrict__ W3, const float* __restrict__ Wl3,
                     const float* __restrict__ a3s, const float* __restrict__ a3d,
                     const float* __restrict__ x,
                     unsigned short* __restrict__ WALL, unsigned short* __restrict__ Xb,
                     float* __restrict__ VS, float* __restrict__ VD) {
    int i = blockIdx.x * blockDim.x + threadIdx.x;
    if (i < WALL_TOT) {
        float v;
        if (i < 65536) {
            const float* src; int base, M, K;
            if      (i < 16384) { src = W1;  base = 0;     M = 128; K = 100; }
            else if (i < 32768) { src = Wl1; base = 16384; M = 128; K = 100; }
            else if (i < 49152) { src = W2;  base = 32768; M = 128; K = 128; }
            else                { src = Wl2; base = 49152; M = 128; K = 128; }
            int local = i - base;
            int m = local >> 7, k = local & 127;
            v = (k < K) ? src[m * K + k] : 0.f;
        } else if (i < 71680) {
            int local = i - 65536;
            int m = local >> 7, k = local & 127;
            v = (m < 47) ? Wl3[m * 128 + k] : 0.f;
        } else {
            int local = i - 71680;
            int c = local >> 9, k512 = local & 511;
            int h = k512 >> 7, kk = k512 & 127;
            v = (c < 47) ? 0.25f * W3[(h * 47 + c) * 128 + kk] : 0.f;
        }
        WALL[i] = f2bbits(v);
    } else if (i < WALL_TOT + N_NODES * 128) {
        int j = i - WALL_TOT;
        int n = j >> 7, k = j & 127;
        float v = (k < 100) ? x[n * 100 + k] : 0.f;
        Xb[j] = f2bbits(v);
    } else if (i < PREP_TOT) {
        int k = i - (WALL_TOT + N_NODES * 128);
        int sd = k >> 9, h = (k >> 7) & 3, kk = k & 127;
        const float* att = sd ? a3d : a3s;
        float s = 0.f;
        for (int c = 0; c < 47; ++c) s += att[h * 47 + c] * W3[(h * 47 + c) * 128 + kk];
        (sd ? VD : VS)[h * 128 + kk] = s;
    }
}

// ---------------- fused bf16 MFMA GEMM + alpha epilogue (layers 1,2) ----------------
// A [N][128] bf16; Wh,Wl [128][128] bf16. Writes HFb bf16, LIN fp32(+bias),
// and ASRC/ADST[n*4+h] = sum_c HF[n,h*32+c]*att[h][c] (fp32-exact from acc).

__global__ __launch_bounds__(256) void gemm_dual_a(
        const unsigned short* __restrict__ A,
        const unsigned short* __restrict__ Wh, const unsigned short* __restrict__ Wl,
        const float* __restrict__ bl,
        const float* __restrict__ att_s, const float* __restrict__ att_d,  // [4][32]
        unsigned short* __restrict__ HFb, float* __restrict__ LIN,
        float* __restrict__ ASRC, float* __restrict__ ADST) {
    int wv = threadIdx.x >> 6, lane = threadIdx.x & 63;
    int rt = blockIdx.x * 4 + wv;
    if (rt >= NROWT) return;
    int l16 = lane & 15, kgrp = lane >> 4;
    const unsigned short* xrow = A + (size_t)(rt * 16 + l16) * 128 + kgrp * 8;
    short8 a[4];
    #pragma unroll
    for (int ks = 0; ks < 4; ++ks)
        a[ks] = *reinterpret_cast<const short8*>(xrow + ks * 32);
    int row0 = rt * 16 + kgrp * 4;
    float ps[4][4] = {}, pd[4][4] = {};
    #pragma unroll
    for (int ct = 0; ct < 16; ++ct) {
        const bool isH = (ct < 8);
        const unsigned short* W = isH ? Wh : Wl;
        int c = (isH ? ct : ct - 8) * 16 + l16;
        const unsigned short* wrow = W + (size_t)c * 128 + kgrp * 8;
        f32x4 acc = {0.f, 0.f, 0.f, 0.f};
        #pragma unroll
        for (int ks = 0; ks < 4; ++ks) {
            short8 b = *reinterpret_cast<const short8*>(wrow + ks * 32);
            acc = __builtin_amdgcn_mfma_f32_16x16x32_bf16(a[ks], b, acc, 0, 0, 0);
        }
        if (isH) {
            const int h = ct >> 1;
            float as = att_s[h * 32 + (ct & 1) * 16 + l16];
            float ad = att_d[h * 32 + (ct & 1) * 16 + l16];
            #pragma unroll
            for (int r = 0; r < 4; ++r) {
                ps[h][r] += acc[r] * as;
                pd[h][r] += acc[r] * ad;
                HFb[(size_t)(row0 + r) * 128 + c] = f2bbits(acc[r]);
            }
        } else {
            float bias = bl[c];
            #pragma unroll
            for (int r = 0; r < 4; ++r)
                LIN[(size_t)(row0 + r) * 128 + c] = acc[r] + bias;
        }
    }
    #pragma unroll
    for (int h = 0; h < 4; ++h)
        #pragma unroll
        for (int r = 0; r < 4; ++r) {
            #pragma unroll
            for (int d = 1; d < 16; d <<= 1) {
                ps[h][r] += __shfl_xor(ps[h][r], d);
                pd[h][r] += __shfl_xor(pd[h][r], d);
            }
        }
    if (l16 == 0) {
        #pragma unroll
        for (int r = 0; r < 4; ++r)
            #pragma unroll
            for (int h = 0; h < 4; ++h) {
                ASRC[(row0 + r) * 4 + h] = ps[h][r];
                ADST[(row0 + r) * 4 + h] = pd[h][r];
            }
    }
}

// ---------------- LIN3 GEMM: Bb[N][128] @ Wl3^T -> LIN3[N][47] (+bl3) ----------------

__global__ __launch_bounds__(256) void gemm_lin3(
        const unsigned short* __restrict__ A, const unsigned short* __restrict__ W,
        const float* __restrict__ bias, float* __restrict__ LIN3) {
    int wv = threadIdx.x >> 6, lane = threadIdx.x & 63;
    int rt = blockIdx.x * 4 + wv;
    if (rt >= NROWT) return;
    int l16 = lane & 15, kgrp = lane >> 4;
    const unsigned short* xrow = A + (size_t)(rt * 16 + l16) * 128 + kgrp * 8;
    short8 a[4];
    #pragma unroll
    for (int ks = 0; ks < 4; ++ks)
        a[ks] = *reinterpret_cast<const short8*>(xrow + ks * 32);
    int row0 = rt * 16 + kgrp * 4;
    #pragma unroll
    for (int ct = 0; ct < 3; ++ct) {
        int c = ct * 16 + l16;
        const unsigned short* wrow = W + (size_t)c * 128 + kgrp * 8;
        f32x4 acc = {0.f, 0.f, 0.f, 0.f};
        #pragma unroll
        for (int ks = 0; ks < 4; ++ks) {
            short8 b = *reinterpret_cast<const short8*>(wrow + ks * 32);
            acc = __builtin_amdgcn_mfma_f32_16x16x32_bf16(a[ks], b, acc, 0, 0, 0);
        }
        if (c < 47) {
            float bias_c = bias[c];
            #pragma unroll
            for (int r = 0; r < 4; ++r)
                LIN3[(size_t)(row0 + r) * 47 + c] = acc[r] + bias_c;
        }
    }
}

// ---------------- layer-3 attention logits from B (folded through W3) ----------------

__global__ void calc_alpha3(const uint2* __restrict__ B2,
                            const float* __restrict__ VS, const float* __restrict__ VD,
                            float* __restrict__ ASRC, float* __restrict__ ADST) {
    int t = blockIdx.x * blockDim.x + threadIdx.x;
    if (t >= N_NODES * HEADS) return;
    int n = t >> 2, h = t & 3;
    const uint2* row = B2 + (size_t)n * 32;
    const float4* vs = (const float4*)(VS + h * 128);
    const float4* vd = (const float4*)(VD + h * 128);
    float ss = 0.f, sd = 0.f;
    #pragma unroll 4
    for (int i = 0; i < 32; ++i) {
        uint2 u = row[i];
        float4 s4 = vs[i], d4 = vd[i];
        float f0 = bf_lo(u.x), f1 = bf_hi(u.x), f2 = bf_lo(u.y), f3 = bf_hi(u.y);
        ss += f0 * s4.x + f1 * s4.y + f2 * s4.z + f3 * s4.w;
        sd += f0 * d4.x + f1 * d4.y + f2 * d4.z + f3 * d4.w;
    }
    ASRC[t] = ss; ADST[t] = sd;
}

// ---------------- edge-centric exp weights ----------------

__global__ void edge_weights(const int* __restrict__ csr_src, const int* __restrict__ csr_dst,
                             const float* __restrict__ asrc, const float* __restrict__ adst,
                             float4* __restrict__ W4) {
    int e = blockIdx.x * blockDim.x + threadIdx.x;
    if (e >= E_TOT) return;
    int s = csr_src[e], d = csr_dst[e];
    float4 av = ((const float4*)asrc)[s];
    float4 dv = ((const float4*)adst)[d];
    float4 w;
    w.x = __expf(lrelu(av.x + dv.x));
    w.y = __expf(lrelu(av.y + dv.y));
    w.z = __expf(lrelu(av.z + dv.z));
    w.w = __expf(lrelu(av.w + dv.w));
    W4[e] = w;
}

// ---------------- aggregation layers 1-2 (unchanged structure) ----------------

__device__ __forceinline__ float sel4(float4 w, int h) {
    float r = w.x;
    r = (h == 1) ? w.y : r;
    r = (h == 2) ? w.z : r;
    r = (h == 3) ? w.w : r;
    return r;
}

__global__ __launch_bounds__(256) void agg12(
        const int* __restrict__ off, const int* __restrict__ csr_src,
        const uint2* __restrict__ HU2,   // bf16 HF: [N][32] uint2
        const float4* __restrict__ W4,
        const float* __restrict__ bias, const float* __restrict__ LIN,
        unsigned* __restrict__ OUTB) {
    int wv = threadIdx.x >> 6, lane = threadIdx.x & 63;
    int n = blockIdx.x * 4 + wv;
    int e0 = off[n], e1 = off[n + 1];
    int el = lane >> 5;
    int fl = lane & 31;
    int h = fl >> 3;
    float acc0 = 0.f, acc1 = 0.f, acc2 = 0.f, acc3 = 0.f, den = 0.f;
    int e = e0;
    for (; e + 4 <= e1; e += 4) {
        int sA = csr_src[e + el];
        int sB = csr_src[e + 2 + el];
        float4 wA4 = W4[e + el];
        float4 wB4 = W4[e + 2 + el];
        uint2 uA = HU2[(size_t)sA * 32 + fl];
        uint2 uB = HU2[(size_t)sB * 32 + fl];
        float wA = sel4(wA4, h), wB = sel4(wB4, h);
        den += wA + wB;
        acc0 += wA * bf_lo(uA.x) + wB * bf_lo(uB.x);
        acc1 += wA * bf_hi(uA.x) + wB * bf_hi(uB.x);
        acc2 += wA * bf_lo(uA.y) + wB * bf_lo(uB.y);
        acc3 += wA * bf_hi(uA.y) + wB * bf_hi(uB.y);
    }
    for (; e + 2 <= e1; e += 2) {
        int s = csr_src[e + el];
        float4 w4 = W4[e + el];
        uint2 u = HU2[(size_t)s * 32 + fl];
        float w = sel4(w4, h);
        den += w;
        acc0 += w * bf_lo(u.x);
        acc1 += w * bf_hi(u.x);
        acc2 += w * bf_lo(u.y);
        acc3 += w * bf_hi(u.y);
    }
    if (e + el < e1) {
        int s = csr_src[e + el];
        float4 w4 = W4[e + el];
        uint2 u = HU2[(size_t)s * 32 + fl];
        float w = sel4(w4, h);
        den += w;
        acc0 += w * bf_lo(u.x);
        acc1 += w * bf_hi(u.x);
        acc2 += w * bf_lo(u.y);
        acc3 += w * bf_hi(u.y);
    }
    acc0 += __shfl_xor(acc0, 32);
    acc1 += __shfl_xor(acc1, 32);
    acc2 += __shfl_xor(acc2, 32);
    acc3 += __shfl_xor(acc3, 32);
    den  += __shfl_xor(den, 32);
    float inv = 1.0f / (den + 1e-16f);
    int f0 = 4 * fl;
    size_t base = (size_t)n * 128;
    float4 lin = *reinterpret_cast<const float4*>(&LIN[base + f0]);
    float4 bs  = *reinterpret_cast<const float4*>(&bias[f0]);
    float o0 = fmaxf(acc0 * inv + bs.x + lin.x, 0.f);
    float o1 = fmaxf(acc1 * inv + bs.y + lin.y, 0.f);
    float o2 = fmaxf(acc2 * inv + bs.z + lin.z, 0.f);
    float o3 = fmaxf(acc3 * inv + bs.w + lin.w, 0.f);
    if (el == 0) {
        uint2 p;
        p.x = ((unsigned)f2bbits(o1) << 16) | f2bbits(o0);
        p.y = ((unsigned)f2bbits(o3) << 16) | f2bbits(o2);
        ((uint2*)OUTB)[(size_t)n * 32 + fl] = p;
    }
}

// ---------------- layer 3 folded aggregation: aggregate B per head ----------------
// AGG[n][h*64 + lane] = pack(bf16(acc_h[2*lane]*inv_h), bf16(acc_h[2*lane+1]*inv_h))

__global__ __launch_bounds__(256) void agg3f(
        const int* __restrict__ off, const int* __restrict__ csr_src,
        const unsigned* __restrict__ BU,   // [N][64] uints (128 bf16)
        const float4* __restrict__ W4,
        unsigned* __restrict__ AGG) {      // [N][256] uints
    int wv = threadIdx.x >> 6, lane = threadIdx.x & 63;
    int n = blockIdx.x * 4 + wv;
    int e0 = off[n], e1 = off[n + 1];
    float acc[4][2] = {};
    float den[4] = {};
    int e = e0;
    for (; e + 2 <= e1; e += 2) {
        int sA = csr_src[e], sB = csr_src[e + 1];
        float4 wA = W4[e], wB = W4[e + 1];
        unsigned uA = BU[(size_t)sA * 64 + lane];
        unsigned uB = BU[(size_t)sB * 64 + lane];
        float fA0 = bf_lo(uA), fA1 = bf_hi(uA);
        float fB0 = bf_lo(uB), fB1 = bf_hi(uB);
        den[0] += wA.x + wB.x; den[1] += wA.y + wB.y;
        den[2] += wA.z + wB.z; den[3] += wA.w + wB.w;
        acc[0][0] += wA.x * fA0 + wB.x * fB0;  acc[0][1] += wA.x * fA1 + wB.x * fB1;
        acc[1][0] += wA.y * fA0 + wB.y * fB0;  acc[1][1] += wA.y * fA1 + wB.y * fB1;
        acc[2][0] += wA.z * fA0 + wB.z * fB0;  acc[2][1] += wA.z * fA1 + wB.z * fB1;
        acc[3][0] += wA.w * fA0 + wB.w * fB0;  acc[3][1] += wA.w * fA1 + wB.w * fB1;
    }
    if (e < e1) {
        int s = csr_src[e];
        float4 w4 = W4[e];
        unsigned u = BU[(size_t)s * 64 + lane];
        float f0 = bf_lo(u), f1 = bf_hi(u);
        den[0] += w4.x; den[1] += w4.y; den[2] += w4.z; den[3] += w4.w;
        acc[0][0] += w4.x * f0;  acc[0][1] += w4.x * f1;
        acc[1][0] += w4.y * f0;  acc[1][1] += w4.y * f1;
        acc[2][0] += w4.z * f0;  acc[2][1] += w4.z * f1;
        acc[3][0] += w4.w * f0;  acc[3][1] += w4.w * f1;
    }
    size_t base = (size_t)n * 256 + lane;
    #pragma unroll
    for (int h = 0; h < 4; ++h) {
        float inv = 1.0f / (den[h] + 1e-16f);
        AGG[base + h * 64] =
            ((unsigned)f2bbits(acc[h][1] * inv) << 16) | f2bbits(acc[h][0] * inv);
    }
}

// ---------------- post GEMM (K=512, head-mean folded) + b3 + LIN3 + log_softmax ----

__global__ __launch_bounds__(256) void post_ls(
        const unsigned short* __restrict__ AGG, const unsigned short* __restrict__ W3m,
        const float* __restrict__ b3, const float* __restrict__ LIN3,
        float* __restrict__ OUT) {
    int wv = threadIdx.x >> 6, lane = threadIdx.x & 63;
    int rt = blockIdx.x * 4 + wv;
    if (rt >= NROWT) return;
    int l16 = lane & 15, kgrp = lane >> 4;
    const unsigned short* arow = AGG + (size_t)(rt * 16 + l16) * 512 + kgrp * 8;
    short8 a[16];
    #pragma unroll
    for (int ks = 0; ks < 16; ++ks)
        a[ks] = *reinterpret_cast<const short8*>(arow + ks * 32);
    f32x4 accs[3];
    #pragma unroll
    for (int ct = 0; ct < 3; ++ct) {
        int c = ct * 16 + l16;
        const unsigned short* wrow = W3m + (size_t)c * 512 + kgrp * 8;
        f32x4 acc = {0.f, 0.f, 0.f, 0.f};
        #pragma unroll
        for (int ks = 0; ks < 16; ++ks) {
            short8 b = *reinterpret_cast<const short8*>(wrow + ks * 32);
            acc = __builtin_amdgcn_mfma_f32_16x16x32_bf16(a[ks], b, acc, 0, 0, 0);
        }
        accs[ct] = acc;
    }
    int row0 = rt * 16 + kgrp * 4;
    int c0 = l16, c1 = 16 + l16, c2 = 32 + l16;
    bool v2 = (c2 < 47);
    float b0 = b3[c0], b1v = b3[c1], b2v = v2 ? b3[c2] : 0.f;
    #pragma unroll
    for (int r = 0; r < 4; ++r) {
        int row = row0 + r;
        const float* lrow = LIN3 + (size_t)row * 47;
        float z0 = accs[0][r] + b0 + lrow[c0];
        float z1 = accs[1][r] + b1v + lrow[c1];
        float z2 = v2 ? (accs[2][r] + b2v + lrow[c2]) : -INFINITY;
        float m = fmaxf(fmaxf(z0, z1), z2);
        #pragma unroll
        for (int d = 1; d < 16; d <<= 1) m = fmaxf(m, __shfl_xor(m, d));
        float s = __expf(z0 - m) + __expf(z1 - m) + (v2 ? __expf(z2 - m) : 0.f);
        #pragma unroll
        for (int d = 1; d < 16; d <<= 1) s += __shfl_xor(s, d);
        float ls = logf(s);
        float* orow = OUT + (size_t)row * 47;
        orow[c0] = z0 - m - ls;
        orow[c1] = z1 - m - ls;
        if (v2) orow[c2] = z2 - m - ls;
    }
}

// ---------------- launch ----------------

extern "C" void kernel_launch(void* const* d_in, const int* in_sizes, int n_in,
                              void* d_out, int out_size, void* d_ws, size_t ws_size,
                              hipStream_t stream) {
    const float* x   = (const float*)d_in[0];
    const int*   ei  = (const int*)d_in[1];
    const float* W1  = (const float*)d_in[2];
    const float* a1s = (const float*)d_in[3];
    const float* a1d = (const float*)d_in[4];
    const float* b1  = (const float*)d_in[5];
    const float* Wl1 = (const float*)d_in[6];
    const float* bl1 = (const float*)d_in[7];
    const float* W2  = (const float*)d_in[8];
    const float* a2s = (const float*)d_in[9];
    const float* a2d = (const float*)d_in[10];
    const float* b2  = (const float*)d_in[11];
    const float* Wl2 = (const float*)d_in[12];
    const float* bl2 = (const float*)d_in[13];
    const float* W3  = (const float*)d_in[14];
    const float* a3s = (const float*)d_in[15];
    const float* a3d = (const float*)d_in[16];
    const float* b3  = (const float*)d_in[17];
    const float* Wl3 = (const float*)d_in[18];
    const float* bl3 = (const float*)d_in[19];
    float* out = (float*)d_out;

    size_t cur = 0;
    char* wsb = (char*)d_ws;
    auto carve = [&](size_t bytes) -> void* {
        void* p = wsb + cur;
        cur += (bytes + 255) & ~(size_t)255;
        return p;
    };
    int*   cnt    = (int*)  carve((size_t)N_NODES * 4);
    int*   offs   = (int*)  carve((size_t)(N_NODES + 1) * 4);
    int*   cursor = (int*)  carve((size_t)N_NODES * 4);
    int*   csr    = (int*)  carve((size_t)E_TOT * 4);
    int*   csrd   = (int*)  carve((size_t)E_TOT * 4);
    unsigned short* WALL = (unsigned short*)carve((size_t)WALL_TOT * 2);
    // Xb, HFb, LIN12 are contiguous (each size multiple of 256B) and all dead
    // before agg3f runs -> AGG (N*512*2 = 51.2MB) aliases exactly this region.
    unsigned short* Xb   = (unsigned short*)carve((size_t)N_NODES * 128 * 2);
    unsigned short* HFb  = (unsigned short*)carve((size_t)N_NODES * 128 * 2);
    float* LIN12  = (float*)carve((size_t)N_NODES * 128 * 4);
    unsigned short* AGG  = Xb;   // alias
    unsigned short* Bb   = (unsigned short*)carve((size_t)N_NODES * 128 * 2);
    float* LIN3   = (float*)carve((size_t)N_NODES * 47 * 4);
    float* ASRC   = (float*)carve((size_t)N_NODES * 4 * 4);
    float* ADST   = (float*)carve((size_t)N_NODES * 4 * 4);
    float4* W4    = (float4*)carve((size_t)E_TOT * 16);
    float* VS     = (float*)carve((size_t)4 * 128 * 4);
    float* VD     = (float*)carve((size_t)4 * 128 * 4);

    unsigned short* Wb1h = WALL + 0;
    unsigned short* Wb1l = WALL + 16384;
    unsigned short* Wb2h = WALL + 32768;
    unsigned short* Wb2l = WALL + 49152;
    unsigned short* Wb3l = WALL + 65536;
    unsigned short* W3m  = WALL + 71680;

    const int* esrc = ei;
    const int* edst = ei + N_EDGES;

    prep<<<PREP_TOT / 256, 256, 0, stream>>>(W1, Wl1, W2, Wl2, W3, Wl3, a3s, a3d, x,
                                             WALL, Xb, VS, VD);

    hipMemsetAsync(cnt, 0, (size_t)N_NODES * 4, stream);
    int egrid = (E_TOT + 255) / 256;
    count_deg<<<egrid, 256, 0, stream>>>(edst, cnt);
    scan_block<<<1, 1024, 0, stream>>>(cnt, offs);
    hipMemcpyAsync(cursor, offs, (size_t)N_NODES * 4, hipMemcpyDeviceToDevice, stream);
    scatter_edges<<<egrid, 256, 0, stream>>>(esrc, edst, cursor, csr, csrd);

    int agrid = (N_NODES * HEADS + 255) / 256;
    int ngrid = N_NODES / 4;
    int ggrid = (NROWT + 3) / 4;   // 782

    // ---- layer 1 ----
    gemm_dual_a<<<ggrid, 256, 0, stream>>>(Xb, Wb1h, Wb1l, bl1, a1s, a1d, HFb, LIN12, ASRC, ADST);
    edge_weights<<<egrid, 256, 0, stream>>>(csr, csrd, ASRC, ADST, W4);
    agg12<<<ngrid, 256, 0, stream>>>(offs, csr, (const uint2*)HFb, W4, b1, LIN12, (unsigned*)Bb);
    // ---- layer 2 ----
    gemm_dual_a<<<ggrid, 256, 0, stream>>>(Bb, Wb2h, Wb2l, bl2, a2s, a2d, HFb, LIN12, ASRC, ADST);
    edge_weights<<<egrid, 256, 0, stream>>>(csr, csrd, ASRC, ADST, W4);
    agg12<<<ngrid, 256, 0, stream>>>(offs, csr, (const uint2*)HFb, W4, b2, LIN12, (unsigned*)Bb);
    // ---- layer 3 (W3 folded past aggregation) ----
    gemm_lin3<<<ggrid, 256, 0, stream>>>(Bb, Wb3l, bl3, LIN3);
    calc_alpha3<<<agrid, 256, 0, stream>>>((const uint2*)Bb, VS, VD, ASRC, ADST);
    edge_weights<<<egrid, 256, 0, stream>>>(csr, csrd, ASRC, ADST, W4);
    agg3f<<<ngrid, 256, 0, stream>>>(offs, csr, (const unsigned*)Bb, W4, (unsigned*)AGG);
    post_ls<<<ggrid, 256, 0, stream>>>(AGG, W3m, b3, LIN3, out);
}

// Round 7
// 439.119 us; speedup vs baseline: 2.2208x; 1.1610x over previous
//
#include <hip/hip_runtime.h>
#include <hip/hip_bf16.h>
#include <math.h>

#define N_NODES 50000
#define N_EDGES 800000
#define E_TOT   (N_EDGES + N_NODES)   // 850000
#define HEADS   4
#define NEG     0.2f
#define NROWT   3125                  // 50000/16 row-tiles
#define SCAN_NB 196                   // ceil(50000/256)

typedef __attribute__((ext_vector_type(8))) short short8;   // 8 bf16 (4 VGPRs)
typedef __attribute__((ext_vector_type(4))) float f32x4;

__device__ __forceinline__ float bf_lo(unsigned u) { return __uint_as_float(u << 16); }
__device__ __forceinline__ float bf_hi(unsigned u) { return __uint_as_float(u & 0xffff0000u); }
__device__ __forceinline__ unsigned short f2bbits(float f) {
    __hip_bfloat16 b = __float2bfloat16(f);
    return *reinterpret_cast<unsigned short*>(&b);
}
__device__ __forceinline__ float lrelu(float v) { return v > 0.f ? v : NEG * v; }

// ---------------- CSR build (dst-sorted) ----------------

__global__ void count_deg(const int* __restrict__ edst, int* __restrict__ cnt) {
    int i = blockIdx.x * blockDim.x + threadIdx.x;
    if (i >= E_TOT) return;
    int d = (i < N_EDGES) ? edst[i] : (i - N_EDGES);
    atomicAdd(&cnt[d], 1);
}

// 3-phase parallel exclusive scan of cnt[0..N) -> off[0..N], cursor[0..N)
__global__ void scan_part1(const int* __restrict__ cnt, int* __restrict__ partial) {
    __shared__ int red[256];
    int t = threadIdx.x;
    int i = blockIdx.x * 256 + t;
    int v = (i < N_NODES) ? cnt[i] : 0;
    red[t] = v;
    __syncthreads();
    #pragma unroll
    for (int s = 128; s; s >>= 1) {
        if (t < s) red[t] += red[t + s];
        __syncthreads();
    }
    if (t == 0) partial[blockIdx.x] = red[0];
}

__global__ void scan_part2(int* __restrict__ partial) {   // 1 block, 256 threads
    __shared__ int sums[256];
    int t = threadIdx.x;
    int v = (t < SCAN_NB) ? partial[t] : 0;
    sums[t] = v;
    __syncthreads();
    #pragma unroll
    for (int d = 1; d < 256; d <<= 1) {
        int add = (t >= d) ? sums[t - d] : 0;
        __syncthreads();
        sums[t] += add;
        __syncthreads();
    }
    if (t < SCAN_NB) partial[t] = sums[t] - v;   // exclusive
}

__global__ void scan_part3(const int* __restrict__ cnt, const int* __restrict__ partial,
                           int* __restrict__ off, int* __restrict__ cursor) {
    __shared__ int sums[256];
    int t = threadIdx.x;
    int i = blockIdx.x * 256 + t;
    int v = (i < N_NODES) ? cnt[i] : 0;
    sums[t] = v;
    __syncthreads();
    #pragma unroll
    for (int d = 1; d < 256; d <<= 1) {
        int add = (t >= d) ? sums[t - d] : 0;
        __syncthreads();
        sums[t] += add;
        __syncthreads();
    }
    int excl = sums[t] - v + partial[blockIdx.x];
    if (i < N_NODES) { off[i] = excl; cursor[i] = excl; }
    if (i == N_NODES - 1) off[N_NODES] = excl + v;   // == E_TOT
}

__global__ void scatter_edges(const int* __restrict__ esrc, const int* __restrict__ edst,
                              int* __restrict__ cursor, int* __restrict__ csr_src,
                              int* __restrict__ csr_dst) {
    int i = blockIdx.x * blockDim.x + threadIdx.x;
    if (i >= E_TOT) return;
    int s, d;
    if (i < N_EDGES) { s = esrc[i]; d = edst[i]; }
    else             { s = i - N_EDGES; d = s; }
    int pos = atomicAdd(&cursor[d], 1);
    csr_src[pos] = s;
    csr_dst[pos] = d;
}

// ---------------- unified preprocessing ----------------
// WALL layout (ushort, zero-padded [Mpad][K]):
//  0      : 128x128 <- W1  (M=128,K=100)
//  16384  : 128x128 <- Wl1 (M=128,K=100)
//  32768  : 128x128 <- W2  (K=128)
//  49152  : 128x128 <- Wl2 (K=128)
//  65536  : 48x128  <- Wl3 (M=47,K=128)
//  71680  : 48x512  <- W3m (0.25*W3 head-concat: [c][h*128+k])
#define WALL_TOT 96256
#define PREP_TOT (WALL_TOT + N_NODES * 128 + 1024)

__global__ void prep(const float* __restrict__ W1, const float* __restrict__ Wl1,
                     const float* __restrict__ W2, const float* __restrict__ Wl2,
                     const float* __restrict__ W3, const float* __restrict__ Wl3,
                     const float* __restrict__ a3s, const float* __restrict__ a3d,
                     const float* __restrict__ x,
                     unsigned short* __restrict__ WALL, unsigned short* __restrict__ Xb,
                     float* __restrict__ VS, float* __restrict__ VD) {
    int i = blockIdx.x * blockDim.x + threadIdx.x;
    if (i < WALL_TOT) {
        float v;
        if (i < 65536) {
            const float* src; int base, K;
            if      (i < 16384) { src = W1;  base = 0;     K = 100; }
            else if (i < 32768) { src = Wl1; base = 16384; K = 100; }
            else if (i < 49152) { src = W2;  base = 32768; K = 128; }
            else                { src = Wl2; base = 49152; K = 128; }
            int local = i - base;
            int m = local >> 7, k = local & 127;
            v = (k < K) ? src[m * K + k] : 0.f;
        } else if (i < 71680) {
            int local = i - 65536;
            int m = local >> 7, k = local & 127;
            v = (m < 47) ? Wl3[m * 128 + k] : 0.f;
        } else {
            int local = i - 71680;
            int c = local >> 9, k512 = local & 511;
            int h = k512 >> 7, kk = k512 & 127;
            v = (c < 47) ? 0.25f * W3[(h * 47 + c) * 128 + kk] : 0.f;
        }
        WALL[i] = f2bbits(v);
    } else if (i < WALL_TOT + N_NODES * 128) {
        int j = i - WALL_TOT;
        int n = j >> 7, k = j & 127;
        float v = (k < 100) ? x[n * 100 + k] : 0.f;
        Xb[j] = f2bbits(v);
    } else if (i < PREP_TOT) {
        int k = i - (WALL_TOT + N_NODES * 128);
        int sd = k >> 9, h = (k >> 7) & 3, kk = k & 127;
        const float* att = sd ? a3d : a3s;
        float s = 0.f;
        for (int c = 0; c < 47; ++c) s += att[h * 47 + c] * W3[(h * 47 + c) * 128 + kk];
        (sd ? VD : VS)[h * 128 + kk] = s;
    }
}

// ---------------- fused bf16 MFMA GEMM + alpha epilogue (layers 1,2) ----------------

__global__ __launch_bounds__(256) void gemm_dual_a(
        const unsigned short* __restrict__ A,
        const unsigned short* __restrict__ Wh, const unsigned short* __restrict__ Wl,
        const float* __restrict__ bl,
        const float* __restrict__ att_s, const float* __restrict__ att_d,  // [4][32]
        unsigned short* __restrict__ HFb, float* __restrict__ LIN,
        float* __restrict__ ASRC, float* __restrict__ ADST) {
    int wv = threadIdx.x >> 6, lane = threadIdx.x & 63;
    int rt = blockIdx.x * 4 + wv;
    if (rt >= NROWT) return;
    int l16 = lane & 15, kgrp = lane >> 4;
    const unsigned short* xrow = A + (size_t)(rt * 16 + l16) * 128 + kgrp * 8;
    short8 a[4];
    #pragma unroll
    for (int ks = 0; ks < 4; ++ks)
        a[ks] = *reinterpret_cast<const short8*>(xrow + ks * 32);
    int row0 = rt * 16 + kgrp * 4;
    float ps[4][4] = {}, pd[4][4] = {};
    #pragma unroll
    for (int ct = 0; ct < 16; ++ct) {
        const bool isH = (ct < 8);
        const unsigned short* W = isH ? Wh : Wl;
        int c = (isH ? ct : ct - 8) * 16 + l16;
        const unsigned short* wrow = W + (size_t)c * 128 + kgrp * 8;
        f32x4 acc = {0.f, 0.f, 0.f, 0.f};
        #pragma unroll
        for (int ks = 0; ks < 4; ++ks) {
            short8 b = *reinterpret_cast<const short8*>(wrow + ks * 32);
            acc = __builtin_amdgcn_mfma_f32_16x16x32_bf16(a[ks], b, acc, 0, 0, 0);
        }
        if (isH) {
            const int h = ct >> 1;
            float as = att_s[h * 32 + (ct & 1) * 16 + l16];
            float ad = att_d[h * 32 + (ct & 1) * 16 + l16];
            #pragma unroll
            for (int r = 0; r < 4; ++r) {
                ps[h][r] += acc[r] * as;
                pd[h][r] += acc[r] * ad;
                HFb[(size_t)(row0 + r) * 128 + c] = f2bbits(acc[r]);
            }
        } else {
            float bias = bl[c];
            #pragma unroll
            for (int r = 0; r < 4; ++r)
                LIN[(size_t)(row0 + r) * 128 + c] = acc[r] + bias;
        }
    }
    #pragma unroll
    for (int h = 0; h < 4; ++h)
        #pragma unroll
        for (int r = 0; r < 4; ++r) {
            #pragma unroll
            for (int d = 1; d < 16; d <<= 1) {
                ps[h][r] += __shfl_xor(ps[h][r], d);
                pd[h][r] += __shfl_xor(pd[h][r], d);
            }
        }
    if (l16 == 0) {
        #pragma unroll
        for (int r = 0; r < 4; ++r)
            #pragma unroll
            for (int h = 0; h < 4; ++h) {
                ASRC[(row0 + r) * 4 + h] = ps[h][r];
                ADST[(row0 + r) * 4 + h] = pd[h][r];
            }
    }
}

// ---------------- LIN3 GEMM: Bb[N][128] @ Wl3^T -> LIN3[N][47] (+bl3) ----------------

__global__ __launch_bounds__(256) void gemm_lin3(
        const unsigned short* __restrict__ A, const unsigned short* __restrict__ W,
        const float* __restrict__ bias, float* __restrict__ LIN3) {
    int wv = threadIdx.x >> 6, lane = threadIdx.x & 63;
    int rt = blockIdx.x * 4 + wv;
    if (rt >= NROWT) return;
    int l16 = lane & 15, kgrp = lane >> 4;
    const unsigned short* xrow = A + (size_t)(rt * 16 + l16) * 128 + kgrp * 8;
    short8 a[4];
    #pragma unroll
    for (int ks = 0; ks < 4; ++ks)
        a[ks] = *reinterpret_cast<const short8*>(xrow + ks * 32);
    int row0 = rt * 16 + kgrp * 4;
    #pragma unroll
    for (int ct = 0; ct < 3; ++ct) {
        int c = ct * 16 + l16;
        const unsigned short* wrow = W + (size_t)c * 128 + kgrp * 8;
        f32x4 acc = {0.f, 0.f, 0.f, 0.f};
        #pragma unroll
        for (int ks = 0; ks < 4; ++ks) {
            short8 b = *reinterpret_cast<const short8*>(wrow + ks * 32);
            acc = __builtin_amdgcn_mfma_f32_16x16x32_bf16(a[ks], b, acc, 0, 0, 0);
        }
        if (c < 47) {
            float bias_c = bias[c];
            #pragma unroll
            for (int r = 0; r < 4; ++r)
                LIN3[(size_t)(row0 + r) * 47 + c] = acc[r] + bias_c;
        }
    }
}

// ---------------- layer-3 attention logits from B (folded through W3) ----------------

__global__ void calc_alpha3(const uint2* __restrict__ B2,
                            const float* __restrict__ VS, const float* __restrict__ VD,
                            float* __restrict__ ASRC, float* __restrict__ ADST) {
    int t = blockIdx.x * blockDim.x + threadIdx.x;
    if (t >= N_NODES * HEADS) return;
    int n = t >> 2, h = t & 3;
    const uint2* row = B2 + (size_t)n * 32;
    const float4* vs = (const float4*)(VS + h * 128);
    const float4* vd = (const float4*)(VD + h * 128);
    float ss = 0.f, sd = 0.f;
    #pragma unroll 4
    for (int i = 0; i < 32; ++i) {
        uint2 u = row[i];
        float4 s4 = vs[i], d4 = vd[i];
        float f0 = bf_lo(u.x), f1 = bf_hi(u.x), f2 = bf_lo(u.y), f3 = bf_hi(u.y);
        ss += f0 * s4.x + f1 * s4.y + f2 * s4.z + f3 * s4.w;
        sd += f0 * d4.x + f1 * d4.y + f2 * d4.z + f3 * d4.w;
    }
    ASRC[t] = ss; ADST[t] = sd;
}

// ---------------- edge-centric exp weights ----------------

__global__ void edge_weights(const int* __restrict__ csr_src, const int* __restrict__ csr_dst,
                             const float* __restrict__ asrc, const float* __restrict__ adst,
                             float4* __restrict__ W4) {
    int e = blockIdx.x * blockDim.x + threadIdx.x;
    if (e >= E_TOT) return;
    int s = csr_src[e], d = csr_dst[e];
    float4 av = ((const float4*)asrc)[s];
    float4 dv = ((const float4*)adst)[d];
    float4 w;
    w.x = __expf(lrelu(av.x + dv.x));
    w.y = __expf(lrelu(av.y + dv.y));
    w.z = __expf(lrelu(av.z + dv.z));
    w.w = __expf(lrelu(av.w + dv.w));
    W4[e] = w;
}

// ---------------- aggregation layers 1-2 ----------------

__device__ __forceinline__ float sel4(float4 w, int h) {
    float r = w.x;
    r = (h == 1) ? w.y : r;
    r = (h == 2) ? w.z : r;
    r = (h == 3) ? w.w : r;
    return r;
}

__global__ __launch_bounds__(256) void agg12(
        const int* __restrict__ off, const int* __restrict__ csr_src,
        const uint2* __restrict__ HU2,   // bf16 HF: [N][32] uint2
        const float4* __restrict__ W4,
        const float* __restrict__ bias, const float* __restrict__ LIN,
        unsigned* __restrict__ OUTB) {
    int wv = threadIdx.x >> 6, lane = threadIdx.x & 63;
    int n = blockIdx.x * 4 + wv;
    int e0 = off[n], e1 = off[n + 1];
    int el = lane >> 5;
    int fl = lane & 31;
    int h = fl >> 3;
    float acc0 = 0.f, acc1 = 0.f, acc2 = 0.f, acc3 = 0.f, den = 0.f;
    int e = e0;
    for (; e + 4 <= e1; e += 4) {
        int sA = csr_src[e + el];
        int sB = csr_src[e + 2 + el];
        float4 wA4 = W4[e + el];
        float4 wB4 = W4[e + 2 + el];
        uint2 uA = HU2[(size_t)sA * 32 + fl];
        uint2 uB = HU2[(size_t)sB * 32 + fl];
        float wA = sel4(wA4, h), wB = sel4(wB4, h);
        den += wA + wB;
        acc0 += wA * bf_lo(uA.x) + wB * bf_lo(uB.x);
        acc1 += wA * bf_hi(uA.x) + wB * bf_hi(uB.x);
        acc2 += wA * bf_lo(uA.y) + wB * bf_lo(uB.y);
        acc3 += wA * bf_hi(uA.y) + wB * bf_hi(uB.y);
    }
    for (; e + 2 <= e1; e += 2) {
        int s = csr_src[e + el];
        float4 w4 = W4[e + el];
        uint2 u = HU2[(size_t)s * 32 + fl];
        float w = sel4(w4, h);
        den += w;
        acc0 += w * bf_lo(u.x);
        acc1 += w * bf_hi(u.x);
        acc2 += w * bf_lo(u.y);
        acc3 += w * bf_hi(u.y);
    }
    if (e + el < e1) {
        int s = csr_src[e + el];
        float4 w4 = W4[e + el];
        uint2 u = HU2[(size_t)s * 32 + fl];
        float w = sel4(w4, h);
        den += w;
        acc0 += w * bf_lo(u.x);
        acc1 += w * bf_hi(u.x);
        acc2 += w * bf_lo(u.y);
        acc3 += w * bf_hi(u.y);
    }
    acc0 += __shfl_xor(acc0, 32);
    acc1 += __shfl_xor(acc1, 32);
    acc2 += __shfl_xor(acc2, 32);
    acc3 += __shfl_xor(acc3, 32);
    den  += __shfl_xor(den, 32);
    float inv = 1.0f / (den + 1e-16f);
    int f0 = 4 * fl;
    size_t base = (size_t)n * 128;
    float4 lin = *reinterpret_cast<const float4*>(&LIN[base + f0]);
    float4 bs  = *reinterpret_cast<const float4*>(&bias[f0]);
    float o0 = fmaxf(acc0 * inv + bs.x + lin.x, 0.f);
    float o1 = fmaxf(acc1 * inv + bs.y + lin.y, 0.f);
    float o2 = fmaxf(acc2 * inv + bs.z + lin.z, 0.f);
    float o3 = fmaxf(acc3 * inv + bs.w + lin.w, 0.f);
    if (el == 0) {
        uint2 p;
        p.x = ((unsigned)f2bbits(o1) << 16) | f2bbits(o0);
        p.y = ((unsigned)f2bbits(o3) << 16) | f2bbits(o2);
        ((uint2*)OUTB)[(size_t)n * 32 + fl] = p;
    }
}

// ---------------- layer 3 folded aggregation: aggregate B per head ----------------

__global__ __launch_bounds__(256) void agg3f(
        const int* __restrict__ off, const int* __restrict__ csr_src,
        const unsigned* __restrict__ BU,   // [N][64] uints (128 bf16)
        const float4* __restrict__ W4,
        unsigned* __restrict__ AGG) {      // [N][256] uints
    int wv = threadIdx.x >> 6, lane = threadIdx.x & 63;
    int n = blockIdx.x * 4 + wv;
    int e0 = off[n], e1 = off[n + 1];
    float acc[4][2] = {};
    float den[4] = {};
    int e = e0;
    for (; e + 2 <= e1; e += 2) {
        int sA = csr_src[e], sB = csr_src[e + 1];
        float4 wA = W4[e], wB = W4[e + 1];
        unsigned uA = BU[(size_t)sA * 64 + lane];
        unsigned uB = BU[(size_t)sB * 64 + lane];
        float fA0 = bf_lo(uA), fA1 = bf_hi(uA);
        float fB0 = bf_lo(uB), fB1 = bf_hi(uB);
        den[0] += wA.x + wB.x; den[1] += wA.y + wB.y;
        den[2] += wA.z + wB.z; den[3] += wA.w + wB.w;
        acc[0][0] += wA.x * fA0 + wB.x * fB0;  acc[0][1] += wA.x * fA1 + wB.x * fB1;
        acc[1][0] += wA.y * fA0 + wB.y * fB0;  acc[1][1] += wA.y * fA1 + wB.y * fB1;
        acc[2][0] += wA.z * fA0 + wB.z * fB0;  acc[2][1] += wA.z * fA1 + wB.z * fB1;
        acc[3][0] += wA.w * fA0 + wB.w * fB0;  acc[3][1] += wA.w * fA1 + wB.w * fB1;
    }
    if (e < e1) {
        int s = csr_src[e];
        float4 w4 = W4[e];
        unsigned u = BU[(size_t)s * 64 + lane];
        float f0 = bf_lo(u), f1 = bf_hi(u);
        den[0] += w4.x; den[1] += w4.y; den[2] += w4.z; den[3] += w4.w;
        acc[0][0] += w4.x * f0;  acc[0][1] += w4.x * f1;
        acc[1][0] += w4.y * f0;  acc[1][1] += w4.y * f1;
        acc[2][0] += w4.z * f0;  acc[2][1] += w4.z * f1;
        acc[3][0] += w4.w * f0;  acc[3][1] += w4.w * f1;
    }
    size_t base = (size_t)n * 256 + lane;
    #pragma unroll
    for (int h = 0; h < 4; ++h) {
        float inv = 1.0f / (den[h] + 1e-16f);
        AGG[base + h * 64] =
            ((unsigned)f2bbits(acc[h][1] * inv) << 16) | f2bbits(acc[h][0] * inv);
    }
}

// ---------------- post GEMM (K=512, head-mean folded) + b3 + LIN3 + log_softmax ----

__global__ __launch_bounds__(256) void post_ls(
        const unsigned short* __restrict__ AGG, const unsigned short* __restrict__ W3m,
        const float* __restrict__ b3, const float* __restrict__ LIN3,
        float* __restrict__ OUT) {
    int wv = threadIdx.x >> 6, lane = threadIdx.x & 63;
    int rt = blockIdx.x * 4 + wv;
    if (rt >= NROWT) return;
    int l16 = lane & 15, kgrp = lane >> 4;
    const unsigned short* arow = AGG + (size_t)(rt * 16 + l16) * 512 + kgrp * 8;
    short8 a[16];
    #pragma unroll
    for (int ks = 0; ks < 16; ++ks)
        a[ks] = *reinterpret_cast<const short8*>(arow + ks * 32);
    f32x4 accs[3];
    #pragma unroll
    for (int ct = 0; ct < 3; ++ct) {
        int c = ct * 16 + l16;
        const unsigned short* wrow = W3m + (size_t)c * 512 + kgrp * 8;
        f32x4 acc = {0.f, 0.f, 0.f, 0.f};
        #pragma unroll
        for (int ks = 0; ks < 16; ++ks) {
            short8 b = *reinterpret_cast<const short8*>(wrow + ks * 32);
            acc = __builtin_amdgcn_mfma_f32_16x16x32_bf16(a[ks], b, acc, 0, 0, 0);
        }
        accs[ct] = acc;
    }
    int row0 = rt * 16 + kgrp * 4;
    int c0 = l16, c1 = 16 + l16, c2 = 32 + l16;
    bool v2 = (c2 < 47);
    float b0 = b3[c0], b1v = b3[c1], b2v = v2 ? b3[c2] : 0.f;
    #pragma unroll
    for (int r = 0; r < 4; ++r) {
        int row = row0 + r;
        const float* lrow = LIN3 + (size_t)row * 47;
        float z0 = accs[0][r] + b0 + lrow[c0];
        float z1 = accs[1][r] + b1v + lrow[c1];
        float z2 = v2 ? (accs[2][r] + b2v + lrow[c2]) : -INFINITY;
        float m = fmaxf(fmaxf(z0, z1), z2);
        #pragma unroll
        for (int d = 1; d < 16; d <<= 1) m = fmaxf(m, __shfl_xor(m, d));
        float s = __expf(z0 - m) + __expf(z1 - m) + (v2 ? __expf(z2 - m) : 0.f);
        #pragma unroll
        for (int d = 1; d < 16; d <<= 1) s += __shfl_xor(s, d);
        float ls = logf(s);
        float* orow = OUT + (size_t)row * 47;
        orow[c0] = z0 - m - ls;
        orow[c1] = z1 - m - ls;
        if (v2) orow[c2] = z2 - m - ls;
    }
}

// ---------------- launch ----------------

extern "C" void kernel_launch(void* const* d_in, const int* in_sizes, int n_in,
                              void* d_out, int out_size, void* d_ws, size_t ws_size,
                              hipStream_t stream) {
    const float* x   = (const float*)d_in[0];
    const int*   ei  = (const int*)d_in[1];
    const float* W1  = (const float*)d_in[2];
    const float* a1s = (const float*)d_in[3];
    const float* a1d = (const float*)d_in[4];
    const float* b1  = (const float*)d_in[5];
    const float* Wl1 = (const float*)d_in[6];
    const float* bl1 = (const float*)d_in[7];
    const float* W2  = (const float*)d_in[8];
    const float* a2s = (const float*)d_in[9];
    const float* a2d = (const float*)d_in[10];
    const float* b2  = (const float*)d_in[11];
    const float* Wl2 = (const float*)d_in[12];
    const float* bl2 = (const float*)d_in[13];
    const float* W3  = (const float*)d_in[14];
    const float* a3s = (const float*)d_in[15];
    const float* a3d = (const float*)d_in[16];
    const float* b3  = (const float*)d_in[17];
    const float* Wl3 = (const float*)d_in[18];
    const float* bl3 = (const float*)d_in[19];
    float* out = (float*)d_out;

    size_t cur = 0;
    char* wsb = (char*)d_ws;
    auto carve = [&](size_t bytes) -> void* {
        void* p = wsb + cur;
        cur += (bytes + 255) & ~(size_t)255;
        return p;
    };
    int*   cnt    = (int*)  carve((size_t)N_NODES * 4);
    int*   offs   = (int*)  carve((size_t)(N_NODES + 1) * 4);
    int*   cursor = (int*)  carve((size_t)N_NODES * 4);
    int*   part   = (int*)  carve((size_t)SCAN_NB * 4);
    int*   csr    = (int*)  carve((size_t)E_TOT * 4);
    int*   csrd   = (int*)  carve((size_t)E_TOT * 4);
    unsigned short* WALL = (unsigned short*)carve((size_t)WALL_TOT * 2);
    // Xb, HFb, LIN12 are contiguous and dead before agg3f -> AGG aliases them.
    unsigned short* Xb   = (unsigned short*)carve((size_t)N_NODES * 128 * 2);
    unsigned short* HFb  = (unsigned short*)carve((size_t)N_NODES * 128 * 2);
    float* LIN12  = (float*)carve((size_t)N_NODES * 128 * 4);
    unsigned short* AGG  = Xb;   // alias
    unsigned short* Bb   = (unsigned short*)carve((size_t)N_NODES * 128 * 2);
    float* LIN3   = (float*)carve((size_t)N_NODES * 47 * 4);
    float* ASRC   = (float*)carve((size_t)N_NODES * 4 * 4);
    float* ADST   = (float*)carve((size_t)N_NODES * 4 * 4);
    float4* W4    = (float4*)carve((size_t)E_TOT * 16);
    float* VS     = (float*)carve((size_t)4 * 128 * 4);
    float* VD     = (float*)carve((size_t)4 * 128 * 4);

    unsigned short* Wb1h = WALL + 0;
    unsigned short* Wb1l = WALL + 16384;
    unsigned short* Wb2h = WALL + 32768;
    unsigned short* Wb2l = WALL + 49152;
    unsigned short* Wb3l = WALL + 65536;
    unsigned short* W3m  = WALL + 71680;

    const int* esrc = ei;
    const int* edst = ei + N_EDGES;

    prep<<<PREP_TOT / 256, 256, 0, stream>>>(W1, Wl1, W2, Wl2, W3, Wl3, a3s, a3d, x,
                                             WALL, Xb, VS, VD);

    hipMemsetAsync(cnt, 0, (size_t)N_NODES * 4, stream);
    int egrid = (E_TOT + 255) / 256;
    count_deg<<<egrid, 256, 0, stream>>>(edst, cnt);
    scan_part1<<<SCAN_NB, 256, 0, stream>>>(cnt, part);
    scan_part2<<<1, 256, 0, stream>>>(part);
    scan_part3<<<SCAN_NB, 256, 0, stream>>>(cnt, part, offs, cursor);
    scatter_edges<<<egrid, 256, 0, stream>>>(esrc, edst, cursor, csr, csrd);

    int agrid = (N_NODES * HEADS + 255) / 256;
    int ngrid = N_NODES / 4;
    int ggrid = (NROWT + 3) / 4;   // 782

    // ---- layer 1 ----
    gemm_dual_a<<<ggrid, 256, 0, stream>>>(Xb, Wb1h, Wb1l, bl1, a1s, a1d, HFb, LIN12, ASRC, ADST);
    edge_weights<<<egrid, 256, 0, stream>>>(csr, csrd, ASRC, ADST, W4);
    agg12<<<ngrid, 256, 0, stream>>>(offs, csr, (const uint2*)HFb, W4, b1, LIN12, (unsigned*)Bb);
    // ---- layer 2 ----
    gemm_dual_a<<<ggrid, 256, 0, stream>>>(Bb, Wb2h, Wb2l, bl2, a2s, a2d, HFb, LIN12, ASRC, ADST);
    edge_weights<<<egrid, 256, 0, stream>>>(csr, csrd, ASRC, ADST, W4);
    agg12<<<ngrid, 256, 0, stream>>>(offs, csr, (const uint2*)HFb, W4, b2, LIN12, (unsigned*)Bb);
    // ---- layer 3 (W3 folded past aggregation) ----
    gemm_lin3<<<ggrid, 256, 0, stream>>>(Bb, Wb3l, bl3, LIN3);
    calc_alpha3<<<agrid, 256, 0, stream>>>((const uint2*)Bb, VS, VD, ASRC, ADST);
    edge_weights<<<egrid, 256, 0, stream>>>(csr, csrd, ASRC, ADST, W4);
    agg3f<<<ngrid, 256, 0, stream>>>(offs, csr, (const unsigned*)Bb, W4, (unsigned*)AGG);
    post_ls<<<ggrid, 256, 0, stream>>>(AGG, W3m, b3, LIN3, out);
}

// Round 8
// 398.046 us; speedup vs baseline: 2.4500x; 1.1032x over previous
//
#include <hip/hip_runtime.h>
#include <hip/hip_bf16.h>
#include <math.h>

#define N_NODES 50000
#define N_EDGES 800000
#define E_TOT   (N_EDGES + N_NODES)   // 850000
#define HEADS   4
#define NEG     0.2f
#define NROWT   3125                  // 50000/16 row-tiles
#define SCAN_NB 196                   // ceil(50000/256)

typedef __attribute__((ext_vector_type(8))) short short8;   // 8 bf16 (4 VGPRs)
typedef __attribute__((ext_vector_type(4))) float f32x4;

__device__ __forceinline__ float bf_lo(unsigned u) { return __uint_as_float(u << 16); }
__device__ __forceinline__ float bf_hi(unsigned u) { return __uint_as_float(u & 0xffff0000u); }
__device__ __forceinline__ unsigned short f2bbits(float f) {
    __hip_bfloat16 b = __float2bfloat16(f);
    return *reinterpret_cast<unsigned short*>(&b);
}
__device__ __forceinline__ float lrelu(float v) { return v > 0.f ? v : NEG * v; }
__device__ __forceinline__ float sel4(float4 w, int h) {
    float r = w.x;
    r = (h == 1) ? w.y : r;
    r = (h == 2) ? w.z : r;
    r = (h == 3) ? w.w : r;
    return r;
}

// ---------------- CSR build (dst-sorted) ----------------

__global__ void count_deg(const int* __restrict__ edst, int* __restrict__ cnt) {
    int i = blockIdx.x * blockDim.x + threadIdx.x;
    if (i >= E_TOT) return;
    int d = (i < N_EDGES) ? edst[i] : (i - N_EDGES);
    atomicAdd(&cnt[d], 1);
}

__global__ void scan_part1(const int* __restrict__ cnt, int* __restrict__ partial) {
    __shared__ int red[256];
    int t = threadIdx.x;
    int i = blockIdx.x * 256 + t;
    int v = (i < N_NODES) ? cnt[i] : 0;
    red[t] = v;
    __syncthreads();
    #pragma unroll
    for (int s = 128; s; s >>= 1) {
        if (t < s) red[t] += red[t + s];
        __syncthreads();
    }
    if (t == 0) partial[blockIdx.x] = red[0];
}

__global__ void scan_part2(int* __restrict__ partial) {   // 1 block, 256 threads
    __shared__ int sums[256];
    int t = threadIdx.x;
    int v = (t < SCAN_NB) ? partial[t] : 0;
    sums[t] = v;
    __syncthreads();
    #pragma unroll
    for (int d = 1; d < 256; d <<= 1) {
        int add = (t >= d) ? sums[t - d] : 0;
        __syncthreads();
        sums[t] += add;
        __syncthreads();
    }
    if (t < SCAN_NB) partial[t] = sums[t] - v;   // exclusive
}

__global__ void scan_part3(const int* __restrict__ cnt, const int* __restrict__ partial,
                           int* __restrict__ off, int* __restrict__ cursor) {
    __shared__ int sums[256];
    int t = threadIdx.x;
    int i = blockIdx.x * 256 + t;
    int v = (i < N_NODES) ? cnt[i] : 0;
    sums[t] = v;
    __syncthreads();
    #pragma unroll
    for (int d = 1; d < 256; d <<= 1) {
        int add = (t >= d) ? sums[t - d] : 0;
        __syncthreads();
        sums[t] += add;
        __syncthreads();
    }
    int excl = sums[t] - v + partial[blockIdx.x];
    if (i < N_NODES) { off[i] = excl; cursor[i] = excl; }
    if (i == N_NODES - 1) off[N_NODES] = excl + v;   // == E_TOT
}

__global__ void scatter_edges(const int* __restrict__ esrc, const int* __restrict__ edst,
                              int* __restrict__ cursor, int* __restrict__ csr_src,
                              int* __restrict__ csr_dst) {
    int i = blockIdx.x * blockDim.x + threadIdx.x;
    if (i >= E_TOT) return;
    int s, d;
    if (i < N_EDGES) { s = esrc[i]; d = edst[i]; }
    else             { s = i - N_EDGES; d = s; }
    int pos = atomicAdd(&cursor[d], 1);
    csr_src[pos] = s;
    csr_dst[pos] = d;
}

// ---------------- unified preprocessing ----------------
// WALL layout (ushort, zero-padded [Mpad][K]):
//  0      : 128x128 <- W1  (M=128,K=100)
//  16384  : 128x128 <- Wl1 (M=128,K=100)
//  32768  : 128x128 <- W2  (K=128)
//  49152  : 128x128 <- Wl2 (K=128)
//  65536  : 48x128  <- Wl3 (M=47,K=128)
//  71680  : 48x512  <- W3m (0.25*W3 head-concat: [c][h*128+k])
#define WALL_TOT 96256
#define PREP_TOT (WALL_TOT + N_NODES * 128 + 1024)

__global__ void prep(const float* __restrict__ W1, const float* __restrict__ Wl1,
                     const float* __restrict__ W2, const float* __restrict__ Wl2,
                     const float* __restrict__ W3, const float* __restrict__ Wl3,
                     const float* __restrict__ a3s, const float* __restrict__ a3d,
                     const float* __restrict__ x,
                     unsigned short* __restrict__ WALL, unsigned short* __restrict__ Xb,
                     float* __restrict__ VS, float* __restrict__ VD) {
    int i = blockIdx.x * blockDim.x + threadIdx.x;
    if (i < WALL_TOT) {
        float v;
        if (i < 65536) {
            const float* src; int base, K;
            if      (i < 16384) { src = W1;  base = 0;     K = 100; }
            else if (i < 32768) { src = Wl1; base = 16384; K = 100; }
            else if (i < 49152) { src = W2;  base = 32768; K = 128; }
            else                { src = Wl2; base = 49152; K = 128; }
            int local = i - base;
            int m = local >> 7, k = local & 127;
            v = (k < K) ? src[m * K + k] : 0.f;
        } else if (i < 71680) {
            int local = i - 65536;
            int m = local >> 7, k = local & 127;
            v = (m < 47) ? Wl3[m * 128 + k] : 0.f;
        } else {
            int local = i - 71680;
            int c = local >> 9, k512 = local & 511;
            int h = k512 >> 7, kk = k512 & 127;
            v = (c < 47) ? 0.25f * W3[(h * 47 + c) * 128 + kk] : 0.f;
        }
        WALL[i] = f2bbits(v);
    } else if (i < WALL_TOT + N_NODES * 128) {
        int j = i - WALL_TOT;
        int n = j >> 7, k = j & 127;
        float v = (k < 100) ? x[n * 100 + k] : 0.f;
        Xb[j] = f2bbits(v);
    } else if (i < PREP_TOT) {
        int k = i - (WALL_TOT + N_NODES * 128);
        int sd = k >> 9, h = (k >> 7) & 3, kk = k & 127;
        const float* att = sd ? a3d : a3s;
        float s = 0.f;
        for (int c = 0; c < 47; ++c) s += att[h * 47 + c] * W3[(h * 47 + c) * 128 + kk];
        (sd ? VD : VS)[h * 128 + kk] = s;
    }
}

// ---------------- fused bf16 MFMA GEMM + alpha epilogue (layers 1,2) ----------------

__global__ __launch_bounds__(256) void gemm_dual_a(
        const unsigned short* __restrict__ A,
        const unsigned short* __restrict__ Wh, const unsigned short* __restrict__ Wl,
        const float* __restrict__ bl,
        const float* __restrict__ att_s, const float* __restrict__ att_d,  // [4][32]
        unsigned short* __restrict__ HFb, float* __restrict__ LIN,
        float* __restrict__ ASRC, float* __restrict__ ADST) {
    int wv = threadIdx.x >> 6, lane = threadIdx.x & 63;
    int rt = blockIdx.x * 4 + wv;
    if (rt >= NROWT) return;
    int l16 = lane & 15, kgrp = lane >> 4;
    const unsigned short* xrow = A + (size_t)(rt * 16 + l16) * 128 + kgrp * 8;
    short8 a[4];
    #pragma unroll
    for (int ks = 0; ks < 4; ++ks)
        a[ks] = *reinterpret_cast<const short8*>(xrow + ks * 32);
    int row0 = rt * 16 + kgrp * 4;
    float ps[4][4] = {}, pd[4][4] = {};
    #pragma unroll
    for (int ct = 0; ct < 16; ++ct) {
        const bool isH = (ct < 8);
        const unsigned short* W = isH ? Wh : Wl;
        int c = (isH ? ct : ct - 8) * 16 + l16;
        const unsigned short* wrow = W + (size_t)c * 128 + kgrp * 8;
        f32x4 acc = {0.f, 0.f, 0.f, 0.f};
        #pragma unroll
        for (int ks = 0; ks < 4; ++ks) {
            short8 b = *reinterpret_cast<const short8*>(wrow + ks * 32);
            acc = __builtin_amdgcn_mfma_f32_16x16x32_bf16(a[ks], b, acc, 0, 0, 0);
        }
        if (isH) {
            const int h = ct >> 1;
            float as = att_s[h * 32 + (ct & 1) * 16 + l16];
            float ad = att_d[h * 32 + (ct & 1) * 16 + l16];
            #pragma unroll
            for (int r = 0; r < 4; ++r) {
                ps[h][r] += acc[r] * as;
                pd[h][r] += acc[r] * ad;
                HFb[(size_t)(row0 + r) * 128 + c] = f2bbits(acc[r]);
            }
        } else {
            float bias = bl[c];
            #pragma unroll
            for (int r = 0; r < 4; ++r)
                LIN[(size_t)(row0 + r) * 128 + c] = acc[r] + bias;
        }
    }
    #pragma unroll
    for (int h = 0; h < 4; ++h)
        #pragma unroll
        for (int r = 0; r < 4; ++r) {
            #pragma unroll
            for (int d = 1; d < 16; d <<= 1) {
                ps[h][r] += __shfl_xor(ps[h][r], d);
                pd[h][r] += __shfl_xor(pd[h][r], d);
            }
        }
    if (l16 == 0) {
        #pragma unroll
        for (int r = 0; r < 4; ++r)
            #pragma unroll
            for (int h = 0; h < 4; ++h) {
                ASRC[(row0 + r) * 4 + h] = ps[h][r];
                ADST[(row0 + r) * 4 + h] = pd[h][r];
            }
    }
}

// ---------------- edge-centric exp weights ----------------

__global__ void edge_weights(const int* __restrict__ csr_src, const int* __restrict__ csr_dst,
                             const float* __restrict__ asrc, const float* __restrict__ adst,
                             float4* __restrict__ W4) {
    int e = blockIdx.x * blockDim.x + threadIdx.x;
    if (e >= E_TOT) return;
    int s = csr_src[e], d = csr_dst[e];
    float4 av = ((const float4*)asrc)[s];
    float4 dv = ((const float4*)adst)[d];
    float4 w;
    w.x = __expf(lrelu(av.x + dv.x));
    w.y = __expf(lrelu(av.y + dv.y));
    w.z = __expf(lrelu(av.z + dv.z));
    w.w = __expf(lrelu(av.w + dv.w));
    W4[e] = w;
}

// ---------------- aggregation layers 1-2 (8-edge unroll; optional layer-3 alpha) ----

template<bool ALPHA3>
__global__ __launch_bounds__(256) void agg12(
        const int* __restrict__ off, const int* __restrict__ csr_src,
        const uint2* __restrict__ HU2,   // bf16 HF: [N][32] uint2
        const float4* __restrict__ W4,
        const float* __restrict__ bias, const float* __restrict__ LIN,
        unsigned* __restrict__ OUTB,
        const float4* __restrict__ VS4, const float4* __restrict__ VD4,
        float* __restrict__ ASRC, float* __restrict__ ADST) {
    int wv = threadIdx.x >> 6, lane = threadIdx.x & 63;
    int n = blockIdx.x * 4 + wv;
    int e0 = off[n], e1 = off[n + 1];
    int el = lane >> 5;
    int fl = lane & 31;
    int h = fl >> 3;
    float acc0 = 0.f, acc1 = 0.f, acc2 = 0.f, acc3 = 0.f, den = 0.f;
    int e = e0;
    for (; e + 8 <= e1; e += 8) {
        int sA = csr_src[e + el],     sB = csr_src[e + 2 + el];
        int sC = csr_src[e + 4 + el], sD = csr_src[e + 6 + el];
        float4 wA4 = W4[e + el],      wB4 = W4[e + 2 + el];
        float4 wC4 = W4[e + 4 + el],  wD4 = W4[e + 6 + el];
        uint2 uA = HU2[(size_t)sA * 32 + fl];
        uint2 uB = HU2[(size_t)sB * 32 + fl];
        uint2 uC = HU2[(size_t)sC * 32 + fl];
        uint2 uD = HU2[(size_t)sD * 32 + fl];
        float wA = sel4(wA4, h), wB = sel4(wB4, h);
        float wC = sel4(wC4, h), wD = sel4(wD4, h);
        den += (wA + wB) + (wC + wD);
        acc0 += wA * bf_lo(uA.x) + wB * bf_lo(uB.x) + wC * bf_lo(uC.x) + wD * bf_lo(uD.x);
        acc1 += wA * bf_hi(uA.x) + wB * bf_hi(uB.x) + wC * bf_hi(uC.x) + wD * bf_hi(uD.x);
        acc2 += wA * bf_lo(uA.y) + wB * bf_lo(uB.y) + wC * bf_lo(uC.y) + wD * bf_lo(uD.y);
        acc3 += wA * bf_hi(uA.y) + wB * bf_hi(uB.y) + wC * bf_hi(uC.y) + wD * bf_hi(uD.y);
    }
    for (; e + 2 <= e1; e += 2) {
        int s = csr_src[e + el];
        float4 w4 = W4[e + el];
        uint2 u = HU2[(size_t)s * 32 + fl];
        float w = sel4(w4, h);
        den += w;
        acc0 += w * bf_lo(u.x);
        acc1 += w * bf_hi(u.x);
        acc2 += w * bf_lo(u.y);
        acc3 += w * bf_hi(u.y);
    }
    if (e + el < e1) {
        int s = csr_src[e + el];
        float4 w4 = W4[e + el];
        uint2 u = HU2[(size_t)s * 32 + fl];
        float w = sel4(w4, h);
        den += w;
        acc0 += w * bf_lo(u.x);
        acc1 += w * bf_hi(u.x);
        acc2 += w * bf_lo(u.y);
        acc3 += w * bf_hi(u.y);
    }
    acc0 += __shfl_xor(acc0, 32);
    acc1 += __shfl_xor(acc1, 32);
    acc2 += __shfl_xor(acc2, 32);
    acc3 += __shfl_xor(acc3, 32);
    den  += __shfl_xor(den, 32);
    float inv = 1.0f / (den + 1e-16f);
    int f0 = 4 * fl;
    size_t base = (size_t)n * 128;
    float4 lin = *reinterpret_cast<const float4*>(&LIN[base + f0]);
    float4 bs  = *reinterpret_cast<const float4*>(&bias[f0]);
    float o0 = fmaxf(acc0 * inv + bs.x + lin.x, 0.f);
    float o1 = fmaxf(acc1 * inv + bs.y + lin.y, 0.f);
    float o2 = fmaxf(acc2 * inv + bs.z + lin.z, 0.f);
    float o3 = fmaxf(acc3 * inv + bs.w + lin.w, 0.f);
    if (el == 0) {
        uint2 p;
        p.x = ((unsigned)f2bbits(o1) << 16) | f2bbits(o0);
        p.y = ((unsigned)f2bbits(o3) << 16) | f2bbits(o2);
        ((uint2*)OUTB)[(size_t)n * 32 + fl] = p;
    }
    if (ALPHA3) {
        // layer-3 logits: ss[h] = sum_f o_f * VS[h][f]  (both halves identical)
        float ss[4], sd[4];
        #pragma unroll
        for (int hh = 0; hh < 4; ++hh) {
            float4 vs = VS4[hh * 32 + fl];
            float4 vd = VD4[hh * 32 + fl];
            ss[hh] = o0 * vs.x + o1 * vs.y + o2 * vs.z + o3 * vs.w;
            sd[hh] = o0 * vd.x + o1 * vd.y + o2 * vd.z + o3 * vd.w;
        }
        #pragma unroll
        for (int d2 = 1; d2 < 32; d2 <<= 1)
            #pragma unroll
            for (int hh = 0; hh < 4; ++hh) {
                ss[hh] += __shfl_xor(ss[hh], d2);
                sd[hh] += __shfl_xor(sd[hh], d2);
            }
        if (lane == 0) {
            #pragma unroll
            for (int hh = 0; hh < 4; ++hh) {
                ASRC[n * 4 + hh] = ss[hh];
                ADST[n * 4 + hh] = sd[hh];
            }
        }
    }
}

// ---------------- layer 3 folded aggregation (4-edge unroll) ----------------

__global__ __launch_bounds__(256) void agg3f(
        const int* __restrict__ off, const int* __restrict__ csr_src,
        const unsigned* __restrict__ BU,   // [N][64] uints (128 bf16)
        const float4* __restrict__ W4,
        unsigned* __restrict__ AGG) {      // [N][256] uints
    int wv = threadIdx.x >> 6, lane = threadIdx.x & 63;
    int n = blockIdx.x * 4 + wv;
    int e0 = off[n], e1 = off[n + 1];
    float acc[4][2] = {};
    float den[4] = {};
    int e = e0;
    for (; e + 4 <= e1; e += 4) {
        int sA = csr_src[e],     sB = csr_src[e + 1];
        int sC = csr_src[e + 2], sD = csr_src[e + 3];
        float4 wA = W4[e],     wB = W4[e + 1];
        float4 wC = W4[e + 2], wD = W4[e + 3];
        unsigned uA = BU[(size_t)sA * 64 + lane];
        unsigned uB = BU[(size_t)sB * 64 + lane];
        unsigned uC = BU[(size_t)sC * 64 + lane];
        unsigned uD = BU[(size_t)sD * 64 + lane];
        float fA0 = bf_lo(uA), fA1 = bf_hi(uA);
        float fB0 = bf_lo(uB), fB1 = bf_hi(uB);
        float fC0 = bf_lo(uC), fC1 = bf_hi(uC);
        float fD0 = bf_lo(uD), fD1 = bf_hi(uD);
        den[0] += (wA.x + wB.x) + (wC.x + wD.x);
        den[1] += (wA.y + wB.y) + (wC.y + wD.y);
        den[2] += (wA.z + wB.z) + (wC.z + wD.z);
        den[3] += (wA.w + wB.w) + (wC.w + wD.w);
        acc[0][0] += wA.x * fA0 + wB.x * fB0 + wC.x * fC0 + wD.x * fD0;
        acc[0][1] += wA.x * fA1 + wB.x * fB1 + wC.x * fC1 + wD.x * fD1;
        acc[1][0] += wA.y * fA0 + wB.y * fB0 + wC.y * fC0 + wD.y * fD0;
        acc[1][1] += wA.y * fA1 + wB.y * fB1 + wC.y * fC1 + wD.y * fD1;
        acc[2][0] += wA.z * fA0 + wB.z * fB0 + wC.z * fC0 + wD.z * fD0;
        acc[2][1] += wA.z * fA1 + wB.z * fB1 + wC.z * fC1 + wD.z * fD1;
        acc[3][0] += wA.w * fA0 + wB.w * fB0 + wC.w * fC0 + wD.w * fD0;
        acc[3][1] += wA.w * fA1 + wB.w * fB1 + wC.w * fC1 + wD.w * fD1;
    }
    for (; e < e1; ++e) {
        int s = csr_src[e];
        float4 w4 = W4[e];
        unsigned u = BU[(size_t)s * 64 + lane];
        float f0 = bf_lo(u), f1 = bf_hi(u);
        den[0] += w4.x; den[1] += w4.y; den[2] += w4.z; den[3] += w4.w;
        acc[0][0] += w4.x * f0;  acc[0][1] += w4.x * f1;
        acc[1][0] += w4.y * f0;  acc[1][1] += w4.y * f1;
        acc[2][0] += w4.z * f0;  acc[2][1] += w4.z * f1;
        acc[3][0] += w4.w * f0;  acc[3][1] += w4.w * f1;
    }
    size_t base = (size_t)n * 256 + lane;
    #pragma unroll
    for (int h = 0; h < 4; ++h) {
        float inv = 1.0f / (den[h] + 1e-16f);
        AGG[base + h * 64] =
            ((unsigned)f2bbits(acc[h][1] * inv) << 16) | f2bbits(acc[h][0] * inv);
    }
}

// ---------------- post: AGG@W3m (K=512) + Bb@Wl3 (K=128) + b3 + bl3 + log_softmax

__global__ __launch_bounds__(256) void post_ls(
        const unsigned short* __restrict__ AGG, const unsigned short* __restrict__ Bb,
        const unsigned short* __restrict__ W3m, const unsigned short* __restrict__ Wl3b,
        const float* __restrict__ b3, const float* __restrict__ bl3,
        float* __restrict__ OUT) {
    int wv = threadIdx.x >> 6, lane = threadIdx.x & 63;
    int rt = blockIdx.x * 4 + wv;
    if (rt >= NROWT) return;
    int l16 = lane & 15, kgrp = lane >> 4;
    const unsigned short* arow = AGG + (size_t)(rt * 16 + l16) * 512 + kgrp * 8;
    short8 a[16];
    #pragma unroll
    for (int ks = 0; ks < 16; ++ks)
        a[ks] = *reinterpret_cast<const short8*>(arow + ks * 32);
    const unsigned short* brow = Bb + (size_t)(rt * 16 + l16) * 128 + kgrp * 8;
    short8 al[4];
    #pragma unroll
    for (int ks = 0; ks < 4; ++ks)
        al[ks] = *reinterpret_cast<const short8*>(brow + ks * 32);
    f32x4 accs[3];
    #pragma unroll
    for (int ct = 0; ct < 3; ++ct) {
        int c = ct * 16 + l16;
        const unsigned short* wrow = W3m + (size_t)c * 512 + kgrp * 8;
        const unsigned short* lrow = Wl3b + (size_t)c * 128 + kgrp * 8;
        f32x4 acc = {0.f, 0.f, 0.f, 0.f};
        #pragma unroll
        for (int ks = 0; ks < 16; ++ks) {
            short8 b = *reinterpret_cast<const short8*>(wrow + ks * 32);
            acc = __builtin_amdgcn_mfma_f32_16x16x32_bf16(a[ks], b, acc, 0, 0, 0);
        }
        #pragma unroll
        for (int ks = 0; ks < 4; ++ks) {
            short8 b = *reinterpret_cast<const short8*>(lrow + ks * 32);
            acc = __builtin_amdgcn_mfma_f32_16x16x32_bf16(al[ks], b, acc, 0, 0, 0);
        }
        accs[ct] = acc;
    }
    int row0 = rt * 16 + kgrp * 4;
    int c0 = l16, c1 = 16 + l16, c2 = 32 + l16;
    bool v2 = (c2 < 47);
    float b0 = b3[c0] + bl3[c0];
    float b1v = b3[c1] + bl3[c1];
    float b2v = v2 ? (b3[c2] + bl3[c2]) : 0.f;
    #pragma unroll
    for (int r = 0; r < 4; ++r) {
        int row = row0 + r;
        float z0 = accs[0][r] + b0;
        float z1 = accs[1][r] + b1v;
        float z2 = v2 ? (accs[2][r] + b2v) : -INFINITY;
        float m = fmaxf(fmaxf(z0, z1), z2);
        #pragma unroll
        for (int d = 1; d < 16; d <<= 1) m = fmaxf(m, __shfl_xor(m, d));
        float s = __expf(z0 - m) + __expf(z1 - m) + (v2 ? __expf(z2 - m) : 0.f);
        #pragma unroll
        for (int d = 1; d < 16; d <<= 1) s += __shfl_xor(s, d);
        float ls = logf(s);
        float* orow = OUT + (size_t)row * 47;
        orow[c0] = z0 - m - ls;
        orow[c1] = z1 - m - ls;
        if (v2) orow[c2] = z2 - m - ls;
    }
}

// ---------------- launch ----------------

extern "C" void kernel_launch(void* const* d_in, const int* in_sizes, int n_in,
                              void* d_out, int out_size, void* d_ws, size_t ws_size,
                              hipStream_t stream) {
    const float* x   = (const float*)d_in[0];
    const int*   ei  = (const int*)d_in[1];
    const float* W1  = (const float*)d_in[2];
    const float* a1s = (const float*)d_in[3];
    const float* a1d = (const float*)d_in[4];
    const float* b1  = (const float*)d_in[5];
    const float* Wl1 = (const float*)d_in[6];
    const float* bl1 = (const float*)d_in[7];
    const float* W2  = (const float*)d_in[8];
    const float* a2s = (const float*)d_in[9];
    const float* a2d = (const float*)d_in[10];
    const float* b2  = (const float*)d_in[11];
    const float* Wl2 = (const float*)d_in[12];
    const float* bl2 = (const float*)d_in[13];
    const float* W3  = (const float*)d_in[14];
    const float* a3s = (const float*)d_in[15];
    const float* a3d = (const float*)d_in[16];
    const float* b3  = (const float*)d_in[17];
    const float* Wl3 = (const float*)d_in[18];
    const float* bl3 = (const float*)d_in[19];
    float* out = (float*)d_out;

    size_t cur = 0;
    char* wsb = (char*)d_ws;
    auto carve = [&](size_t bytes) -> void* {
        void* p = wsb + cur;
        cur += (bytes + 255) & ~(size_t)255;
        return p;
    };
    int*   cnt    = (int*)  carve((size_t)N_NODES * 4);
    int*   offs   = (int*)  carve((size_t)(N_NODES + 1) * 4);
    int*   cursor = (int*)  carve((size_t)N_NODES * 4);
    int*   part   = (int*)  carve((size_t)SCAN_NB * 4);
    int*   csr    = (int*)  carve((size_t)E_TOT * 4);
    int*   csrd   = (int*)  carve((size_t)E_TOT * 4);
    unsigned short* WALL = (unsigned short*)carve((size_t)WALL_TOT * 2);
    // Xb, HFb, LIN12 contiguous and dead before agg3f -> AGG aliases them.
    unsigned short* Xb   = (unsigned short*)carve((size_t)N_NODES * 128 * 2);
    unsigned short* HFb  = (unsigned short*)carve((size_t)N_NODES * 128 * 2);
    float* LIN12  = (float*)carve((size_t)N_NODES * 128 * 4);
    unsigned short* AGG  = Xb;   // alias
    unsigned short* Bb   = (unsigned short*)carve((size_t)N_NODES * 128 * 2);
    float* ASRC   = (float*)carve((size_t)N_NODES * 4 * 4);
    float* ADST   = (float*)carve((size_t)N_NODES * 4 * 4);
    float4* W4    = (float4*)carve((size_t)E_TOT * 16);
    float* VS     = (float*)carve((size_t)4 * 128 * 4);
    float* VD     = (float*)carve((size_t)4 * 128 * 4);

    unsigned short* Wb1h = WALL + 0;
    unsigned short* Wb1l = WALL + 16384;
    unsigned short* Wb2h = WALL + 32768;
    unsigned short* Wb2l = WALL + 49152;
    unsigned short* Wb3l = WALL + 65536;
    unsigned short* W3m  = WALL + 71680;

    const int* esrc = ei;
    const int* edst = ei + N_EDGES;

    prep<<<PREP_TOT / 256, 256, 0, stream>>>(W1, Wl1, W2, Wl2, W3, Wl3, a3s, a3d, x,
                                             WALL, Xb, VS, VD);

    hipMemsetAsync(cnt, 0, (size_t)N_NODES * 4, stream);
    int egrid = (E_TOT + 255) / 256;
    count_deg<<<egrid, 256, 0, stream>>>(edst, cnt);
    scan_part1<<<SCAN_NB, 256, 0, stream>>>(cnt, part);
    scan_part2<<<1, 256, 0, stream>>>(part);
    scan_part3<<<SCAN_NB, 256, 0, stream>>>(cnt, part, offs, cursor);
    scatter_edges<<<egrid, 256, 0, stream>>>(esrc, edst, cursor, csr, csrd);

    int ngrid = N_NODES / 4;
    int ggrid = (NROWT + 3) / 4;   // 782

    // ---- layer 1 ----
    gemm_dual_a<<<ggrid, 256, 0, stream>>>(Xb, Wb1h, Wb1l, bl1, a1s, a1d, HFb, LIN12, ASRC, ADST);
    edge_weights<<<egrid, 256, 0, stream>>>(csr, csrd, ASRC, ADST, W4);
    agg12<false><<<ngrid, 256, 0, stream>>>(offs, csr, (const uint2*)HFb, W4, b1, LIN12,
                                            (unsigned*)Bb, nullptr, nullptr, nullptr, nullptr);
    // ---- layer 2 (epilogue computes layer-3 logits from fp32 outputs) ----
    gemm_dual_a<<<ggrid, 256, 0, stream>>>(Bb, Wb2h, Wb2l, bl2, a2s, a2d, HFb, LIN12, ASRC, ADST);
    edge_weights<<<egrid, 256, 0, stream>>>(csr, csrd, ASRC, ADST, W4);
    agg12<true><<<ngrid, 256, 0, stream>>>(offs, csr, (const uint2*)HFb, W4, b2, LIN12,
                                           (unsigned*)Bb, (const float4*)VS, (const float4*)VD,
                                           ASRC, ADST);
    // ---- layer 3 (W3 folded past aggregation; LIN3 fused into post) ----
    edge_weights<<<egrid, 256, 0, stream>>>(csr, csrd, ASRC, ADST, W4);
    agg3f<<<ngrid, 256, 0, stream>>>(offs, csr, (const unsigned*)Bb, W4, (unsigned*)AGG);
    post_ls<<<ggrid, 256, 0, stream>>>(AGG, Bb, W3m, Wb3l, b3, bl3, out);
}

// Round 9
// 388.178 us; speedup vs baseline: 2.5123x; 1.0254x over previous
//
#include <hip/hip_runtime.h>
#include <hip/hip_bf16.h>
#include <math.h>

#define N_NODES 50000
#define N_EDGES 800000
#define E_TOT   (N_EDGES + N_NODES)   // 850000
#define HEADS   4
#define NEG     0.2f
#define NROWT   3125                  // 50000/16 row-tiles
#define SCAN_NB 196                   // ceil(50000/256)

typedef __attribute__((ext_vector_type(8))) short short8;   // 8 bf16 (4 VGPRs)
typedef __attribute__((ext_vector_type(4))) float f32x4;

__device__ __forceinline__ float bf_lo(unsigned u) { return __uint_as_float(u << 16); }
__device__ __forceinline__ float bf_hi(unsigned u) { return __uint_as_float(u & 0xffff0000u); }
__device__ __forceinline__ unsigned short f2bbits(float f) {
    __hip_bfloat16 b = __float2bfloat16(f);
    return *reinterpret_cast<unsigned short*>(&b);
}
__device__ __forceinline__ float lrelu(float v) { return v > 0.f ? v : NEG * v; }

// ---------------- CSR build (dst-sorted) ----------------

__global__ void count_deg(const int* __restrict__ edst, int* __restrict__ cnt) {
    int i = blockIdx.x * blockDim.x + threadIdx.x;
    if (i >= E_TOT) return;
    int d = (i < N_EDGES) ? edst[i] : (i - N_EDGES);
    atomicAdd(&cnt[d], 1);
}

__global__ void scan_part1(const int* __restrict__ cnt, int* __restrict__ partial) {
    __shared__ int red[256];
    int t = threadIdx.x;
    int i = blockIdx.x * 256 + t;
    int v = (i < N_NODES) ? cnt[i] : 0;
    red[t] = v;
    __syncthreads();
    #pragma unroll
    for (int s = 128; s; s >>= 1) {
        if (t < s) red[t] += red[t + s];
        __syncthreads();
    }
    if (t == 0) partial[blockIdx.x] = red[0];
}

__global__ void scan_part2(int* __restrict__ partial) {   // 1 block, 256 threads
    __shared__ int sums[256];
    int t = threadIdx.x;
    int v = (t < SCAN_NB) ? partial[t] : 0;
    sums[t] = v;
    __syncthreads();
    #pragma unroll
    for (int d = 1; d < 256; d <<= 1) {
        int add = (t >= d) ? sums[t - d] : 0;
        __syncthreads();
        sums[t] += add;
        __syncthreads();
    }
    if (t < SCAN_NB) partial[t] = sums[t] - v;   // exclusive
}

__global__ void scan_part3(const int* __restrict__ cnt, const int* __restrict__ partial,
                           int* __restrict__ off, int* __restrict__ cursor) {
    __shared__ int sums[256];
    int t = threadIdx.x;
    int i = blockIdx.x * 256 + t;
    int v = (i < N_NODES) ? cnt[i] : 0;
    sums[t] = v;
    __syncthreads();
    #pragma unroll
    for (int d = 1; d < 256; d <<= 1) {
        int add = (t >= d) ? sums[t - d] : 0;
        __syncthreads();
        sums[t] += add;
        __syncthreads();
    }
    int excl = sums[t] - v + partial[blockIdx.x];
    if (i < N_NODES) { off[i] = excl; cursor[i] = excl; }
    if (i == N_NODES - 1) off[N_NODES] = excl + v;   // == E_TOT
}

__global__ void scatter_edges(const int* __restrict__ esrc, const int* __restrict__ edst,
                              int* __restrict__ cursor, int* __restrict__ csr_src,
                              int* __restrict__ csr_dst) {
    int i = blockIdx.x * blockDim.x + threadIdx.x;
    if (i >= E_TOT) return;
    int s, d;
    if (i < N_EDGES) { s = esrc[i]; d = edst[i]; }
    else             { s = i - N_EDGES; d = s; }
    int pos = atomicAdd(&cursor[d], 1);
    csr_src[pos] = s;
    csr_dst[pos] = d;
}

// ---------------- unified preprocessing ----------------
// WALL layout (ushort, zero-padded [Mpad][K]):
//  0      : 128x128 <- W1  (M=128,K=100)
//  16384  : 128x128 <- Wl1 (M=128,K=100)
//  32768  : 128x128 <- W2  (K=128)
//  49152  : 128x128 <- Wl2 (K=128)
//  65536  : 48x128  <- Wl3 (M=47,K=128)
//  71680  : 48x512  <- W3m (0.25*W3 head-concat: [c][h*128+k])
#define WALL_TOT 96256
#define PREP_TOT (WALL_TOT + N_NODES * 128 + 1024)

__global__ void prep(const float* __restrict__ W1, const float* __restrict__ Wl1,
                     const float* __restrict__ W2, const float* __restrict__ Wl2,
                     const float* __restrict__ W3, const float* __restrict__ Wl3,
                     const float* __restrict__ a3s, const float* __restrict__ a3d,
                     const float* __restrict__ x,
                     unsigned short* __restrict__ WALL, unsigned short* __restrict__ Xb,
                     float* __restrict__ VS, float* __restrict__ VD) {
    int i = blockIdx.x * blockDim.x + threadIdx.x;
    if (i < WALL_TOT) {
        float v;
        if (i < 65536) {
            const float* src; int base, K;
            if      (i < 16384) { src = W1;  base = 0;     K = 100; }
            else if (i < 32768) { src = Wl1; base = 16384; K = 100; }
            else if (i < 49152) { src = W2;  base = 32768; K = 128; }
            else                { src = Wl2; base = 49152; K = 128; }
            int local = i - base;
            int m = local >> 7, k = local & 127;
            v = (k < K) ? src[m * K + k] : 0.f;
        } else if (i < 71680) {
            int local = i - 65536;
            int m = local >> 7, k = local & 127;
            v = (m < 47) ? Wl3[m * 128 + k] : 0.f;
        } else {
            int local = i - 71680;
            int c = local >> 9, k512 = local & 511;
            int h = k512 >> 7, kk = k512 & 127;
            v = (c < 47) ? 0.25f * W3[(h * 47 + c) * 128 + kk] : 0.f;
        }
        WALL[i] = f2bbits(v);
    } else if (i < WALL_TOT + N_NODES * 128) {
        int j = i - WALL_TOT;
        int n = j >> 7, k = j & 127;
        float v = (k < 100) ? x[n * 100 + k] : 0.f;
        Xb[j] = f2bbits(v);
    } else if (i < PREP_TOT) {
        int k = i - (WALL_TOT + N_NODES * 128);
        int sd = k >> 9, h = (k >> 7) & 3, kk = k & 127;
        const float* att = sd ? a3d : a3s;
        float s = 0.f;
        for (int c = 0; c < 47; ++c) s += att[h * 47 + c] * W3[(h * 47 + c) * 128 + kk];
        (sd ? VD : VS)[h * 128 + kk] = s;
    }
}

// ---------------- fused bf16 MFMA GEMM + alpha epilogue (layers 1,2) ----------------
// LINB: bf16 [N][128], holds lin + bl + bagg (both biases folded).

__global__ __launch_bounds__(256) void gemm_dual_a(
        const unsigned short* __restrict__ A,
        const unsigned short* __restrict__ Wh, const unsigned short* __restrict__ Wl,
        const float* __restrict__ bl, const float* __restrict__ bagg,
        const float* __restrict__ att_s, const float* __restrict__ att_d,  // [4][32]
        unsigned short* __restrict__ HFb, unsigned short* __restrict__ LINB,
        float* __restrict__ ASRC, float* __restrict__ ADST) {
    int wv = threadIdx.x >> 6, lane = threadIdx.x & 63;
    int rt = blockIdx.x * 4 + wv;
    if (rt >= NROWT) return;
    int l16 = lane & 15, kgrp = lane >> 4;
    const unsigned short* xrow = A + (size_t)(rt * 16 + l16) * 128 + kgrp * 8;
    short8 a[4];
    #pragma unroll
    for (int ks = 0; ks < 4; ++ks)
        a[ks] = *reinterpret_cast<const short8*>(xrow + ks * 32);
    int row0 = rt * 16 + kgrp * 4;
    float ps[4][4] = {}, pd[4][4] = {};
    #pragma unroll
    for (int ct = 0; ct < 16; ++ct) {
        const bool isH = (ct < 8);
        const unsigned short* W = isH ? Wh : Wl;
        int c = (isH ? ct : ct - 8) * 16 + l16;
        const unsigned short* wrow = W + (size_t)c * 128 + kgrp * 8;
        f32x4 acc = {0.f, 0.f, 0.f, 0.f};
        #pragma unroll
        for (int ks = 0; ks < 4; ++ks) {
            short8 b = *reinterpret_cast<const short8*>(wrow + ks * 32);
            acc = __builtin_amdgcn_mfma_f32_16x16x32_bf16(a[ks], b, acc, 0, 0, 0);
        }
        if (isH) {
            const int h = ct >> 1;
            float as = att_s[h * 32 + (ct & 1) * 16 + l16];
            float ad = att_d[h * 32 + (ct & 1) * 16 + l16];
            #pragma unroll
            for (int r = 0; r < 4; ++r) {
                ps[h][r] += acc[r] * as;
                pd[h][r] += acc[r] * ad;
                HFb[(size_t)(row0 + r) * 128 + c] = f2bbits(acc[r]);
            }
        } else {
            float bias = bl[c] + bagg[c];
            #pragma unroll
            for (int r = 0; r < 4; ++r)
                LINB[(size_t)(row0 + r) * 128 + c] = f2bbits(acc[r] + bias);
        }
    }
    #pragma unroll
    for (int h = 0; h < 4; ++h)
        #pragma unroll
        for (int r = 0; r < 4; ++r) {
            #pragma unroll
            for (int d = 1; d < 16; d <<= 1) {
                ps[h][r] += __shfl_xor(ps[h][r], d);
                pd[h][r] += __shfl_xor(pd[h][r], d);
            }
        }
    if (l16 == 0) {
        #pragma unroll
        for (int r = 0; r < 4; ++r)
            #pragma unroll
            for (int h = 0; h < 4; ++h) {
                ASRC[(row0 + r) * 4 + h] = ps[h][r];
                ADST[(row0 + r) * 4 + h] = pd[h][r];
            }
    }
}

// ---------------- edge-centric exp weights ----------------
// PLANAR: head-major planes W4T[h*E_TOT + e] (for agg12).
// else  : interleaved float4 W4[e] (for agg3f).

template<bool PLANAR>
__global__ void edge_weights(const int* __restrict__ csr_src, const int* __restrict__ csr_dst,
                             const float* __restrict__ asrc, const float* __restrict__ adst,
                             float4* __restrict__ W4, float* __restrict__ W4T) {
    int e = blockIdx.x * blockDim.x + threadIdx.x;
    if (e >= E_TOT) return;
    int s = csr_src[e], d = csr_dst[e];
    float4 av = ((const float4*)asrc)[s];
    float4 dv = ((const float4*)adst)[d];
    float wx = __expf(lrelu(av.x + dv.x));
    float wy = __expf(lrelu(av.y + dv.y));
    float wz = __expf(lrelu(av.z + dv.z));
    float ww = __expf(lrelu(av.w + dv.w));
    if (PLANAR) {
        W4T[e] = wx;
        W4T[E_TOT + e] = wy;
        W4T[2 * E_TOT + e] = wz;
        W4T[3 * E_TOT + e] = ww;
    } else {
        W4[e] = make_float4(wx, wy, wz, ww);
    }
}

// ---------------- aggregation layers 1-2 (16-edge unroll, planar weights) ----------

template<bool ALPHA3>
__global__ __launch_bounds__(256) void agg12(
        const int* __restrict__ off, const int* __restrict__ csr_src,
        const uint2* __restrict__ HU2,   // bf16 HF: [N][32] uint2
        const float* __restrict__ W4T,   // [4][E_TOT] planar weights
        const uint2* __restrict__ LINB2, // bf16 lin+biases: [N][32] uint2
        unsigned* __restrict__ OUTB,
        const float4* __restrict__ VS4, const float4* __restrict__ VD4,
        float* __restrict__ ASRC, float* __restrict__ ADST) {
    int wv = threadIdx.x >> 6, lane = threadIdx.x & 63;
    int n = blockIdx.x * 4 + wv;
    int e0 = off[n], e1 = off[n + 1];
    int el = lane >> 5;
    int fl = lane & 31;
    int h = fl >> 3;
    const float* Wh = W4T + (size_t)h * E_TOT;
    float acc0 = 0.f, acc1 = 0.f, acc2 = 0.f, acc3 = 0.f, den = 0.f;
    int e = e0;
    for (; e + 16 <= e1; e += 16) {
        int s[8]; float w[8]; uint2 u[8];
        #pragma unroll
        for (int j = 0; j < 8; ++j) s[j] = csr_src[e + 2 * j + el];
        #pragma unroll
        for (int j = 0; j < 8; ++j) w[j] = Wh[e + 2 * j + el];
        #pragma unroll
        for (int j = 0; j < 8; ++j) u[j] = HU2[(size_t)s[j] * 32 + fl];
        #pragma unroll
        for (int j = 0; j < 8; ++j) {
            den += w[j];
            acc0 += w[j] * bf_lo(u[j].x);
            acc1 += w[j] * bf_hi(u[j].x);
            acc2 += w[j] * bf_lo(u[j].y);
            acc3 += w[j] * bf_hi(u[j].y);
        }
    }
    for (; e + 4 <= e1; e += 4) {
        int s[2]; float w[2]; uint2 u[2];
        #pragma unroll
        for (int j = 0; j < 2; ++j) s[j] = csr_src[e + 2 * j + el];
        #pragma unroll
        for (int j = 0; j < 2; ++j) w[j] = Wh[e + 2 * j + el];
        #pragma unroll
        for (int j = 0; j < 2; ++j) u[j] = HU2[(size_t)s[j] * 32 + fl];
        #pragma unroll
        for (int j = 0; j < 2; ++j) {
            den += w[j];
            acc0 += w[j] * bf_lo(u[j].x);
            acc1 += w[j] * bf_hi(u[j].x);
            acc2 += w[j] * bf_lo(u[j].y);
            acc3 += w[j] * bf_hi(u[j].y);
        }
    }
    for (; e + 2 <= e1; e += 2) {
        int s = csr_src[e + el];
        float w = Wh[e + el];
        uint2 u = HU2[(size_t)s * 32 + fl];
        den += w;
        acc0 += w * bf_lo(u.x);
        acc1 += w * bf_hi(u.x);
        acc2 += w * bf_lo(u.y);
        acc3 += w * bf_hi(u.y);
    }
    if (e + el < e1) {
        int s = csr_src[e + el];
        float w = Wh[e + el];
        uint2 u = HU2[(size_t)s * 32 + fl];
        den += w;
        acc0 += w * bf_lo(u.x);
        acc1 += w * bf_hi(u.x);
        acc2 += w * bf_lo(u.y);
        acc3 += w * bf_hi(u.y);
    }
    acc0 += __shfl_xor(acc0, 32);
    acc1 += __shfl_xor(acc1, 32);
    acc2 += __shfl_xor(acc2, 32);
    acc3 += __shfl_xor(acc3, 32);
    den  += __shfl_xor(den, 32);
    float inv = 1.0f / (den + 1e-16f);
    uint2 lu = LINB2[(size_t)n * 32 + fl];
    float o0 = fmaxf(acc0 * inv + bf_lo(lu.x), 0.f);
    float o1 = fmaxf(acc1 * inv + bf_hi(lu.x), 0.f);
    float o2 = fmaxf(acc2 * inv + bf_lo(lu.y), 0.f);
    float o3 = fmaxf(acc3 * inv + bf_hi(lu.y), 0.f);
    if (el == 0) {
        uint2 p;
        p.x = ((unsigned)f2bbits(o1) << 16) | f2bbits(o0);
        p.y = ((unsigned)f2bbits(o3) << 16) | f2bbits(o2);
        ((uint2*)OUTB)[(size_t)n * 32 + fl] = p;
    }
    if (ALPHA3) {
        float ss[4], sd[4];
        #pragma unroll
        for (int hh = 0; hh < 4; ++hh) {
            float4 vs = VS4[hh * 32 + fl];
            float4 vd = VD4[hh * 32 + fl];
            ss[hh] = o0 * vs.x + o1 * vs.y + o2 * vs.z + o3 * vs.w;
            sd[hh] = o0 * vd.x + o1 * vd.y + o2 * vd.z + o3 * vd.w;
        }
        #pragma unroll
        for (int d2 = 1; d2 < 32; d2 <<= 1)
            #pragma unroll
            for (int hh = 0; hh < 4; ++hh) {
                ss[hh] += __shfl_xor(ss[hh], d2);
                sd[hh] += __shfl_xor(sd[hh], d2);
            }
        if (lane == 0) {
            #pragma unroll
            for (int hh = 0; hh < 4; ++hh) {
                ASRC[n * 4 + hh] = ss[hh];
                ADST[n * 4 + hh] = sd[hh];
            }
        }
    }
}

// ---------------- layer 3 folded aggregation (8-edge unroll) ----------------

__global__ __launch_bounds__(256) void agg3f(
        const int* __restrict__ off, const int* __restrict__ csr_src,
        const unsigned* __restrict__ BU,   // [N][64] uints (128 bf16)
        const float4* __restrict__ W4,
        unsigned* __restrict__ AGG) {      // [N][256] uints
    int wv = threadIdx.x >> 6, lane = threadIdx.x & 63;
    int n = blockIdx.x * 4 + wv;
    int e0 = off[n], e1 = off[n + 1];
    float acc[4][2] = {};
    float den[4] = {};
    int e = e0;
    for (; e + 8 <= e1; e += 8) {
        int s[8]; float4 w[8]; unsigned u[8];
        #pragma unroll
        for (int j = 0; j < 8; ++j) s[j] = csr_src[e + j];
        #pragma unroll
        for (int j = 0; j < 8; ++j) w[j] = W4[e + j];
        #pragma unroll
        for (int j = 0; j < 8; ++j) u[j] = BU[(size_t)s[j] * 64 + lane];
        #pragma unroll
        for (int j = 0; j < 8; ++j) {
            float f0 = bf_lo(u[j]), f1 = bf_hi(u[j]);
            den[0] += w[j].x; den[1] += w[j].y; den[2] += w[j].z; den[3] += w[j].w;
            acc[0][0] += w[j].x * f0;  acc[0][1] += w[j].x * f1;
            acc[1][0] += w[j].y * f0;  acc[1][1] += w[j].y * f1;
            acc[2][0] += w[j].z * f0;  acc[2][1] += w[j].z * f1;
            acc[3][0] += w[j].w * f0;  acc[3][1] += w[j].w * f1;
        }
    }
    for (; e + 2 <= e1; e += 2) {
        int sA = csr_src[e], sB = csr_src[e + 1];
        float4 wA = W4[e], wB = W4[e + 1];
        unsigned uA = BU[(size_t)sA * 64 + lane];
        unsigned uB = BU[(size_t)sB * 64 + lane];
        float fA0 = bf_lo(uA), fA1 = bf_hi(uA);
        float fB0 = bf_lo(uB), fB1 = bf_hi(uB);
        den[0] += wA.x + wB.x; den[1] += wA.y + wB.y;
        den[2] += wA.z + wB.z; den[3] += wA.w + wB.w;
        acc[0][0] += wA.x * fA0 + wB.x * fB0;  acc[0][1] += wA.x * fA1 + wB.x * fB1;
        acc[1][0] += wA.y * fA0 + wB.y * fB0;  acc[1][1] += wA.y * fA1 + wB.y * fB1;
        acc[2][0] += wA.z * fA0 + wB.z * fB0;  acc[2][1] += wA.z * fA1 + wB.z * fB1;
        acc[3][0] += wA.w * fA0 + wB.w * fB0;  acc[3][1] += wA.w * fA1 + wB.w * fB1;
    }
    if (e < e1) {
        int s = csr_src[e];
        float4 w4 = W4[e];
        unsigned u = BU[(size_t)s * 64 + lane];
        float f0 = bf_lo(u), f1 = bf_hi(u);
        den[0] += w4.x; den[1] += w4.y; den[2] += w4.z; den[3] += w4.w;
        acc[0][0] += w4.x * f0;  acc[0][1] += w4.x * f1;
        acc[1][0] += w4.y * f0;  acc[1][1] += w4.y * f1;
        acc[2][0] += w4.z * f0;  acc[2][1] += w4.z * f1;
        acc[3][0] += w4.w * f0;  acc[3][1] += w4.w * f1;
    }
    size_t base = (size_t)n * 256 + lane;
    #pragma unroll
    for (int h = 0; h < 4; ++h) {
        float inv = 1.0f / (den[h] + 1e-16f);
        AGG[base + h * 64] =
            ((unsigned)f2bbits(acc[h][1] * inv) << 16) | f2bbits(acc[h][0] * inv);
    }
}

// ---------------- post: AGG@W3m (K=512) + Bb@Wl3 (K=128) + b3 + bl3 + log_softmax

__global__ __launch_bounds__(256) void post_ls(
        const unsigned short* __restrict__ AGG, const unsigned short* __restrict__ Bb,
        const unsigned short* __restrict__ W3m, const unsigned short* __restrict__ Wl3b,
        const float* __restrict__ b3, const float* __restrict__ bl3,
        float* __restrict__ OUT) {
    int wv = threadIdx.x >> 6, lane = threadIdx.x & 63;
    int rt = blockIdx.x * 4 + wv;
    if (rt >= NROWT) return;
    int l16 = lane & 15, kgrp = lane >> 4;
    const unsigned short* arow = AGG + (size_t)(rt * 16 + l16) * 512 + kgrp * 8;
    short8 a[16];
    #pragma unroll
    for (int ks = 0; ks < 16; ++ks)
        a[ks] = *reinterpret_cast<const short8*>(arow + ks * 32);
    const unsigned short* brow = Bb + (size_t)(rt * 16 + l16) * 128 + kgrp * 8;
    short8 al[4];
    #pragma unroll
    for (int ks = 0; ks < 4; ++ks)
        al[ks] = *reinterpret_cast<const short8*>(brow + ks * 32);
    f32x4 accs[3];
    #pragma unroll
    for (int ct = 0; ct < 3; ++ct) {
        int c = ct * 16 + l16;
        const unsigned short* wrow = W3m + (size_t)c * 512 + kgrp * 8;
        const unsigned short* lrow = Wl3b + (size_t)c * 128 + kgrp * 8;
        f32x4 acc = {0.f, 0.f, 0.f, 0.f};
        #pragma unroll
        for (int ks = 0; ks < 16; ++ks) {
            short8 b = *reinterpret_cast<const short8*>(wrow + ks * 32);
            acc = __builtin_amdgcn_mfma_f32_16x16x32_bf16(a[ks], b, acc, 0, 0, 0);
        }
        #pragma unroll
        for (int ks = 0; ks < 4; ++ks) {
            short8 b = *reinterpret_cast<const short8*>(lrow + ks * 32);
            acc = __builtin_amdgcn_mfma_f32_16x16x32_bf16(al[ks], b, acc, 0, 0, 0);
        }
        accs[ct] = acc;
    }
    int row0 = rt * 16 + kgrp * 4;
    int c0 = l16, c1 = 16 + l16, c2 = 32 + l16;
    bool v2 = (c2 < 47);
    float b0 = b3[c0] + bl3[c0];
    float b1v = b3[c1] + bl3[c1];
    float b2v = v2 ? (b3[c2] + bl3[c2]) : 0.f;
    #pragma unroll
    for (int r = 0; r < 4; ++r) {
        int row = row0 + r;
        float z0 = accs[0][r] + b0;
        float z1 = accs[1][r] + b1v;
        float z2 = v2 ? (accs[2][r] + b2v) : -INFINITY;
        float m = fmaxf(fmaxf(z0, z1), z2);
        #pragma unroll
        for (int d = 1; d < 16; d <<= 1) m = fmaxf(m, __shfl_xor(m, d));
        float s = __expf(z0 - m) + __expf(z1 - m) + (v2 ? __expf(z2 - m) : 0.f);
        #pragma unroll
        for (int d = 1; d < 16; d <<= 1) s += __shfl_xor(s, d);
        float ls = logf(s);
        float* orow = OUT + (size_t)row * 47;
        orow[c0] = z0 - m - ls;
        orow[c1] = z1 - m - ls;
        if (v2) orow[c2] = z2 - m - ls;
    }
}

// ---------------- launch ----------------

extern "C" void kernel_launch(void* const* d_in, const int* in_sizes, int n_in,
                              void* d_out, int out_size, void* d_ws, size_t ws_size,
                              hipStream_t stream) {
    const float* x   = (const float*)d_in[0];
    const int*   ei  = (const int*)d_in[1];
    const float* W1  = (const float*)d_in[2];
    const float* a1s = (const float*)d_in[3];
    const float* a1d = (const float*)d_in[4];
    const float* b1  = (const float*)d_in[5];
    const float* Wl1 = (const float*)d_in[6];
    const float* bl1 = (const float*)d_in[7];
    const float* W2  = (const float*)d_in[8];
    const float* a2s = (const float*)d_in[9];
    const float* a2d = (const float*)d_in[10];
    const float* b2  = (const float*)d_in[11];
    const float* Wl2 = (const float*)d_in[12];
    const float* bl2 = (const float*)d_in[13];
    const float* W3  = (const float*)d_in[14];
    const float* a3s = (const float*)d_in[15];
    const float* a3d = (const float*)d_in[16];
    const float* b3  = (const float*)d_in[17];
    const float* Wl3 = (const float*)d_in[18];
    const float* bl3 = (const float*)d_in[19];
    float* out = (float*)d_out;

    size_t cur = 0;
    char* wsb = (char*)d_ws;
    auto carve = [&](size_t bytes) -> void* {
        void* p = wsb + cur;
        cur += (bytes + 255) & ~(size_t)255;
        return p;
    };
    int*   cnt    = (int*)  carve((size_t)N_NODES * 4);
    int*   offs   = (int*)  carve((size_t)(N_NODES + 1) * 4);
    int*   cursor = (int*)  carve((size_t)N_NODES * 4);
    int*   part   = (int*)  carve((size_t)SCAN_NB * 4);
    int*   csr    = (int*)  carve((size_t)E_TOT * 4);
    int*   csrd   = (int*)  carve((size_t)E_TOT * 4);
    unsigned short* WALL = (unsigned short*)carve((size_t)WALL_TOT * 2);
    // Xb, HFb, LINB, PAD contiguous (each 12.8 MB) and all dead before agg3f
    // -> AGG ([N][512] bf16 = 51.2 MB) aliases exactly this 4x12.8 MB region.
    unsigned short* Xb   = (unsigned short*)carve((size_t)N_NODES * 128 * 2);
    unsigned short* HFb  = (unsigned short*)carve((size_t)N_NODES * 128 * 2);
    unsigned short* LINB = (unsigned short*)carve((size_t)N_NODES * 128 * 2);
    carve((size_t)N_NODES * 128 * 2);   // pad so AGG doesn't overlap Bb
    unsigned short* AGG  = Xb;   // alias
    unsigned short* Bb   = (unsigned short*)carve((size_t)N_NODES * 128 * 2);
    float* ASRC   = (float*)carve((size_t)N_NODES * 4 * 4);
    float* ADST   = (float*)carve((size_t)N_NODES * 4 * 4);
    float4* W4    = (float4*)carve((size_t)E_TOT * 16);
    float* W4T    = (float*)W4;   // planar alias (same 13.6 MB, disjoint in time)
    float* VS     = (float*)carve((size_t)4 * 128 * 4);
    float* VD     = (float*)carve((size_t)4 * 128 * 4);

    unsigned short* Wb1h = WALL + 0;
    unsigned short* Wb1l = WALL + 16384;
    unsigned short* Wb2h = WALL + 32768;
    unsigned short* Wb2l = WALL + 49152;
    unsigned short* Wb3l = WALL + 65536;
    unsigned short* W3m  = WALL + 71680;

    const int* esrc = ei;
    const int* edst = ei + N_EDGES;

    prep<<<PREP_TOT / 256, 256, 0, stream>>>(W1, Wl1, W2, Wl2, W3, Wl3, a3s, a3d, x,
                                             WALL, Xb, VS, VD);

    hipMemsetAsync(cnt, 0, (size_t)N_NODES * 4, stream);
    int egrid = (E_TOT + 255) / 256;
    count_deg<<<egrid, 256, 0, stream>>>(edst, cnt);
    scan_part1<<<SCAN_NB, 256, 0, stream>>>(cnt, part);
    scan_part2<<<1, 256, 0, stream>>>(part);
    scan_part3<<<SCAN_NB, 256, 0, stream>>>(cnt, part, offs, cursor);
    scatter_edges<<<egrid, 256, 0, stream>>>(esrc, edst, cursor, csr, csrd);

    int ngrid = N_NODES / 4;
    int ggrid = (NROWT + 3) / 4;   // 782

    // ---- layer 1 ----
    gemm_dual_a<<<ggrid, 256, 0, stream>>>(Xb, Wb1h, Wb1l, bl1, b1, a1s, a1d,
                                           HFb, LINB, ASRC, ADST);
    edge_weights<true><<<egrid, 256, 0, stream>>>(csr, csrd, ASRC, ADST, W4, W4T);
    agg12<false><<<ngrid, 256, 0, stream>>>(offs, csr, (const uint2*)HFb, W4T,
                                            (const uint2*)LINB, (unsigned*)Bb,
                                            nullptr, nullptr, nullptr, nullptr);
    // ---- layer 2 (epilogue computes layer-3 logits from fp32 outputs) ----
    gemm_dual_a<<<ggrid, 256, 0, stream>>>(Bb, Wb2h, Wb2l, bl2, b2, a2s, a2d,
                                           HFb, LINB, ASRC, ADST);
    edge_weights<true><<<egrid, 256, 0, stream>>>(csr, csrd, ASRC, ADST, W4, W4T);
    agg12<true><<<ngrid, 256, 0, stream>>>(offs, csr, (const uint2*)HFb, W4T,
                                           (const uint2*)LINB, (unsigned*)Bb,
                                           (const float4*)VS, (const float4*)VD,
                                           ASRC, ADST);
    // ---- layer 3 (W3 folded past aggregation; LIN3 fused into post) ----
    edge_weights<false><<<egrid, 256, 0, stream>>>(csr, csrd, ASRC, ADST, W4, W4T);
    agg3f<<<ngrid, 256, 0, stream>>>(offs, csr, (const unsigned*)Bb, W4, (unsigned*)AGG);
    post_ls<<<ggrid, 256, 0, stream>>>(AGG, Bb, W3m, Wb3l, b3, bl3, out);
}

// Round 10
// 385.674 us; speedup vs baseline: 2.5286x; 1.0065x over previous
//
#include <hip/hip_runtime.h>
#include <hip/hip_bf16.h>
#include <math.h>

#define N_NODES 50000
#define N_EDGES 800000
#define E_TOT   (N_EDGES + N_NODES)   // 850000
#define HEADS   4
#define NEG     0.2f
#define NROWT   3125                  // 50000/16 row-tiles
#define SCAN_NB 196                   // ceil(50000/256)

typedef __attribute__((ext_vector_type(8))) short short8;   // 8 bf16 (4 VGPRs)
typedef __attribute__((ext_vector_type(4))) float f32x4;

__device__ __forceinline__ float bf_lo(unsigned u) { return __uint_as_float(u << 16); }
__device__ __forceinline__ float bf_hi(unsigned u) { return __uint_as_float(u & 0xffff0000u); }
__device__ __forceinline__ unsigned short f2bbits(float f) {
    __hip_bfloat16 b = __float2bfloat16(f);
    return *reinterpret_cast<unsigned short*>(&b);
}
__device__ __forceinline__ float lrelu(float v) { return v > 0.f ? v : NEG * v; }

// ---------------- CSR build (dst-sorted, packed (d<<16)|s) ----------------

__global__ void count_deg(const int* __restrict__ edst, int* __restrict__ cnt) {
    int i = blockIdx.x * blockDim.x + threadIdx.x;
    if (i >= E_TOT) return;
    int d = (i < N_EDGES) ? edst[i] : (i - N_EDGES);
    atomicAdd(&cnt[d], 1);
}

__global__ void scan_part1(const int* __restrict__ cnt, int* __restrict__ partial) {
    __shared__ int red[256];
    int t = threadIdx.x;
    int i = blockIdx.x * 256 + t;
    int v = (i < N_NODES) ? cnt[i] : 0;
    red[t] = v;
    __syncthreads();
    #pragma unroll
    for (int s = 128; s; s >>= 1) {
        if (t < s) red[t] += red[t + s];
        __syncthreads();
    }
    if (t == 0) partial[blockIdx.x] = red[0];
}

__global__ void scan_part2(int* __restrict__ partial) {   // 1 block, 256 threads
    __shared__ int sums[256];
    int t = threadIdx.x;
    int v = (t < SCAN_NB) ? partial[t] : 0;
    sums[t] = v;
    __syncthreads();
    #pragma unroll
    for (int d = 1; d < 256; d <<= 1) {
        int add = (t >= d) ? sums[t - d] : 0;
        __syncthreads();
        sums[t] += add;
        __syncthreads();
    }
    if (t < SCAN_NB) partial[t] = sums[t] - v;   // exclusive
}

__global__ void scan_part3(const int* __restrict__ cnt, const int* __restrict__ partial,
                           int* __restrict__ off, int* __restrict__ cursor) {
    __shared__ int sums[256];
    int t = threadIdx.x;
    int i = blockIdx.x * 256 + t;
    int v = (i < N_NODES) ? cnt[i] : 0;
    sums[t] = v;
    __syncthreads();
    #pragma unroll
    for (int d = 1; d < 256; d <<= 1) {
        int add = (t >= d) ? sums[t - d] : 0;
        __syncthreads();
        sums[t] += add;
        __syncthreads();
    }
    int excl = sums[t] - v + partial[blockIdx.x];
    if (i < N_NODES) { off[i] = excl; cursor[i] = excl; }
    if (i == N_NODES - 1) off[N_NODES] = excl + v;   // == E_TOT
}

__global__ void scatter_edges(const int* __restrict__ esrc, const int* __restrict__ edst,
                              int* __restrict__ cursor, unsigned* __restrict__ csr) {
    int i = blockIdx.x * blockDim.x + threadIdx.x;
    if (i >= E_TOT) return;
    int s, d;
    if (i < N_EDGES) { s = esrc[i]; d = edst[i]; }
    else             { s = i - N_EDGES; d = s; }
    int pos = atomicAdd(&cursor[d], 1);
    csr[pos] = ((unsigned)d << 16) | (unsigned)s;   // node ids < 65536
}

// ---------------- unified preprocessing ----------------
// WALL layout (ushort, zero-padded [Mpad][K]):
//  0      : 128x128 <- W1  (M=128,K=100)
//  16384  : 128x128 <- Wl1 (M=128,K=100)
//  32768  : 128x128 <- W2  (K=128)
//  49152  : 128x128 <- Wl2 (K=128)
//  65536  : 48x128  <- Wl3 (M=47,K=128)
//  71680  : 48x512  <- W3m (0.25*W3 head-concat: [c][h*128+k])
#define WALL_TOT 96256
#define PREP_TOT (WALL_TOT + N_NODES * 128 + 1024)

__global__ void prep(const float* __restrict__ W1, const float* __restrict__ Wl1,
                     const float* __restrict__ W2, const float* __restrict__ Wl2,
                     const float* __restrict__ W3, const float* __restrict__ Wl3,
                     const float* __restrict__ a3s, const float* __restrict__ a3d,
                     const float* __restrict__ x,
                     unsigned short* __restrict__ WALL, unsigned short* __restrict__ Xb,
                     float* __restrict__ VS, float* __restrict__ VD) {
    int i = blockIdx.x * blockDim.x + threadIdx.x;
    if (i < WALL_TOT) {
        float v;
        if (i < 65536) {
            const float* src; int base, K;
            if      (i < 16384) { src = W1;  base = 0;     K = 100; }
            else if (i < 32768) { src = Wl1; base = 16384; K = 100; }
            else if (i < 49152) { src = W2;  base = 32768; K = 128; }
            else                { src = Wl2; base = 49152; K = 128; }
            int local = i - base;
            int m = local >> 7, k = local & 127;
            v = (k < K) ? src[m * K + k] : 0.f;
        } else if (i < 71680) {
            int local = i - 65536;
            int m = local >> 7, k = local & 127;
            v = (m < 47) ? Wl3[m * 128 + k] : 0.f;
        } else {
            int local = i - 71680;
            int c = local >> 9, k512 = local & 511;
            int h = k512 >> 7, kk = k512 & 127;
            v = (c < 47) ? 0.25f * W3[(h * 47 + c) * 128 + kk] : 0.f;
        }
        WALL[i] = f2bbits(v);
    } else if (i < WALL_TOT + N_NODES * 128) {
        int j = i - WALL_TOT;
        int n = j >> 7, k = j & 127;
        float v = (k < 100) ? x[n * 100 + k] : 0.f;
        Xb[j] = f2bbits(v);
    } else if (i < PREP_TOT) {
        int k = i - (WALL_TOT + N_NODES * 128);
        int sd = k >> 9, h = (k >> 7) & 3, kk = k & 127;
        const float* att = sd ? a3d : a3s;
        float s = 0.f;
        for (int c = 0; c < 47; ++c) s += att[h * 47 + c] * W3[(h * 47 + c) * 128 + kk];
        (sd ? VD : VS)[h * 128 + kk] = s;
    }
}

// ---------------- fused bf16 MFMA GEMM + alpha epilogue (layers 1,2) ----------------
// LINB: bf16 [N][128], holds lin + bl + bagg (both biases folded).

__global__ __launch_bounds__(256) void gemm_dual_a(
        const unsigned short* __restrict__ A,
        const unsigned short* __restrict__ Wh, const unsigned short* __restrict__ Wl,
        const float* __restrict__ bl, const float* __restrict__ bagg,
        const float* __restrict__ att_s, const float* __restrict__ att_d,  // [4][32]
        unsigned short* __restrict__ HFb, unsigned short* __restrict__ LINB,
        float* __restrict__ ASRC, float* __restrict__ ADST) {
    int wv = threadIdx.x >> 6, lane = threadIdx.x & 63;
    int rt = blockIdx.x * 4 + wv;
    if (rt >= NROWT) return;
    int l16 = lane & 15, kgrp = lane >> 4;
    const unsigned short* xrow = A + (size_t)(rt * 16 + l16) * 128 + kgrp * 8;
    short8 a[4];
    #pragma unroll
    for (int ks = 0; ks < 4; ++ks)
        a[ks] = *reinterpret_cast<const short8*>(xrow + ks * 32);
    int row0 = rt * 16 + kgrp * 4;
    float ps[4][4] = {}, pd[4][4] = {};
    #pragma unroll
    for (int ct = 0; ct < 16; ++ct) {
        const bool isH = (ct < 8);
        const unsigned short* W = isH ? Wh : Wl;
        int c = (isH ? ct : ct - 8) * 16 + l16;
        const unsigned short* wrow = W + (size_t)c * 128 + kgrp * 8;
        f32x4 acc = {0.f, 0.f, 0.f, 0.f};
        #pragma unroll
        for (int ks = 0; ks < 4; ++ks) {
            short8 b = *reinterpret_cast<const short8*>(wrow + ks * 32);
            acc = __builtin_amdgcn_mfma_f32_16x16x32_bf16(a[ks], b, acc, 0, 0, 0);
        }
        if (isH) {
            const int h = ct >> 1;
            float as = att_s[h * 32 + (ct & 1) * 16 + l16];
            float ad = att_d[h * 32 + (ct & 1) * 16 + l16];
            #pragma unroll
            for (int r = 0; r < 4; ++r) {
                ps[h][r] += acc[r] * as;
                pd[h][r] += acc[r] * ad;
                HFb[(size_t)(row0 + r) * 128 + c] = f2bbits(acc[r]);
            }
        } else {
            float bias = bl[c] + bagg[c];
            #pragma unroll
            for (int r = 0; r < 4; ++r)
                LINB[(size_t)(row0 + r) * 128 + c] = f2bbits(acc[r] + bias);
        }
    }
    #pragma unroll
    for (int h = 0; h < 4; ++h)
        #pragma unroll
        for (int r = 0; r < 4; ++r) {
            #pragma unroll
            for (int d = 1; d < 16; d <<= 1) {
                ps[h][r] += __shfl_xor(ps[h][r], d);
                pd[h][r] += __shfl_xor(pd[h][r], d);
            }
        }
    if (l16 == 0) {
        #pragma unroll
        for (int r = 0; r < 4; ++r)
            #pragma unroll
            for (int h = 0; h < 4; ++h) {
                ASRC[(row0 + r) * 4 + h] = ps[h][r];
                ADST[(row0 + r) * 4 + h] = pd[h][r];
            }
    }
}

// ---------------- edge-centric exp weights (packed csr) ----------------
// PLANAR: head-major planes W4T[h*E_TOT + e] (for agg12).
// else  : interleaved float4 W4[e] (for agg3f).

template<bool PLANAR>
__global__ void edge_weights(const unsigned* __restrict__ csr,
                             const float* __restrict__ asrc, const float* __restrict__ adst,
                             float4* __restrict__ W4, float* __restrict__ W4T) {
    int e = blockIdx.x * blockDim.x + threadIdx.x;
    if (e >= E_TOT) return;
    unsigned u = csr[e];
    int s = u & 0xffffu, d = u >> 16;
    float4 av = ((const float4*)asrc)[s];
    float4 dv = ((const float4*)adst)[d];
    float wx = __expf(lrelu(av.x + dv.x));
    float wy = __expf(lrelu(av.y + dv.y));
    float wz = __expf(lrelu(av.z + dv.z));
    float ww = __expf(lrelu(av.w + dv.w));
    if (PLANAR) {
        W4T[e] = wx;
        W4T[E_TOT + e] = wy;
        W4T[2 * E_TOT + e] = wz;
        W4T[3 * E_TOT + e] = ww;
    } else {
        W4[e] = make_float4(wx, wy, wz, ww);
    }
}

// ---------------- aggregation layers 1-2 (16-edge unroll, planar weights) ----------

template<bool ALPHA3>
__global__ __launch_bounds__(256) void agg12(
        const int* __restrict__ off, const unsigned* __restrict__ csr,
        const uint2* __restrict__ HU2,   // bf16 HF: [N][32] uint2
        const float* __restrict__ W4T,   // [4][E_TOT] planar weights
        const uint2* __restrict__ LINB2, // bf16 lin+biases: [N][32] uint2
        unsigned* __restrict__ OUTB,
        const float4* __restrict__ VS4, const float4* __restrict__ VD4,
        float* __restrict__ ASRC, float* __restrict__ ADST) {
    int wv = threadIdx.x >> 6, lane = threadIdx.x & 63;
    int n = blockIdx.x * 4 + wv;
    int e0 = off[n], e1 = off[n + 1];
    int el = lane >> 5;
    int fl = lane & 31;
    int h = fl >> 3;
    const float* Wh = W4T + (size_t)h * E_TOT;
    float acc0 = 0.f, acc1 = 0.f, acc2 = 0.f, acc3 = 0.f, den = 0.f;
    int e = e0;
    for (; e + 16 <= e1; e += 16) {
        int s[8]; float w[8]; uint2 u[8];
        #pragma unroll
        for (int j = 0; j < 8; ++j) s[j] = csr[e + 2 * j + el] & 0xffffu;
        #pragma unroll
        for (int j = 0; j < 8; ++j) w[j] = Wh[e + 2 * j + el];
        #pragma unroll
        for (int j = 0; j < 8; ++j) u[j] = HU2[(size_t)s[j] * 32 + fl];
        #pragma unroll
        for (int j = 0; j < 8; ++j) {
            den += w[j];
            acc0 += w[j] * bf_lo(u[j].x);
            acc1 += w[j] * bf_hi(u[j].x);
            acc2 += w[j] * bf_lo(u[j].y);
            acc3 += w[j] * bf_hi(u[j].y);
        }
    }
    for (; e + 4 <= e1; e += 4) {
        int s[2]; float w[2]; uint2 u[2];
        #pragma unroll
        for (int j = 0; j < 2; ++j) s[j] = csr[e + 2 * j + el] & 0xffffu;
        #pragma unroll
        for (int j = 0; j < 2; ++j) w[j] = Wh[e + 2 * j + el];
        #pragma unroll
        for (int j = 0; j < 2; ++j) u[j] = HU2[(size_t)s[j] * 32 + fl];
        #pragma unroll
        for (int j = 0; j < 2; ++j) {
            den += w[j];
            acc0 += w[j] * bf_lo(u[j].x);
            acc1 += w[j] * bf_hi(u[j].x);
            acc2 += w[j] * bf_lo(u[j].y);
            acc3 += w[j] * bf_hi(u[j].y);
        }
    }
    for (; e + 2 <= e1; e += 2) {
        int s = csr[e + el] & 0xffffu;
        float w = Wh[e + el];
        uint2 u = HU2[(size_t)s * 32 + fl];
        den += w;
        acc0 += w * bf_lo(u.x);
        acc1 += w * bf_hi(u.x);
        acc2 += w * bf_lo(u.y);
        acc3 += w * bf_hi(u.y);
    }
    if (e + el < e1) {
        int s = csr[e + el] & 0xffffu;
        float w = Wh[e + el];
        uint2 u = HU2[(size_t)s * 32 + fl];
        den += w;
        acc0 += w * bf_lo(u.x);
        acc1 += w * bf_hi(u.x);
        acc2 += w * bf_lo(u.y);
        acc3 += w * bf_hi(u.y);
    }
    acc0 += __shfl_xor(acc0, 32);
    acc1 += __shfl_xor(acc1, 32);
    acc2 += __shfl_xor(acc2, 32);
    acc3 += __shfl_xor(acc3, 32);
    den  += __shfl_xor(den, 32);
    float inv = 1.0f / (den + 1e-16f);
    uint2 lu = LINB2[(size_t)n * 32 + fl];
    float o0 = fmaxf(acc0 * inv + bf_lo(lu.x), 0.f);
    float o1 = fmaxf(acc1 * inv + bf_hi(lu.x), 0.f);
    float o2 = fmaxf(acc2 * inv + bf_lo(lu.y), 0.f);
    float o3 = fmaxf(acc3 * inv + bf_hi(lu.y), 0.f);
    if (el == 0) {
        uint2 p;
        p.x = ((unsigned)f2bbits(o1) << 16) | f2bbits(o0);
        p.y = ((unsigned)f2bbits(o3) << 16) | f2bbits(o2);
        ((uint2*)OUTB)[(size_t)n * 32 + fl] = p;
    }
    if (ALPHA3) {
        float ss[4], sd[4];
        #pragma unroll
        for (int hh = 0; hh < 4; ++hh) {
            float4 vs = VS4[hh * 32 + fl];
            float4 vd = VD4[hh * 32 + fl];
            ss[hh] = o0 * vs.x + o1 * vs.y + o2 * vs.z + o3 * vs.w;
            sd[hh] = o0 * vd.x + o1 * vd.y + o2 * vd.z + o3 * vd.w;
        }
        #pragma unroll
        for (int d2 = 1; d2 < 32; d2 <<= 1)
            #pragma unroll
            for (int hh = 0; hh < 4; ++hh) {
                ss[hh] += __shfl_xor(ss[hh], d2);
                sd[hh] += __shfl_xor(sd[hh], d2);
            }
        if (lane == 0) {
            #pragma unroll
            for (int hh = 0; hh < 4; ++hh) {
                ASRC[n * 4 + hh] = ss[hh];
                ADST[n * 4 + hh] = sd[hh];
            }
        }
    }
}

// ---------------- layer 3 folded aggregation (8-edge unroll) ----------------

__global__ __launch_bounds__(256) void agg3f(
        const int* __restrict__ off, const unsigned* __restrict__ csr,
        const unsigned* __restrict__ BU,   // [N][64] uints (128 bf16)
        const float4* __restrict__ W4,
        unsigned* __restrict__ AGG) {      // [N][256] uints
    int wv = threadIdx.x >> 6, lane = threadIdx.x & 63;
    int n = blockIdx.x * 4 + wv;
    int e0 = off[n], e1 = off[n + 1];
    float acc[4][2] = {};
    float den[4] = {};
    int e = e0;
    for (; e + 8 <= e1; e += 8) {
        int s[8]; float4 w[8]; unsigned u[8];
        #pragma unroll
        for (int j = 0; j < 8; ++j) s[j] = csr[e + j] & 0xffffu;
        #pragma unroll
        for (int j = 0; j < 8; ++j) w[j] = W4[e + j];
        #pragma unroll
        for (int j = 0; j < 8; ++j) u[j] = BU[(size_t)s[j] * 64 + lane];
        #pragma unroll
        for (int j = 0; j < 8; ++j) {
            float f0 = bf_lo(u[j]), f1 = bf_hi(u[j]);
            den[0] += w[j].x; den[1] += w[j].y; den[2] += w[j].z; den[3] += w[j].w;
            acc[0][0] += w[j].x * f0;  acc[0][1] += w[j].x * f1;
            acc[1][0] += w[j].y * f0;  acc[1][1] += w[j].y * f1;
            acc[2][0] += w[j].z * f0;  acc[2][1] += w[j].z * f1;
            acc[3][0] += w[j].w * f0;  acc[3][1] += w[j].w * f1;
        }
    }
    for (; e + 2 <= e1; e += 2) {
        int sA = csr[e] & 0xffffu, sB = csr[e + 1] & 0xffffu;
        float4 wA = W4[e], wB = W4[e + 1];
        unsigned uA = BU[(size_t)sA * 64 + lane];
        unsigned uB = BU[(size_t)sB * 64 + lane];
        float fA0 = bf_lo(uA), fA1 = bf_hi(uA);
        float fB0 = bf_lo(uB), fB1 = bf_hi(uB);
        den[0] += wA.x + wB.x; den[1] += wA.y + wB.y;
        den[2] += wA.z + wB.z; den[3] += wA.w + wB.w;
        acc[0][0] += wA.x * fA0 + wB.x * fB0;  acc[0][1] += wA.x * fA1 + wB.x * fB1;
        acc[1][0] += wA.y * fA0 + wB.y * fB0;  acc[1][1] += wA.y * fA1 + wB.y * fB1;
        acc[2][0] += wA.z * fA0 + wB.z * fB0;  acc[2][1] += wA.z * fA1 + wB.z * fB1;
        acc[3][0] += wA.w * fA0 + wB.w * fB0;  acc[3][1] += wA.w * fA1 + wB.w * fB1;
    }
    if (e < e1) {
        int s = csr[e] & 0xffffu;
        float4 w4 = W4[e];
        unsigned u = BU[(size_t)s * 64 + lane];
        float f0 = bf_lo(u), f1 = bf_hi(u);
        den[0] += w4.x; den[1] += w4.y; den[2] += w4.z; den[3] += w4.w;
        acc[0][0] += w4.x * f0;  acc[0][1] += w4.x * f1;
        acc[1][0] += w4.y * f0;  acc[1][1] += w4.y * f1;
        acc[2][0] += w4.z * f0;  acc[2][1] += w4.z * f1;
        acc[3][0] += w4.w * f0;  acc[3][1] += w4.w * f1;
    }
    size_t base = (size_t)n * 256 + lane;
    #pragma unroll
    for (int h = 0; h < 4; ++h) {
        float inv = 1.0f / (den[h] + 1e-16f);
        AGG[base + h * 64] =
            ((unsigned)f2bbits(acc[h][1] * inv) << 16) | f2bbits(acc[h][0] * inv);
    }
}

// ---------------- post: AGG@W3m (K=512) + Bb@Wl3 (K=128) + b3 + bl3 + log_softmax

__global__ __launch_bounds__(256) void post_ls(
        const unsigned short* __restrict__ AGG, const unsigned short* __restrict__ Bb,
        const unsigned short* __restrict__ W3m, const unsigned short* __restrict__ Wl3b,
        const float* __restrict__ b3, const float* __restrict__ bl3,
        float* __restrict__ OUT) {
    int wv = threadIdx.x >> 6, lane = threadIdx.x & 63;
    int rt = blockIdx.x * 4 + wv;
    if (rt >= NROWT) return;
    int l16 = lane & 15, kgrp = lane >> 4;
    const unsigned short* arow = AGG + (size_t)(rt * 16 + l16) * 512 + kgrp * 8;
    short8 a[16];
    #pragma unroll
    for (int ks = 0; ks < 16; ++ks)
        a[ks] = *reinterpret_cast<const short8*>(arow + ks * 32);
    const unsigned short* brow = Bb + (size_t)(rt * 16 + l16) * 128 + kgrp * 8;
    short8 al[4];
    #pragma unroll
    for (int ks = 0; ks < 4; ++ks)
        al[ks] = *reinterpret_cast<const short8*>(brow + ks * 32);
    f32x4 accs[3];
    #pragma unroll
    for (int ct = 0; ct < 3; ++ct) {
        int c = ct * 16 + l16;
        const unsigned short* wrow = W3m + (size_t)c * 512 + kgrp * 8;
        const unsigned short* lrow = Wl3b + (size_t)c * 128 + kgrp * 8;
        f32x4 acc = {0.f, 0.f, 0.f, 0.f};
        #pragma unroll
        for (int ks = 0; ks < 16; ++ks) {
            short8 b = *reinterpret_cast<const short8*>(wrow + ks * 32);
            acc = __builtin_amdgcn_mfma_f32_16x16x32_bf16(a[ks], b, acc, 0, 0, 0);
        }
        #pragma unroll
        for (int ks = 0; ks < 4; ++ks) {
            short8 b = *reinterpret_cast<const short8*>(lrow + ks * 32);
            acc = __builtin_amdgcn_mfma_f32_16x16x32_bf16(al[ks], b, acc, 0, 0, 0);
        }
        accs[ct] = acc;
    }
    int row0 = rt * 16 + kgrp * 4;
    int c0 = l16, c1 = 16 + l16, c2 = 32 + l16;
    bool v2 = (c2 < 47);
    float b0 = b3[c0] + bl3[c0];
    float b1v = b3[c1] + bl3[c1];
    float b2v = v2 ? (b3[c2] + bl3[c2]) : 0.f;
    #pragma unroll
    for (int r = 0; r < 4; ++r) {
        int row = row0 + r;
        float z0 = accs[0][r] + b0;
        float z1 = accs[1][r] + b1v;
        float z2 = v2 ? (accs[2][r] + b2v) : -INFINITY;
        float m = fmaxf(fmaxf(z0, z1), z2);
        #pragma unroll
        for (int d = 1; d < 16; d <<= 1) m = fmaxf(m, __shfl_xor(m, d));
        float s = __expf(z0 - m) + __expf(z1 - m) + (v2 ? __expf(z2 - m) : 0.f);
        #pragma unroll
        for (int d = 1; d < 16; d <<= 1) s += __shfl_xor(s, d);
        float ls = logf(s);
        float* orow = OUT + (size_t)row * 47;
        orow[c0] = z0 - m - ls;
        orow[c1] = z1 - m - ls;
        if (v2) orow[c2] = z2 - m - ls;
    }
}

// ---------------- launch ----------------

extern "C" void kernel_launch(void* const* d_in, const int* in_sizes, int n_in,
                              void* d_out, int out_size, void* d_ws, size_t ws_size,
                              hipStream_t stream) {
    const float* x   = (const float*)d_in[0];
    const int*   ei  = (const int*)d_in[1];
    const float* W1  = (const float*)d_in[2];
    const float* a1s = (const float*)d_in[3];
    const float* a1d = (const float*)d_in[4];
    const float* b1  = (const float*)d_in[5];
    const float* Wl1 = (const float*)d_in[6];
    const float* bl1 = (const float*)d_in[7];
    const float* W2  = (const float*)d_in[8];
    const float* a2s = (const float*)d_in[9];
    const float* a2d = (const float*)d_in[10];
    const float* b2  = (const float*)d_in[11];
    const float* Wl2 = (const float*)d_in[12];
    const float* bl2 = (const float*)d_in[13];
    const float* W3  = (const float*)d_in[14];
    const float* a3s = (const float*)d_in[15];
    const float* a3d = (const float*)d_in[16];
    const float* b3  = (const float*)d_in[17];
    const float* Wl3 = (const float*)d_in[18];
    const float* bl3 = (const float*)d_in[19];
    float* out = (float*)d_out;

    size_t cur = 0;
    char* wsb = (char*)d_ws;
    auto carve = [&](size_t bytes) -> void* {
        void* p = wsb + cur;
        cur += (bytes + 255) & ~(size_t)255;
        return p;
    };
    int*   cnt    = (int*)  carve((size_t)N_NODES * 4);
    int*   offs   = (int*)  carve((size_t)(N_NODES + 1) * 4);
    int*   cursor = (int*)  carve((size_t)N_NODES * 4);
    int*   part   = (int*)  carve((size_t)SCAN_NB * 4);
    unsigned* csr = (unsigned*)carve((size_t)E_TOT * 4);
    unsigned short* WALL = (unsigned short*)carve((size_t)WALL_TOT * 2);
    // Xb, HFb, LINB, PAD contiguous (each 12.8 MB) and all dead before agg3f
    // -> AGG ([N][512] bf16 = 51.2 MB) aliases exactly this 4x12.8 MB region.
    unsigned short* Xb   = (unsigned short*)carve((size_t)N_NODES * 128 * 2);
    unsigned short* HFb  = (unsigned short*)carve((size_t)N_NODES * 128 * 2);
    unsigned short* LINB = (unsigned short*)carve((size_t)N_NODES * 128 * 2);
    carve((size_t)N_NODES * 128 * 2);   // pad so AGG doesn't overlap Bb
    unsigned short* AGG  = Xb;   // alias
    unsigned short* Bb   = (unsigned short*)carve((size_t)N_NODES * 128 * 2);
    float* ASRC   = (float*)carve((size_t)N_NODES * 4 * 4);
    float* ADST   = (float*)carve((size_t)N_NODES * 4 * 4);
    float4* W4    = (float4*)carve((size_t)E_TOT * 16);
    float* W4T    = (float*)W4;   // planar alias (same 13.6 MB, disjoint in time)
    float* VS     = (float*)carve((size_t)4 * 128 * 4);
    float* VD     = (float*)carve((size_t)4 * 128 * 4);

    unsigned short* Wb1h = WALL + 0;
    unsigned short* Wb1l = WALL + 16384;
    unsigned short* Wb2h = WALL + 32768;
    unsigned short* Wb2l = WALL + 49152;
    unsigned short* Wb3l = WALL + 65536;
    unsigned short* W3m  = WALL + 71680;

    const int* esrc = ei;
    const int* edst = ei + N_EDGES;

    prep<<<PREP_TOT / 256, 256, 0, stream>>>(W1, Wl1, W2, Wl2, W3, Wl3, a3s, a3d, x,
                                             WALL, Xb, VS, VD);

    hipMemsetAsync(cnt, 0, (size_t)N_NODES * 4, stream);
    int egrid = (E_TOT + 255) / 256;
    count_deg<<<egrid, 256, 0, stream>>>(edst, cnt);
    scan_part1<<<SCAN_NB, 256, 0, stream>>>(cnt, part);
    scan_part2<<<1, 256, 0, stream>>>(part);
    scan_part3<<<SCAN_NB, 256, 0, stream>>>(cnt, part, offs, cursor);
    scatter_edges<<<egrid, 256, 0, stream>>>(esrc, edst, cursor, csr);

    int ngrid = N_NODES / 4;
    int ggrid = (NROWT + 3) / 4;   // 782

    // ---- layer 1 ----
    gemm_dual_a<<<ggrid, 256, 0, stream>>>(Xb, Wb1h, Wb1l, bl1, b1, a1s, a1d,
                                           HFb, LINB, ASRC, ADST);
    edge_weights<true><<<egrid, 256, 0, stream>>>(csr, ASRC, ADST, W4, W4T);
    agg12<false><<<ngrid, 256, 0, stream>>>(offs, csr, (const uint2*)HFb, W4T,
                                            (const uint2*)LINB, (unsigned*)Bb,
                                            nullptr, nullptr, nullptr, nullptr);
    // ---- layer 2 (epilogue computes layer-3 logits from fp32 outputs) ----
    gemm_dual_a<<<ggrid, 256, 0, stream>>>(Bb, Wb2h, Wb2l, bl2, b2, a2s, a2d,
                                           HFb, LINB, ASRC, ADST);
    edge_weights<true><<<egrid, 256, 0, stream>>>(csr, ASRC, ADST, W4, W4T);
    agg12<true><<<ngrid, 256, 0, stream>>>(offs, csr, (const uint2*)HFb, W4T,
                                           (const uint2*)LINB, (unsigned*)Bb,
                                           (const float4*)VS, (const float4*)VD,
                                           ASRC, ADST);
    // ---- layer 3 (W3 folded past aggregation; LIN3 fused into post) ----
    edge_weights<false><<<egrid, 256, 0, stream>>>(csr, ASRC, ADST, W4, W4T);
    agg3f<<<ngrid, 256, 0, stream>>>(offs, csr, (const unsigned*)Bb, W4, (unsigned*)AGG);
    post_ls<<<ggrid, 256, 0, stream>>>(AGG, Bb, W3m, Wb3l, b3, bl3, out);
}